// Round 11
// baseline (1965.363 us; speedup 1.0000x reference)
//
#include <hip/hip_runtime.h>

// ---------------------------------------------------------------------------
// Llama decoder layer, MI355X (gfx950).
// B=2 S=2048 HIDDEN=4096 HQ=32 HKV=8 D=128 INTER=11008, fp32 in/out.
// R11: dual-N gate+up GEMM (gemm256_gateup_kernel): one block computes a
// 128x256 tile of BOTH gate and up projections sharing the A-fragments
// (LDS-reads per MFMA halved: 24/64 vs 24/32 -- the measured 46% ceiling is
// LDS-read serialization), silu applied in-register at the epilogue (gate
// buffer round-trip eliminated). Bu single-buffered; counted-vmcnt ledger:
// {A,Bg}(u+1)@top (6), Bu(u+1)@P4-end (4); vmcnt(6) gate before P3,
// vmcnt(4) at tile end. gemm256_kernel/attn/others byte-frozen at R10.
// ---------------------------------------------------------------------------

typedef __attribute__((ext_vector_type(8))) short bf16x8;
typedef __attribute__((ext_vector_type(4))) float f32x4;

__device__ __forceinline__ ushort f2bf(float f) {           // RNE fp32->bf16
  unsigned u = __float_as_uint(f);
  return (ushort)((u + 0x7fffu + ((u >> 16) & 1u)) >> 16);
}
__device__ __forceinline__ float bf2f(ushort u) {
  union { unsigned u32; float f; } x; x.u32 = ((unsigned)u) << 16; return x.f;
}
__device__ __forceinline__ void gload16(const void* g, void* l) {
  __builtin_amdgcn_global_load_lds((__attribute__((address_space(1))) void*)g,
                                   (__attribute__((address_space(3))) void*)l,
                                   16, 0, 0);
}

#define BARRIER() asm volatile("s_barrier" ::: "memory")
#define WAIT_LGKM0() asm volatile("s_waitcnt lgkmcnt(0)" ::: "memory")
#define WAIT_VM6() asm volatile("s_waitcnt vmcnt(6)" ::: "memory")
#define WAIT_VM4() asm volatile("s_waitcnt vmcnt(4)" ::: "memory")
#define WAIT_VM0() asm volatile("s_waitcnt vmcnt(0)" ::: "memory")

// --------------------------- RMSNorm (fp32 -> bf16) ------------------------
__global__ __launch_bounds__(256) void rmsnorm_kernel(
    const float* __restrict__ x, const float* __restrict__ g,
    ushort* __restrict__ out) {
  const int row = blockIdx.x, t = threadIdx.x;
  const float4* xp = (const float4*)(x + (size_t)row * 4096);
  float4 v[4]; float ss = 0.f;
#pragma unroll
  for (int i = 0; i < 4; ++i) {
    v[i] = xp[t + i * 256];
    ss += v[i].x * v[i].x + v[i].y * v[i].y + v[i].z * v[i].z + v[i].w * v[i].w;
  }
#pragma unroll
  for (int m = 32; m; m >>= 1) ss += __shfl_xor(ss, m);
  __shared__ float red[4];
  if ((t & 63) == 0) red[t >> 6] = ss;
  __syncthreads();
  float inv = rsqrtf((red[0] + red[1] + red[2] + red[3]) * (1.f / 4096.f) + 1e-6f);
  const float4* gp = (const float4*)g;
  ushort* op = out + (size_t)row * 4096;
#pragma unroll
  for (int i = 0; i < 4; ++i) {
    float4 gv = gp[t + i * 256];
    ushort4 o;
    o.x = f2bf(v[i].x * inv * gv.x); o.y = f2bf(v[i].y * inv * gv.y);
    o.z = f2bf(v[i].z * inv * gv.z); o.w = f2bf(v[i].w * inv * gv.w);
    *(ushort4*)(op + (size_t)(t + i * 256) * 4) = o;
  }
}

// ----------------- transpose + cast fp32 [R][ld_in] -> bf16 [C][R] ---------
__global__ __launch_bounds__(256) void transpose_cast_kernel(
    const float* __restrict__ in, ushort* __restrict__ out,
    int ld_in, int col_off, int R) {
  __shared__ ushort tile[64][65];
  const int t = threadIdx.x;
  const int r0 = blockIdx.x * 64, c0 = blockIdx.y * 64;
  const int rl = t >> 2, cl = (t & 3) * 16;
  const float* ip = in + (size_t)(r0 + rl) * ld_in + col_off + c0 + cl;
#pragma unroll
  for (int i = 0; i < 4; ++i) {
    float4 f = ((const float4*)ip)[i];
    tile[rl][cl + i * 4 + 0] = f2bf(f.x);
    tile[rl][cl + i * 4 + 1] = f2bf(f.y);
    tile[rl][cl + i * 4 + 2] = f2bf(f.z);
    tile[rl][cl + i * 4 + 3] = f2bf(f.w);
  }
  __syncthreads();
  union { ushort us[8]; uint4 v; } pk0, pk1;
#pragma unroll
  for (int j = 0; j < 8; ++j) pk0.us[j] = tile[cl + j][rl];
#pragma unroll
  for (int j = 0; j < 8; ++j) pk1.us[j] = tile[cl + 8 + j][rl];
  uint4* op = (uint4*)(out + (size_t)(c0 + rl) * R + r0 + cl);
  op[0] = pk0.v; op[1] = pk1.v;
}

// ------------------------- GEMM 256x256 8-phase ----------------------------
// Byte-identical to R8/R9/R10 (R4 body + col-major XCD chunk mapping).
template <typename OutT, bool RES>
__global__ __launch_bounds__(512, 2) void gemm256_kernel(
    const ushort* __restrict__ A, const ushort* __restrict__ Bt,
    OutT* __restrict__ C, const float* __restrict__ res,
    int M, int N, int K) {
  extern __shared__ ushort lds[];
  ushort* Al = lds;            // [buf:2][half:2][8192 ushorts]
  ushort* Bl = lds + 32768;
  const int t = threadIdx.x, l = t & 63, w = t >> 6;
  const int wr = w >> 2, wc = w & 3;
  const int lr = l & 15, lg = l >> 4;
  const int rhi = lr >> 3, rlo = lr & 7;
  const int srow = l >> 3, sg = (l & 7) ^ srow;

  const int nby = M >> 8;
  const int nwg = (N >> 8) * nby;
  const int cpx = nwg >> 3;
  const int bid = (int)blockIdx.x;
  const int swz = (bid & 7) * cpx + (bid >> 3);   // XCD chunk (nwg%8==0)
  const int m0 = (swz % nby) << 8;                // col-major: B panel shared
  const int n0 = (swz / nby) << 8;                // by 16 consecutive blocks

  const int lof0 = rhi * 512 + rlo * 64 + ((0 + lg) ^ rlo) * 8;  // kk=0
  const int lof1 = rhi * 512 + rlo * 64 + ((4 + lg) ^ rlo) * 8;  // kk=1

  const f32x4 fz = {0.f, 0.f, 0.f, 0.f};
  f32x4 acc[8][4];
#pragma unroll
  for (int i = 0; i < 8; ++i)
#pragma unroll
    for (int j = 0; j < 4; ++j) acc[i][j] = fz;
  bf16x8 a[8][2];
  bf16x8 bq[2][2];

  const ushort* Asrc = A + (size_t)(m0 + w * 8 + srow) * K + sg * 8;
  const ushort* Bsrc = Bt + (size_t)(n0 + w * 8 + srow) * K + sg * 8;
  const size_t rK64 = (size_t)64 * K, rK128 = (size_t)128 * K;
  ushort* Adst = Al + w * 512;
  ushort* Bdst = Bl + w * 512;

#define STAGE_A(buf, half, tile) do {                                   \
    const ushort* s_ = Asrc + (size_t)(half) * rK128 + ((tile) << 6);   \
    ushort* d_ = Adst + (buf) * 16384 + (half) * 8192;                  \
    gload16(s_, d_);                                                    \
    gload16(s_ + rK64, d_ + 4096);                                      \
  } while (0)
#define STAGE_B(buf, half, tile) do {                                   \
    const ushort* s_ = Bsrc + (size_t)(half) * rK128 + ((tile) << 6);   \
    ushort* d_ = Bdst + (buf) * 16384 + (half) * 8192;                  \
    gload16(s_, d_);                                                    \
    gload16(s_ + rK64, d_ + 4096);                                      \
  } while (0)
#define LDA4(AH, QM) do {                                                   \
    _Pragma("unroll") for (int mi_ = 0; mi_ < 4; ++mi_) {                   \
      a[(QM) * 4 + mi_][0] =                                                \
          *(const bf16x8*)((AH) + ((QM) * 4 + mi_) * 1024 + lof0);          \
      a[(QM) * 4 + mi_][1] =                                                \
          *(const bf16x8*)((AH) + ((QM) * 4 + mi_) * 1024 + lof1);          \
    } } while (0)
#define LDB2(BH, NQ) do {                                                   \
    _Pragma("unroll") for (int nj_ = 0; nj_ < 2; ++nj_) {                   \
      bq[nj_][0] = *(const bf16x8*)((BH) + ((NQ) * 2 + nj_) * 1024 + lof0); \
      bq[nj_][1] = *(const bf16x8*)((BH) + ((NQ) * 2 + nj_) * 1024 + lof1); \
    } } while (0)
#define MFMA16(QM, QN)                                                      \
    __builtin_amdgcn_s_setprio(1);                                          \
    _Pragma("unroll") for (int mi_ = 0; mi_ < 4; ++mi_)                     \
    _Pragma("unroll") for (int nj_ = 0; nj_ < 2; ++nj_) {                   \
      acc[(QM) * 4 + mi_][(QN) * 2 + nj_] =                                 \
          __builtin_amdgcn_mfma_f32_16x16x32_bf16(                          \
              a[(QM) * 4 + mi_][0], bq[nj_][0],                             \
              acc[(QM) * 4 + mi_][(QN) * 2 + nj_], 0, 0, 0);                \
      acc[(QM) * 4 + mi_][(QN) * 2 + nj_] =                                 \
          __builtin_amdgcn_mfma_f32_16x16x32_bf16(                          \
              a[(QM) * 4 + mi_][1], bq[nj_][1],                             \
              acc[(QM) * 4 + mi_][(QN) * 2 + nj_], 0, 0, 0);                \
    }                                                                       \
    __builtin_amdgcn_s_setprio(0);

  const ushort* A0h = Al + wr * 8192;
  const ushort* A1h = A0h + 16384;
  const ushort* B0h = Bl + (wc >> 1) * 8192 + (wc & 1) * 4096;
  const ushort* B1h = B0h + 16384;

  const int ntiles = K >> 6, nIter = K >> 7;
  // prologue: tile0 full -> buf0; tile1 A halves -> buf1
  STAGE_A(0, 0, 0); STAGE_A(0, 1, 0); STAGE_B(0, 0, 0); STAGE_B(0, 1, 0);
  STAGE_A(1, 0, 1); STAGE_A(1, 1, 1);
  WAIT_VM4(); BARRIER();

  for (int it = 0; it < nIter; ++it) {
    const int u = it * 2;
    // ---- tile u (buf0) ----
    LDA4(A0h, 0); LDB2(B0h, 0);                 // P1
    STAGE_B(1, 0, u + 1);
    BARRIER(); WAIT_LGKM0(); MFMA16(0, 0); BARRIER();
    LDA4(A0h, 1);                               // P2
    STAGE_B(1, 1, u + 1);
    BARRIER(); WAIT_LGKM0(); MFMA16(1, 0); BARRIER();
    LDB2(B0h, 1);                               // P3
    if (u + 2 < ntiles) STAGE_A(0, 0, u + 2);
    BARRIER(); WAIT_LGKM0(); MFMA16(0, 1); BARRIER();
    if (u + 2 < ntiles) STAGE_A(0, 1, u + 2);   // P4
    BARRIER(); MFMA16(1, 1);
    if (u + 2 < ntiles) { WAIT_VM4(); } else { WAIT_VM0(); }
    BARRIER();
    // ---- tile u+1 (buf1) ----
    LDA4(A1h, 0); LDB2(B1h, 0);                 // P5
    if (u + 2 < ntiles) STAGE_B(0, 0, u + 2);
    BARRIER(); WAIT_LGKM0(); MFMA16(0, 0); BARRIER();
    LDA4(A1h, 1);                               // P6
    if (u + 2 < ntiles) STAGE_B(0, 1, u + 2);
    BARRIER(); WAIT_LGKM0(); MFMA16(1, 0); BARRIER();
    LDB2(B1h, 1);                               // P7
    if (u + 3 < ntiles) STAGE_A(1, 0, u + 3);
    BARRIER(); WAIT_LGKM0(); MFMA16(0, 1); BARRIER();
    if (u + 3 < ntiles) STAGE_A(1, 1, u + 3);   // P8
    BARRIER(); MFMA16(1, 1);
    WAIT_VM4(); BARRIER();
  }

  // epilogue: C row = m0+wr*128+mi*16+lg*4+r, col = n0+wc*64+ni*16+lr
#pragma unroll
  for (int mi = 0; mi < 8; ++mi)
#pragma unroll
    for (int ni = 0; ni < 4; ++ni)
#pragma unroll
      for (int r = 0; r < 4; ++r) {
        int row = m0 + wr * 128 + mi * 16 + lg * 4 + r;
        int col = n0 + wc * 64 + ni * 16 + lr;
        size_t idx = (size_t)row * N + col;
        float v = acc[mi][ni][r];
        if (RES) v += res[idx];
        if constexpr (sizeof(OutT) == 2) C[idx] = f2bf(v);
        else                             C[idx] = v;
      }
#undef STAGE_A
#undef STAGE_B
#undef LDA4
#undef LDB2
#undef MFMA16
}

// ----------------- dual-N GEMM: act = silu(A*Bg^T) * (A*Bu^T) --------------
// 128x256 tile of BOTH gate and up per block; A-fragments shared.
// LDS: A dbuf 32K + Bg dbuf 64K + Bu single 32K = 128KB.
__global__ __launch_bounds__(512, 2) void gemm256_gateup_kernel(
    const ushort* __restrict__ A, const ushort* __restrict__ Bg,
    const ushort* __restrict__ Bu, ushort* __restrict__ C,
    int M, int N, int K) {
  extern __shared__ ushort lds[];
  ushort* Al  = lds;           // [2][8192]  A tile 128x64
  ushort* Bgl = lds + 16384;   // [2][16384] Bg tile 256x64
  ushort* Bul = lds + 49152;   // [16384]    Bu tile 256x64 (single buf)
  const int t = threadIdx.x, l = t & 63, w = t >> 6;
  const int wr = w >> 2, wc = w & 3;           // wave tile: rows wr*64, cols wc*64
  const int lr = l & 15, lg = l >> 4;
  const int rhi = lr >> 3, rlo = lr & 7;
  const int srow = l >> 3, sg = (l & 7) ^ srow;

  const int nby = M >> 7;                      // 32
  const int nwg = (N >> 8) * nby;              // 1376 (%8==0)
  const int cpx = nwg >> 3;
  const int bid = (int)blockIdx.x;
  const int swz = (bid & 7) * cpx + (bid >> 3);
  const int m0 = (swz % nby) << 7;
  const int n0 = (swz / nby) << 8;

  const int lof0 = rhi * 512 + rlo * 64 + ((0 + lg) ^ rlo) * 8;
  const int lof1 = rhi * 512 + rlo * 64 + ((4 + lg) ^ rlo) * 8;

  const f32x4 fz = {0.f, 0.f, 0.f, 0.f};
  f32x4 accg[4][4], accu[4][4];
#pragma unroll
  for (int i = 0; i < 4; ++i)
#pragma unroll
    for (int j = 0; j < 4; ++j) { accg[i][j] = fz; accu[i][j] = fz; }
  bf16x8 a[4][2];
  bf16x8 bq[2][2];

  const ushort* Asrc  = A  + (size_t)(m0 + w * 8 + srow) * K + sg * 8;
  const ushort* Bgsrc = Bg + (size_t)(n0 + w * 8 + srow) * K + sg * 8;
  const ushort* Busrc = Bu + (size_t)(n0 + w * 8 + srow) * K + sg * 8;
  const size_t rK64 = (size_t)64 * K;
  ushort* Adst  = Al  + w * 512;
  ushort* Bgdst = Bgl + w * 512;
  ushort* Budst = Bul + w * 512;

#define GU_STAGE_A2(buf, tile) do {                                     \
    const ushort* s_ = Asrc + ((tile) << 6);                            \
    ushort* d_ = Adst + (buf) * 8192;                                   \
    gload16(s_, d_); gload16(s_ + rK64, d_ + 4096);                     \
  } while (0)
#define GU_STAGE_BG4(buf, tile) do {                                    \
    const ushort* s_ = Bgsrc + ((tile) << 6);                           \
    ushort* d_ = Bgdst + (buf) * 16384;                                 \
    gload16(s_, d_);             gload16(s_ + rK64, d_ + 4096);         \
    gload16(s_ + 2 * rK64, d_ + 8192); gload16(s_ + 3 * rK64, d_ + 12288); \
  } while (0)
#define GU_STAGE_BU4(tile) do {                                         \
    const ushort* s_ = Busrc + ((tile) << 6);                           \
    gload16(s_, Budst);              gload16(s_ + rK64, Budst + 4096);  \
    gload16(s_ + 2 * rK64, Budst + 8192);                               \
    gload16(s_ + 3 * rK64, Budst + 12288);                              \
  } while (0)
#define GU_LDA8(AH) do {                                                    \
    _Pragma("unroll") for (int mi_ = 0; mi_ < 4; ++mi_) {                   \
      a[mi_][0] = *(const bf16x8*)((AH) + mi_ * 1024 + lof0);               \
      a[mi_][1] = *(const bf16x8*)((AH) + mi_ * 1024 + lof1);               \
    } } while (0)
#define GU_LDB2(BH, NQ) do {                                                \
    _Pragma("unroll") for (int nj_ = 0; nj_ < 2; ++nj_) {                   \
      bq[nj_][0] = *(const bf16x8*)((BH) + ((NQ) * 2 + nj_) * 1024 + lof0); \
      bq[nj_][1] = *(const bf16x8*)((BH) + ((NQ) * 2 + nj_) * 1024 + lof1); \
    } } while (0)
#define GU_MFMA16(ACC, QN)                                                  \
    __builtin_amdgcn_s_setprio(1);                                          \
    _Pragma("unroll") for (int mi_ = 0; mi_ < 4; ++mi_)                     \
    _Pragma("unroll") for (int nj_ = 0; nj_ < 2; ++nj_) {                   \
      ACC[mi_][(QN) * 2 + nj_] =                                            \
          __builtin_amdgcn_mfma_f32_16x16x32_bf16(                          \
              a[mi_][0], bq[nj_][0], ACC[mi_][(QN) * 2 + nj_], 0, 0, 0);    \
      ACC[mi_][(QN) * 2 + nj_] =                                            \
          __builtin_amdgcn_mfma_f32_16x16x32_bf16(                          \
              a[mi_][1], bq[nj_][1], ACC[mi_][(QN) * 2 + nj_], 0, 0, 0);    \
    }                                                                       \
    __builtin_amdgcn_s_setprio(0);

  const int nt = K >> 6;
  // prologue: full tile 0, drain
  GU_STAGE_A2(0, 0); GU_STAGE_BG4(0, 0); GU_STAGE_BU4(0);
  WAIT_VM0(); BARRIER();

  for (int u = 0; u < nt; ++u) {
    const int buf = u & 1;
    const ushort* Ah  = Al  + buf * 8192  + wr * 4096;
    const ushort* Bgh = Bgl + buf * 16384 + wc * 4096;
    const ushort* Buh = Bul + wc * 4096;
    const bool more = (u + 1 < nt);
    if (more) { GU_STAGE_A2(buf ^ 1, u + 1); GU_STAGE_BG4(buf ^ 1, u + 1); }
    // P1: A frags + gate quad 0
    GU_LDA8(Ah); GU_LDB2(Bgh, 0);
    BARRIER(); WAIT_LGKM0(); GU_MFMA16(accg, 0); BARRIER();
    // P2: gate quad 1
    GU_LDB2(Bgh, 1);
    BARRIER(); WAIT_LGKM0(); GU_MFMA16(accg, 1); BARRIER();
    // gate: Bu(u) landed (4 oldest of 10 outstanding) before reading Bu
    if (more) { WAIT_VM6(); } else { WAIT_VM0(); }
    BARRIER();
    // P3: up quad 0
    GU_LDB2(Buh, 0);
    BARRIER(); WAIT_LGKM0(); GU_MFMA16(accu, 0); BARRIER();
    // P4: up quad 1
    GU_LDB2(Buh, 1);
    BARRIER(); WAIT_LGKM0(); GU_MFMA16(accu, 1); BARRIER();
    // stage Bu(u+1) after all Bu(u) reads; drain A,Bg(u+1) (leave Bu in flight)
    if (more) { GU_STAGE_BU4(u + 1); WAIT_VM4(); }
    BARRIER();
  }

  // epilogue: act = silu(gate) * up, in-register
#pragma unroll
  for (int mi = 0; mi < 4; ++mi)
#pragma unroll
    for (int ni = 0; ni < 4; ++ni)
#pragma unroll
      for (int r = 0; r < 4; ++r) {
        int row = m0 + wr * 64 + mi * 16 + lg * 4 + r;
        int col = n0 + wc * 64 + ni * 16 + lr;
        size_t idx = (size_t)row * N + col;
        float g = accg[mi][ni][r];
        float s = g / (1.f + __expf(-g));
        C[idx] = f2bf(s * accu[mi][ni][r]);
      }
#undef GU_STAGE_A2
#undef GU_STAGE_BG4
#undef GU_STAGE_BU4
#undef GU_LDA8
#undef GU_LDB2
#undef GU_MFMA16
}

// ------------------------------ RoPE table ---------------------------------
__global__ void rope_table_kernel(const int* __restrict__ pos,
                                  float2* __restrict__ tab) {
  int idx = blockIdx.x * 256 + threadIdx.x;  // 2048*64
  int s = idx >> 6, fi = idx & 63;
  float inv = (float)exp(-(double)(2 * fi) / 128.0 * 9.210340371976184);
  float a = (float)pos[s] * inv;
  tab[idx] = make_float2(cosf(a), sinf(a));
}

// --------- RoPE + scatter qkv[T,6144] -> Qr[b,h,s,d] Kr[b,h,s,d] Vt[b,h,d,s]
__global__ __launch_bounds__(256) void rope_scatter_kernel(
    const ushort* __restrict__ qkv, const float2* __restrict__ tab,
    ushort* __restrict__ Qr, ushort* __restrict__ Kr, ushort* __restrict__ Vt) {
  __shared__ ushort vt[64][132];
  const int t = threadIdx.x, tt = blockIdx.x, h = blockIdx.y;  // h: 0..47
  const int row = t >> 2, c = (t & 3) * 16;
  const int tok = tt * 64 + row;
  const int b = tok >> 11, s = tok & 2047;
  const ushort* ip = qkv + (size_t)tok * 6144 + h * 128;
  union U { uint4 v; ushort us[8]; };
  U a0, a1, b0, b1;
  a0.v = *(const uint4*)(ip + c);      a1.v = *(const uint4*)(ip + c + 8);
  b0.v = *(const uint4*)(ip + c + 64); b1.v = *(const uint4*)(ip + c + 72);
  if (h < 40) {  // q or k head: NeoX rope on pairs (i, i+64)
    U o0, o1, o2, o3;
#pragma unroll
    for (int j = 0; j < 8; ++j) {
      float2 cs = tab[s * 64 + c + j];
      float x1 = bf2f(a0.us[j]), x2 = bf2f(b0.us[j]);
      o0.us[j] = f2bf(x1 * cs.x - x2 * cs.y);
      o2.us[j] = f2bf(x2 * cs.x + x1 * cs.y);
    }
#pragma unroll
    for (int j = 0; j < 8; ++j) {
      float2 cs = tab[s * 64 + c + 8 + j];
      float x1 = bf2f(a1.us[j]), x2 = bf2f(b1.us[j]);
      o1.us[j] = f2bf(x1 * cs.x - x2 * cs.y);
      o3.us[j] = f2bf(x2 * cs.x + x1 * cs.y);
    }
    ushort* base;
    if (h < 32) base = Qr + ((size_t)((b * 32 + h) * 2048 + s)) * 128;
    else        base = Kr + ((size_t)((b * 8 + (h - 32)) * 2048 + s)) * 128;
    *(uint4*)(base + c)      = o0.v; *(uint4*)(base + c + 8)  = o1.v;
    *(uint4*)(base + c + 64) = o2.v; *(uint4*)(base + c + 72) = o3.v;
  } else {  // v head: LDS transpose -> Vt[b,hv,d,s]
    const int hv = h - 40;
#pragma unroll
    for (int j = 0; j < 8; ++j) {
      vt[row][c + j]      = a0.us[j]; vt[row][c + 8 + j]  = a1.us[j];
      vt[row][c + 64 + j] = b0.us[j]; vt[row][c + 72 + j] = b1.us[j];
    }
    __syncthreads();
    const int d = t >> 1, s0 = (t & 1) * 32, sb = (tt & 31) * 64;
    U w0, w1, w2, w3;
#pragma unroll
    for (int j = 0; j < 8; ++j) {
      w0.us[j] = vt[s0 + j][d];      w1.us[j] = vt[s0 + 8 + j][d];
      w2.us[j] = vt[s0 + 16 + j][d]; w3.us[j] = vt[s0 + 24 + j][d];
    }
    ushort* vb = Vt + ((size_t)((b * 8 + hv) * 128 + d)) * 2048 + sb + s0;
    *(uint4*)(vb) = w0.v;      *(uint4*)(vb + 8) = w1.v;
    *(uint4*)(vb + 16) = w2.v; *(uint4*)(vb + 24) = w3.v;
  }
}

// --------------------------- flash attention -------------------------------
// QBLK=128, 8 waves, KVBLK=64; XOR-swizzled K/V/P LDS, K/V dbuf vmcnt(4),
// log2 softmax, MFMA row-sum, defer-max THR=8, wave-uniform mask.
__global__ __launch_bounds__(512) void attn_kernel(
    const ushort* __restrict__ Q, const ushort* __restrict__ K,
    const ushort* __restrict__ V, ushort* __restrict__ O) {
  extern __shared__ ushort sm[];
  ushort* Kl = sm;           // [2][64 s][128 d]
  ushort* Vl = sm + 16384;   // [2][128 d][64 s]
  ushort* Pl = sm + 32768;   // [128][64]
  const int t = threadIdx.x, l = t & 63, w = t >> 6;   // w: 0..7
  const int lr = l & 15, lg = l >> 4;
  const int qb = blockIdx.x, h = blockIdx.y, b = blockIdx.z;
  const int hkv = h >> 2;
  const f32x4 fzero = {0.f, 0.f, 0.f, 0.f};

  const int rm = lr & 7;
  int ksw[4], vsw[2];
#pragma unroll
  for (int ks = 0; ks < 4; ++ks) ksw[ks] = ((ks * 4 + lg) ^ rm) * 8;
  vsw[0] = (lg ^ rm) * 8;
  vsw[1] = ((4 + lg) ^ rm) * 8;
  const int kcol = ((t & 15) ^ ((t >> 4) & 7)) * 8;   // staging src swizzle
  const int vcol = ((t & 7) ^ ((t >> 3) & 7)) * 8;

  const float qscale = 0.08838834764831845f * 1.4426950408889634f;
  const ushort* qp =
      Q + ((size_t)((b * 32 + h) * 2048 + qb * 128 + w * 16 + lr)) * 128 + lg * 8;
  bf16x8 qf[4];
#pragma unroll
  for (int ks = 0; ks < 4; ++ks) {
    bf16x8 raw = *(const bf16x8*)(qp + ks * 32);
#pragma unroll
    for (int j = 0; j < 8; ++j)
      qf[ks][j] = (short)f2bf(bf2f((ushort)raw[j]) * qscale);
  }
  bf16x8 ones;
#pragma unroll
  for (int j = 0; j < 8; ++j) ones[j] = (short)0x3F80;
  WAIT_VM0();

  const ushort* kg = K + ((size_t)(b * 8 + hkv)) * 2048 * 128;
  const ushort* vg = V + ((size_t)(b * 8 + hkv)) * 128 * 2048;

#define STAGE_KV(buf, s0_) do {                                              \
    _Pragma("unroll") for (int i_ = 0; i_ < 2; ++i_)                         \
      gload16(kg + (size_t)((s0_) + i_ * 32 + (t >> 4)) * 128 + kcol,        \
              (char*)Kl + (buf) * 16384 + i_ * 8192 + t * 16);               \
    _Pragma("unroll") for (int i_ = 0; i_ < 2; ++i_)                         \
      gload16(vg + (size_t)(i_ * 64 + (t >> 3)) * 2048 + (s0_) + vcol,       \
              (char*)Vl + (buf) * 16384 + i_ * 8192 + t * 16);               \
  } while (0)

  f32x4 accO[8];
#pragma unroll
  for (int i = 0; i < 8; ++i) accO[i] = fzero;
  float m_r[4] = {-1e30f, -1e30f, -1e30f, -1e30f};
  float l_r[4] = {0.f, 0.f, 0.f, 0.f};
  const int qrow = qb * 128 + w * 16 + lg * 4;
  const int wrow0 = qb * 128 + w * 16;
  const int jend = 2 * qb + 1;

  STAGE_KV(0, 0);
  for (int j = 0; j <= jend; ++j) {
    if (j < jend) { STAGE_KV((j + 1) & 1, (j + 1) * 64); WAIT_VM4(); }
    else          { WAIT_VM0(); }
    BARRIER();
    const ushort* Kb = Kl + (j & 1) * 8192;
    const ushort* Vb = Vl + (j & 1) * 8192;

    f32x4 sc[4];
#pragma unroll
    for (int ni = 0; ni < 4; ++ni) sc[ni] = fzero;
    __builtin_amdgcn_s_setprio(1);
#pragma unroll
    for (int ni = 0; ni < 4; ++ni)
#pragma unroll
      for (int ks = 0; ks < 4; ++ks) {
        bf16x8 kf = *(const bf16x8*)(Kb + (ni * 16 + lr) * 128 + ksw[ks]);
        sc[ni] = __builtin_amdgcn_mfma_f32_16x16x32_bf16(qf[ks], kf, sc[ni], 0, 0, 0);
      }
    __builtin_amdgcn_s_setprio(0);
    if (j * 64 + 63 > wrow0) {
#pragma unroll
      for (int ni = 0; ni < 4; ++ni)
#pragma unroll
        for (int r = 0; r < 4; ++r)
          if (j * 64 + ni * 16 + lr > qrow + r) sc[ni][r] = -1e30f;
    }
    float mx[4];
#pragma unroll
    for (int r = 0; r < 4; ++r) {
      float v = fmaxf(fmaxf(sc[0][r], sc[1][r]), fmaxf(sc[2][r], sc[3][r]));
#pragma unroll
      for (int m = 8; m; m >>= 1) v = fmaxf(v, __shfl_xor(v, m));
      mx[r] = v;
    }
    bool ok = mx[0] <= m_r[0] + 8.f && mx[1] <= m_r[1] + 8.f &&
              mx[2] <= m_r[2] + 8.f && mx[3] <= m_r[3] + 8.f;
    if (!__all(ok)) {
#pragma unroll
      for (int r = 0; r < 4; ++r) {
        float mnew = fmaxf(m_r[r], mx[r]);
        float fsc = exp2f(m_r[r] - mnew);
        l_r[r] *= fsc;
        m_r[r] = mnew;
#pragma unroll
        for (int i = 0; i < 8; ++i) accO[i][r] *= fsc;
      }
    }
#pragma unroll
    for (int ni = 0; ni < 4; ++ni)
#pragma unroll
      for (int r = 0; r < 4; ++r) {
        int prow = w * 16 + lg * 4 + r;
        int slot = (ni * 2 + (lr >> 3)) ^ (prow & 7);
        Pl[prow * 64 + slot * 8 + rm] = f2bf(exp2f(sc[ni][r] - m_r[r]));
      }
    WAIT_LGKM0();
    f32x4 accL = fzero;
    __builtin_amdgcn_s_setprio(1);
#pragma unroll
    for (int ks = 0; ks < 2; ++ks) {
      bf16x8 pf = *(const bf16x8*)(Pl + (w * 16 + lr) * 64 + vsw[ks]);
#pragma unroll
      for (int nf = 0; nf < 8; ++nf) {
        bf16x8 vf = *(const bf16x8*)(Vb + (nf * 16 + lr) * 64 + vsw[ks]);
        accO[nf] = __builtin_amdgcn_mfma_f32_16x16x32_bf16(pf, vf, accO[nf], 0, 0, 0);
      }
      accL = __builtin_amdgcn_mfma_f32_16x16x32_bf16(pf, ones, accL, 0, 0, 0);
    }
    __builtin_amdgcn_s_setprio(0);
#pragma unroll
    for (int r = 0; r < 4; ++r) l_r[r] += accL[r];
    BARRIER();
  }
#undef STAGE_KV
  float invl[4];
#pragma unroll
  for (int r = 0; r < 4; ++r) invl[r] = 1.f / l_r[r];
#pragma unroll
  for (int nf = 0; nf < 8; ++nf)
#pragma unroll
    for (int r = 0; r < 4; ++r) {
      int q = qb * 128 + w * 16 + lg * 4 + r;
      int d = nf * 16 + lr;
      O[((size_t)(b * 2048 + q)) * 4096 + h * 128 + d] = f2bf(accO[nf][r] * invl[r]);
    }
}

// ------------------------------ launcher -----------------------------------
#define OFF_W    ((size_t)0)
#define OFF_H1   ((size_t)90177536)
#define OFF_XN   ((size_t)157286400)
#define OFF_QKV  ((size_t)190840832)
#define OFF_TAB  ((size_t)241172480)
#define OFF_QR   ((size_t)242221056)
#define OFF_KR   ((size_t)275775488)
#define OFF_VT   ((size_t)284164096)
#define OFF_ATTN ((size_t)292552704)
#define OFF_W2   OFF_QKV   // up-weight^T: reuses qkv/tab/qr/kr space (dead in MLP)
#define OFF_UP   ((size_t)326107136)
#define WS_NEED  ((size_t)416284672)

extern "C" void kernel_launch(void* const* d_in, const int* in_sizes, int n_in,
                              void* d_out, int out_size, void* d_ws,
                              size_t ws_size, hipStream_t stream) {
  (void)in_sizes; (void)n_in; (void)out_size;
  if (ws_size < WS_NEED) return;
  const float* hs     = (const float*)d_in[0];
  const int*   pos    = (const int*)d_in[1];
  const float* w_qkv  = (const float*)d_in[2];
  const float* w_o    = (const float*)d_in[3];
  const float* w_gu   = (const float*)d_in[4];
  const float* w_down = (const float*)d_in[5];
  const float* ln1    = (const float*)d_in[6];
  const float* ln2    = (const float*)d_in[7];
  float* out = (float*)d_out;
  char* ws = (char*)d_ws;

  ushort* W    = (ushort*)(ws + OFF_W);
  ushort* W2   = (ushort*)(ws + OFF_W2);
  float*  h1   = (float*)(ws + OFF_H1);
  ushort* xn   = (ushort*)(ws + OFF_XN);
  ushort* qkv  = (ushort*)(ws + OFF_QKV);
  float2* tab  = (float2*)(ws + OFF_TAB);
  ushort* Qr   = (ushort*)(ws + OFF_QR);
  ushort* Kr   = (ushort*)(ws + OFF_KR);
  ushort* Vt   = (ushort*)(ws + OFF_VT);
  ushort* attn = (ushort*)(ws + OFF_ATTN);
  ushort* act  = (ushort*)(ws + OFF_UP);

  auto kb = gemm256_kernel<ushort, false>;
  auto kf = gemm256_kernel<float, true>;
  hipFuncSetAttribute((const void*)kb, hipFuncAttributeMaxDynamicSharedMemorySize, 131072);
  hipFuncSetAttribute((const void*)kf, hipFuncAttributeMaxDynamicSharedMemorySize, 131072);
  hipFuncSetAttribute((const void*)gemm256_gateup_kernel, hipFuncAttributeMaxDynamicSharedMemorySize, 131072);
  hipFuncSetAttribute((const void*)attn_kernel, hipFuncAttributeMaxDynamicSharedMemorySize, 81920);

  // --- attention block ---
  rmsnorm_kernel<<<4096, 256, 0, stream>>>(hs, ln1, xn);
  transpose_cast_kernel<<<dim3(64, 96), 256, 0, stream>>>(w_qkv, W, 6144, 0, 4096);
  gemm256_kernel<ushort, false><<<384, 512, 131072, stream>>>(
      xn, W, qkv, nullptr, 4096, 6144, 4096);
  rope_table_kernel<<<512, 256, 0, stream>>>(pos, tab);
  rope_scatter_kernel<<<dim3(64, 48), 256, 0, stream>>>(qkv, tab, Qr, Kr, Vt);
  attn_kernel<<<dim3(16, 32, 2), 512, 81920, stream>>>(Qr, Kr, Vt, attn);
  transpose_cast_kernel<<<dim3(64, 64), 256, 0, stream>>>(w_o, W, 4096, 0, 4096);
  gemm256_kernel<float, true><<<256, 512, 131072, stream>>>(
      attn, W, h1, hs, 4096, 4096, 4096);

  // --- MLP block ---
  rmsnorm_kernel<<<4096, 256, 0, stream>>>(h1, ln2, xn);
  transpose_cast_kernel<<<dim3(64, 172), 256, 0, stream>>>(w_gu, W, 22016, 0, 4096);
  transpose_cast_kernel<<<dim3(64, 172), 256, 0, stream>>>(w_gu, W2, 22016, 11008, 4096);
  gemm256_gateup_kernel<<<1376, 512, 131072, stream>>>(
      xn, W, W2, act, 4096, 11008, 4096);
  transpose_cast_kernel<<<dim3(172, 64), 256, 0, stream>>>(w_down, W, 4096, 0, 11008);
  gemm256_kernel<float, true><<<256, 512, 131072, stream>>>(
      act, W, out, h1, 4096, 4096, 11008);
}

// Round 12
// 1787.522 us; speedup vs baseline: 1.0995x; 1.0995x over previous
//
#include <hip/hip_runtime.h>

// ---------------------------------------------------------------------------
// Llama decoder layer, MI355X (gfx950).
// B=2 S=2048 HIDDEN=4096 HQ=32 HKV=8 D=128 INTER=11008, fp32 in/out.
// R12: revert to R10 (measured best, 1794us). R11's dual-N gate+up kernel
// regressed (900us, MfmaUtil 34.6%, FETCH 880MB): +25% stage traffic/FLOP,
// 4MB B-panel working set = L2 capacity (thrash), +2 barrier-pairs/K-tile.
// GEMM R4-body + col-major XCD mapping is a verified local optimum; the
// SwiGLU-fused up-GEMM lives in a separate copy-pasted kernel (rule #19).
// ---------------------------------------------------------------------------

typedef __attribute__((ext_vector_type(8))) short bf16x8;
typedef __attribute__((ext_vector_type(4))) float f32x4;

__device__ __forceinline__ ushort f2bf(float f) {           // RNE fp32->bf16
  unsigned u = __float_as_uint(f);
  return (ushort)((u + 0x7fffu + ((u >> 16) & 1u)) >> 16);
}
__device__ __forceinline__ float bf2f(ushort u) {
  union { unsigned u32; float f; } x; x.u32 = ((unsigned)u) << 16; return x.f;
}
__device__ __forceinline__ void gload16(const void* g, void* l) {
  __builtin_amdgcn_global_load_lds((__attribute__((address_space(1))) void*)g,
                                   (__attribute__((address_space(3))) void*)l,
                                   16, 0, 0);
}

#define BARRIER() asm volatile("s_barrier" ::: "memory")
#define WAIT_LGKM0() asm volatile("s_waitcnt lgkmcnt(0)" ::: "memory")
#define WAIT_VM4() asm volatile("s_waitcnt vmcnt(4)" ::: "memory")
#define WAIT_VM0() asm volatile("s_waitcnt vmcnt(0)" ::: "memory")

// --------------------------- RMSNorm (fp32 -> bf16) ------------------------
__global__ __launch_bounds__(256) void rmsnorm_kernel(
    const float* __restrict__ x, const float* __restrict__ g,
    ushort* __restrict__ out) {
  const int row = blockIdx.x, t = threadIdx.x;
  const float4* xp = (const float4*)(x + (size_t)row * 4096);
  float4 v[4]; float ss = 0.f;
#pragma unroll
  for (int i = 0; i < 4; ++i) {
    v[i] = xp[t + i * 256];
    ss += v[i].x * v[i].x + v[i].y * v[i].y + v[i].z * v[i].z + v[i].w * v[i].w;
  }
#pragma unroll
  for (int m = 32; m; m >>= 1) ss += __shfl_xor(ss, m);
  __shared__ float red[4];
  if ((t & 63) == 0) red[t >> 6] = ss;
  __syncthreads();
  float inv = rsqrtf((red[0] + red[1] + red[2] + red[3]) * (1.f / 4096.f) + 1e-6f);
  const float4* gp = (const float4*)g;
  ushort* op = out + (size_t)row * 4096;
#pragma unroll
  for (int i = 0; i < 4; ++i) {
    float4 gv = gp[t + i * 256];
    ushort4 o;
    o.x = f2bf(v[i].x * inv * gv.x); o.y = f2bf(v[i].y * inv * gv.y);
    o.z = f2bf(v[i].z * inv * gv.z); o.w = f2bf(v[i].w * inv * gv.w);
    *(ushort4*)(op + (size_t)(t + i * 256) * 4) = o;
  }
}

// ----------------- transpose + cast fp32 [R][ld_in] -> bf16 [C][R] ---------
__global__ __launch_bounds__(256) void transpose_cast_kernel(
    const float* __restrict__ in, ushort* __restrict__ out,
    int ld_in, int col_off, int R) {
  __shared__ ushort tile[64][65];
  const int t = threadIdx.x;
  const int r0 = blockIdx.x * 64, c0 = blockIdx.y * 64;
  const int rl = t >> 2, cl = (t & 3) * 16;
  const float* ip = in + (size_t)(r0 + rl) * ld_in + col_off + c0 + cl;
#pragma unroll
  for (int i = 0; i < 4; ++i) {
    float4 f = ((const float4*)ip)[i];
    tile[rl][cl + i * 4 + 0] = f2bf(f.x);
    tile[rl][cl + i * 4 + 1] = f2bf(f.y);
    tile[rl][cl + i * 4 + 2] = f2bf(f.z);
    tile[rl][cl + i * 4 + 3] = f2bf(f.w);
  }
  __syncthreads();
  union { ushort us[8]; uint4 v; } pk0, pk1;
#pragma unroll
  for (int j = 0; j < 8; ++j) pk0.us[j] = tile[cl + j][rl];
#pragma unroll
  for (int j = 0; j < 8; ++j) pk1.us[j] = tile[cl + 8 + j][rl];
  uint4* op = (uint4*)(out + (size_t)(c0 + rl) * R + r0 + cl);
  op[0] = pk0.v; op[1] = pk1.v;
}

// ------------------------- GEMM 256x256 8-phase ----------------------------
// Byte-identical to R8/R9/R10 (R4 body + col-major XCD chunk mapping).
template <typename OutT, bool RES>
__global__ __launch_bounds__(512, 2) void gemm256_kernel(
    const ushort* __restrict__ A, const ushort* __restrict__ Bt,
    OutT* __restrict__ C, const float* __restrict__ res,
    int M, int N, int K) {
  extern __shared__ ushort lds[];
  ushort* Al = lds;            // [buf:2][half:2][8192 ushorts]
  ushort* Bl = lds + 32768;
  const int t = threadIdx.x, l = t & 63, w = t >> 6;
  const int wr = w >> 2, wc = w & 3;
  const int lr = l & 15, lg = l >> 4;
  const int rhi = lr >> 3, rlo = lr & 7;
  const int srow = l >> 3, sg = (l & 7) ^ srow;

  const int nby = M >> 8;
  const int nwg = (N >> 8) * nby;
  const int cpx = nwg >> 3;
  const int bid = (int)blockIdx.x;
  const int swz = (bid & 7) * cpx + (bid >> 3);   // XCD chunk (nwg%8==0)
  const int m0 = (swz % nby) << 8;                // col-major: B panel shared
  const int n0 = (swz / nby) << 8;                // by 16 consecutive blocks

  const int lof0 = rhi * 512 + rlo * 64 + ((0 + lg) ^ rlo) * 8;  // kk=0
  const int lof1 = rhi * 512 + rlo * 64 + ((4 + lg) ^ rlo) * 8;  // kk=1

  const f32x4 fz = {0.f, 0.f, 0.f, 0.f};
  f32x4 acc[8][4];
#pragma unroll
  for (int i = 0; i < 8; ++i)
#pragma unroll
    for (int j = 0; j < 4; ++j) acc[i][j] = fz;
  bf16x8 a[8][2];
  bf16x8 bq[2][2];

  const ushort* Asrc = A + (size_t)(m0 + w * 8 + srow) * K + sg * 8;
  const ushort* Bsrc = Bt + (size_t)(n0 + w * 8 + srow) * K + sg * 8;
  const size_t rK64 = (size_t)64 * K, rK128 = (size_t)128 * K;
  ushort* Adst = Al + w * 512;
  ushort* Bdst = Bl + w * 512;

#define STAGE_A(buf, half, tile) do {                                   \
    const ushort* s_ = Asrc + (size_t)(half) * rK128 + ((tile) << 6);   \
    ushort* d_ = Adst + (buf) * 16384 + (half) * 8192;                  \
    gload16(s_, d_);                                                    \
    gload16(s_ + rK64, d_ + 4096);                                      \
  } while (0)
#define STAGE_B(buf, half, tile) do {                                   \
    const ushort* s_ = Bsrc + (size_t)(half) * rK128 + ((tile) << 6);   \
    ushort* d_ = Bdst + (buf) * 16384 + (half) * 8192;                  \
    gload16(s_, d_);                                                    \
    gload16(s_ + rK64, d_ + 4096);                                      \
  } while (0)
#define LDA4(AH, QM) do {                                                   \
    _Pragma("unroll") for (int mi_ = 0; mi_ < 4; ++mi_) {                   \
      a[(QM) * 4 + mi_][0] =                                                \
          *(const bf16x8*)((AH) + ((QM) * 4 + mi_) * 1024 + lof0);          \
      a[(QM) * 4 + mi_][1] =                                                \
          *(const bf16x8*)((AH) + ((QM) * 4 + mi_) * 1024 + lof1);          \
    } } while (0)
#define LDB2(BH, NQ) do {                                                   \
    _Pragma("unroll") for (int nj_ = 0; nj_ < 2; ++nj_) {                   \
      bq[nj_][0] = *(const bf16x8*)((BH) + ((NQ) * 2 + nj_) * 1024 + lof0); \
      bq[nj_][1] = *(const bf16x8*)((BH) + ((NQ) * 2 + nj_) * 1024 + lof1); \
    } } while (0)
#define MFMA16(QM, QN)                                                      \
    __builtin_amdgcn_s_setprio(1);                                          \
    _Pragma("unroll") for (int mi_ = 0; mi_ < 4; ++mi_)                     \
    _Pragma("unroll") for (int nj_ = 0; nj_ < 2; ++nj_) {                   \
      acc[(QM) * 4 + mi_][(QN) * 2 + nj_] =                                 \
          __builtin_amdgcn_mfma_f32_16x16x32_bf16(                          \
              a[(QM) * 4 + mi_][0], bq[nj_][0],                             \
              acc[(QM) * 4 + mi_][(QN) * 2 + nj_], 0, 0, 0);                \
      acc[(QM) * 4 + mi_][(QN) * 2 + nj_] =                                 \
          __builtin_amdgcn_mfma_f32_16x16x32_bf16(                          \
              a[(QM) * 4 + mi_][1], bq[nj_][1],                             \
              acc[(QM) * 4 + mi_][(QN) * 2 + nj_], 0, 0, 0);                \
    }                                                                       \
    __builtin_amdgcn_s_setprio(0);

  const ushort* A0h = Al + wr * 8192;
  const ushort* A1h = A0h + 16384;
  const ushort* B0h = Bl + (wc >> 1) * 8192 + (wc & 1) * 4096;
  const ushort* B1h = B0h + 16384;

  const int ntiles = K >> 6, nIter = K >> 7;
  // prologue: tile0 full -> buf0; tile1 A halves -> buf1
  STAGE_A(0, 0, 0); STAGE_A(0, 1, 0); STAGE_B(0, 0, 0); STAGE_B(0, 1, 0);
  STAGE_A(1, 0, 1); STAGE_A(1, 1, 1);
  WAIT_VM4(); BARRIER();

  for (int it = 0; it < nIter; ++it) {
    const int u = it * 2;
    // ---- tile u (buf0) ----
    LDA4(A0h, 0); LDB2(B0h, 0);                 // P1
    STAGE_B(1, 0, u + 1);
    BARRIER(); WAIT_LGKM0(); MFMA16(0, 0); BARRIER();
    LDA4(A0h, 1);                               // P2
    STAGE_B(1, 1, u + 1);
    BARRIER(); WAIT_LGKM0(); MFMA16(1, 0); BARRIER();
    LDB2(B0h, 1);                               // P3
    if (u + 2 < ntiles) STAGE_A(0, 0, u + 2);
    BARRIER(); WAIT_LGKM0(); MFMA16(0, 1); BARRIER();
    if (u + 2 < ntiles) STAGE_A(0, 1, u + 2);   // P4
    BARRIER(); MFMA16(1, 1);
    if (u + 2 < ntiles) { WAIT_VM4(); } else { WAIT_VM0(); }
    BARRIER();
    // ---- tile u+1 (buf1) ----
    LDA4(A1h, 0); LDB2(B1h, 0);                 // P5
    if (u + 2 < ntiles) STAGE_B(0, 0, u + 2);
    BARRIER(); WAIT_LGKM0(); MFMA16(0, 0); BARRIER();
    LDA4(A1h, 1);                               // P6
    if (u + 2 < ntiles) STAGE_B(0, 1, u + 2);
    BARRIER(); WAIT_LGKM0(); MFMA16(1, 0); BARRIER();
    LDB2(B1h, 1);                               // P7
    if (u + 3 < ntiles) STAGE_A(1, 0, u + 3);
    BARRIER(); WAIT_LGKM0(); MFMA16(0, 1); BARRIER();
    if (u + 3 < ntiles) STAGE_A(1, 1, u + 3);   // P8
    BARRIER(); MFMA16(1, 1);
    WAIT_VM4(); BARRIER();
  }

  // epilogue: C row = m0+wr*128+mi*16+lg*4+r, col = n0+wc*64+ni*16+lr
#pragma unroll
  for (int mi = 0; mi < 8; ++mi)
#pragma unroll
    for (int ni = 0; ni < 4; ++ni)
#pragma unroll
      for (int r = 0; r < 4; ++r) {
        int row = m0 + wr * 128 + mi * 16 + lg * 4 + r;
        int col = n0 + wc * 64 + ni * 16 + lr;
        size_t idx = (size_t)row * N + col;
        float v = acc[mi][ni][r];
        if (RES) v += res[idx];
        if constexpr (sizeof(OutT) == 2) C[idx] = f2bf(v);
        else                             C[idx] = v;
      }
#undef STAGE_A
#undef STAGE_B
#undef LDA4
#undef LDB2
#undef MFMA16
}

// ---------------- GEMM 256x256 8-phase, fused-SwiGLU epilogue --------------
// Separate function (NOT a new template arg on gemm256_kernel) to avoid
// perturbing the proven instantiations' codegen (rule #19 / R5 regression).
// out = silu(gate) * (A*Bt^T), bf16. gate: bf16 [M][N].
__global__ __launch_bounds__(512, 2) void gemm256_swiglu_kernel(
    const ushort* __restrict__ A, const ushort* __restrict__ Bt,
    ushort* __restrict__ C, const ushort* __restrict__ gate,
    int M, int N, int K) {
  extern __shared__ ushort lds[];
  ushort* Al = lds;
  ushort* Bl = lds + 32768;
  const int t = threadIdx.x, l = t & 63, w = t >> 6;
  const int wr = w >> 2, wc = w & 3;
  const int lr = l & 15, lg = l >> 4;
  const int rhi = lr >> 3, rlo = lr & 7;
  const int srow = l >> 3, sg = (l & 7) ^ srow;

  const int nby = M >> 8;
  const int nwg = (N >> 8) * nby;
  const int cpx = nwg >> 3;
  const int bid = (int)blockIdx.x;
  const int swz = (bid & 7) * cpx + (bid >> 3);
  const int m0 = (swz % nby) << 8;
  const int n0 = (swz / nby) << 8;

  const int lof0 = rhi * 512 + rlo * 64 + ((0 + lg) ^ rlo) * 8;
  const int lof1 = rhi * 512 + rlo * 64 + ((4 + lg) ^ rlo) * 8;

  const f32x4 fz = {0.f, 0.f, 0.f, 0.f};
  f32x4 acc[8][4];
#pragma unroll
  for (int i = 0; i < 8; ++i)
#pragma unroll
    for (int j = 0; j < 4; ++j) acc[i][j] = fz;
  bf16x8 a[8][2];
  bf16x8 bq[2][2];

  const ushort* Asrc = A + (size_t)(m0 + w * 8 + srow) * K + sg * 8;
  const ushort* Bsrc = Bt + (size_t)(n0 + w * 8 + srow) * K + sg * 8;
  const size_t rK64 = (size_t)64 * K, rK128 = (size_t)128 * K;
  ushort* Adst = Al + w * 512;
  ushort* Bdst = Bl + w * 512;

#define STAGE_A(buf, half, tile) do {                                   \
    const ushort* s_ = Asrc + (size_t)(half) * rK128 + ((tile) << 6);   \
    ushort* d_ = Adst + (buf) * 16384 + (half) * 8192;                  \
    gload16(s_, d_);                                                    \
    gload16(s_ + rK64, d_ + 4096);                                      \
  } while (0)
#define STAGE_B(buf, half, tile) do {                                   \
    const ushort* s_ = Bsrc + (size_t)(half) * rK128 + ((tile) << 6);   \
    ushort* d_ = Bdst + (buf) * 16384 + (half) * 8192;                  \
    gload16(s_, d_);                                                    \
    gload16(s_ + rK64, d_ + 4096);                                      \
  } while (0)
#define LDA4(AH, QM) do {                                                   \
    _Pragma("unroll") for (int mi_ = 0; mi_ < 4; ++mi_) {                   \
      a[(QM) * 4 + mi_][0] =                                                \
          *(const bf16x8*)((AH) + ((QM) * 4 + mi_) * 1024 + lof0);          \
      a[(QM) * 4 + mi_][1] =                                                \
          *(const bf16x8*)((AH) + ((QM) * 4 + mi_) * 1024 + lof1);          \
    } } while (0)
#define LDB2(BH, NQ) do {                                                   \
    _Pragma("unroll") for (int nj_ = 0; nj_ < 2; ++nj_) {                   \
      bq[nj_][0] = *(const bf16x8*)((BH) + ((NQ) * 2 + nj_) * 1024 + lof0); \
      bq[nj_][1] = *(const bf16x8*)((BH) + ((NQ) * 2 + nj_) * 1024 + lof1); \
    } } while (0)
#define MFMA16(QM, QN)                                                      \
    __builtin_amdgcn_s_setprio(1);                                          \
    _Pragma("unroll") for (int mi_ = 0; mi_ < 4; ++mi_)                     \
    _Pragma("unroll") for (int nj_ = 0; nj_ < 2; ++nj_) {                   \
      acc[(QM) * 4 + mi_][(QN) * 2 + nj_] =                                 \
          __builtin_amdgcn_mfma_f32_16x16x32_bf16(                          \
              a[(QM) * 4 + mi_][0], bq[nj_][0],                             \
              acc[(QM) * 4 + mi_][(QN) * 2 + nj_], 0, 0, 0);                \
      acc[(QM) * 4 + mi_][(QN) * 2 + nj_] =                                 \
          __builtin_amdgcn_mfma_f32_16x16x32_bf16(                          \
              a[(QM) * 4 + mi_][1], bq[nj_][1],                             \
              acc[(QM) * 4 + mi_][(QN) * 2 + nj_], 0, 0, 0);                \
    }                                                                       \
    __builtin_amdgcn_s_setprio(0);

  const ushort* A0h = Al + wr * 8192;
  const ushort* A1h = A0h + 16384;
  const ushort* B0h = Bl + (wc >> 1) * 8192 + (wc & 1) * 4096;
  const ushort* B1h = B0h + 16384;

  const int ntiles = K >> 6, nIter = K >> 7;
  STAGE_A(0, 0, 0); STAGE_A(0, 1, 0); STAGE_B(0, 0, 0); STAGE_B(0, 1, 0);
  STAGE_A(1, 0, 1); STAGE_A(1, 1, 1);
  WAIT_VM4(); BARRIER();

  for (int it = 0; it < nIter; ++it) {
    const int u = it * 2;
    LDA4(A0h, 0); LDB2(B0h, 0);
    STAGE_B(1, 0, u + 1);
    BARRIER(); WAIT_LGKM0(); MFMA16(0, 0); BARRIER();
    LDA4(A0h, 1);
    STAGE_B(1, 1, u + 1);
    BARRIER(); WAIT_LGKM0(); MFMA16(1, 0); BARRIER();
    LDB2(B0h, 1);
    if (u + 2 < ntiles) STAGE_A(0, 0, u + 2);
    BARRIER(); WAIT_LGKM0(); MFMA16(0, 1); BARRIER();
    if (u + 2 < ntiles) STAGE_A(0, 1, u + 2);
    BARRIER(); MFMA16(1, 1);
    if (u + 2 < ntiles) { WAIT_VM4(); } else { WAIT_VM0(); }
    BARRIER();
    LDA4(A1h, 0); LDB2(B1h, 0);
    if (u + 2 < ntiles) STAGE_B(0, 0, u + 2);
    BARRIER(); WAIT_LGKM0(); MFMA16(0, 0); BARRIER();
    LDA4(A1h, 1);
    if (u + 2 < ntiles) STAGE_B(0, 1, u + 2);
    BARRIER(); WAIT_LGKM0(); MFMA16(1, 0); BARRIER();
    LDB2(B1h, 1);
    if (u + 3 < ntiles) STAGE_A(1, 0, u + 3);
    BARRIER(); WAIT_LGKM0(); MFMA16(0, 1); BARRIER();
    if (u + 3 < ntiles) STAGE_A(1, 1, u + 3);
    BARRIER(); MFMA16(1, 1);
    WAIT_VM4(); BARRIER();
  }

  // fused epilogue: out = silu(gate) * acc
#pragma unroll
  for (int mi = 0; mi < 8; ++mi)
#pragma unroll
    for (int ni = 0; ni < 4; ++ni)
#pragma unroll
      for (int r = 0; r < 4; ++r) {
        int row = m0 + wr * 128 + mi * 16 + lg * 4 + r;
        int col = n0 + wc * 64 + ni * 16 + lr;
        size_t idx = (size_t)row * N + col;
        float g = bf2f(gate[idx]);
        float s = g / (1.f + __expf(-g));
        C[idx] = f2bf(s * acc[mi][ni][r]);
      }
#undef STAGE_A
#undef STAGE_B
#undef LDA4
#undef LDB2
#undef MFMA16
}

// ------------------------------ RoPE table ---------------------------------
__global__ void rope_table_kernel(const int* __restrict__ pos,
                                  float2* __restrict__ tab) {
  int idx = blockIdx.x * 256 + threadIdx.x;  // 2048*64
  int s = idx >> 6, fi = idx & 63;
  float inv = (float)exp(-(double)(2 * fi) / 128.0 * 9.210340371976184);
  float a = (float)pos[s] * inv;
  tab[idx] = make_float2(cosf(a), sinf(a));
}

// --------- RoPE + scatter qkv[T,6144] -> Qr[b,h,s,d] Kr[b,h,s,d] Vt[b,h,d,s]
__global__ __launch_bounds__(256) void rope_scatter_kernel(
    const ushort* __restrict__ qkv, const float2* __restrict__ tab,
    ushort* __restrict__ Qr, ushort* __restrict__ Kr, ushort* __restrict__ Vt) {
  __shared__ ushort vt[64][132];
  const int t = threadIdx.x, tt = blockIdx.x, h = blockIdx.y;  // h: 0..47
  const int row = t >> 2, c = (t & 3) * 16;
  const int tok = tt * 64 + row;
  const int b = tok >> 11, s = tok & 2047;
  const ushort* ip = qkv + (size_t)tok * 6144 + h * 128;
  union U { uint4 v; ushort us[8]; };
  U a0, a1, b0, b1;
  a0.v = *(const uint4*)(ip + c);      a1.v = *(const uint4*)(ip + c + 8);
  b0.v = *(const uint4*)(ip + c + 64); b1.v = *(const uint4*)(ip + c + 72);
  if (h < 40) {  // q or k head: NeoX rope on pairs (i, i+64)
    U o0, o1, o2, o3;
#pragma unroll
    for (int j = 0; j < 8; ++j) {
      float2 cs = tab[s * 64 + c + j];
      float x1 = bf2f(a0.us[j]), x2 = bf2f(b0.us[j]);
      o0.us[j] = f2bf(x1 * cs.x - x2 * cs.y);
      o2.us[j] = f2bf(x2 * cs.x + x1 * cs.y);
    }
#pragma unroll
    for (int j = 0; j < 8; ++j) {
      float2 cs = tab[s * 64 + c + 8 + j];
      float x1 = bf2f(a1.us[j]), x2 = bf2f(b1.us[j]);
      o1.us[j] = f2bf(x1 * cs.x - x2 * cs.y);
      o3.us[j] = f2bf(x2 * cs.x + x1 * cs.y);
    }
    ushort* base;
    if (h < 32) base = Qr + ((size_t)((b * 32 + h) * 2048 + s)) * 128;
    else        base = Kr + ((size_t)((b * 8 + (h - 32)) * 2048 + s)) * 128;
    *(uint4*)(base + c)      = o0.v; *(uint4*)(base + c + 8)  = o1.v;
    *(uint4*)(base + c + 64) = o2.v; *(uint4*)(base + c + 72) = o3.v;
  } else {  // v head: LDS transpose -> Vt[b,hv,d,s]
    const int hv = h - 40;
#pragma unroll
    for (int j = 0; j < 8; ++j) {
      vt[row][c + j]      = a0.us[j]; vt[row][c + 8 + j]  = a1.us[j];
      vt[row][c + 64 + j] = b0.us[j]; vt[row][c + 72 + j] = b1.us[j];
    }
    __syncthreads();
    const int d = t >> 1, s0 = (t & 1) * 32, sb = (tt & 31) * 64;
    U w0, w1, w2, w3;
#pragma unroll
    for (int j = 0; j < 8; ++j) {
      w0.us[j] = vt[s0 + j][d];      w1.us[j] = vt[s0 + 8 + j][d];
      w2.us[j] = vt[s0 + 16 + j][d]; w3.us[j] = vt[s0 + 24 + j][d];
    }
    ushort* vb = Vt + ((size_t)((b * 8 + hv) * 128 + d)) * 2048 + sb + s0;
    *(uint4*)(vb) = w0.v;      *(uint4*)(vb + 8) = w1.v;
    *(uint4*)(vb + 16) = w2.v; *(uint4*)(vb + 24) = w3.v;
  }
}

// --------------------------- flash attention -------------------------------
// QBLK=128, 8 waves, KVBLK=64; XOR-swizzled K/V/P LDS, K/V dbuf vmcnt(4),
// log2 softmax, MFMA row-sum, defer-max THR=8, wave-uniform mask.
__global__ __launch_bounds__(512) void attn_kernel(
    const ushort* __restrict__ Q, const ushort* __restrict__ K,
    const ushort* __restrict__ V, ushort* __restrict__ O) {
  extern __shared__ ushort sm[];
  ushort* Kl = sm;           // [2][64 s][128 d]
  ushort* Vl = sm + 16384;   // [2][128 d][64 s]
  ushort* Pl = sm + 32768;   // [128][64]
  const int t = threadIdx.x, l = t & 63, w = t >> 6;   // w: 0..7
  const int lr = l & 15, lg = l >> 4;
  const int qb = blockIdx.x, h = blockIdx.y, b = blockIdx.z;
  const int hkv = h >> 2;
  const f32x4 fzero = {0.f, 0.f, 0.f, 0.f};

  const int rm = lr & 7;
  int ksw[4], vsw[2];
#pragma unroll
  for (int ks = 0; ks < 4; ++ks) ksw[ks] = ((ks * 4 + lg) ^ rm) * 8;
  vsw[0] = (lg ^ rm) * 8;
  vsw[1] = ((4 + lg) ^ rm) * 8;
  const int kcol = ((t & 15) ^ ((t >> 4) & 7)) * 8;   // staging src swizzle
  const int vcol = ((t & 7) ^ ((t >> 3) & 7)) * 8;

  const float qscale = 0.08838834764831845f * 1.4426950408889634f;
  const ushort* qp =
      Q + ((size_t)((b * 32 + h) * 2048 + qb * 128 + w * 16 + lr)) * 128 + lg * 8;
  bf16x8 qf[4];
#pragma unroll
  for (int ks = 0; ks < 4; ++ks) {
    bf16x8 raw = *(const bf16x8*)(qp + ks * 32);
#pragma unroll
    for (int j = 0; j < 8; ++j)
      qf[ks][j] = (short)f2bf(bf2f((ushort)raw[j]) * qscale);
  }
  bf16x8 ones;
#pragma unroll
  for (int j = 0; j < 8; ++j) ones[j] = (short)0x3F80;
  WAIT_VM0();

  const ushort* kg = K + ((size_t)(b * 8 + hkv)) * 2048 * 128;
  const ushort* vg = V + ((size_t)(b * 8 + hkv)) * 128 * 2048;

#define STAGE_KV(buf, s0_) do {                                              \
    _Pragma("unroll") for (int i_ = 0; i_ < 2; ++i_)                         \
      gload16(kg + (size_t)((s0_) + i_ * 32 + (t >> 4)) * 128 + kcol,        \
              (char*)Kl + (buf) * 16384 + i_ * 8192 + t * 16);               \
    _Pragma("unroll") for (int i_ = 0; i_ < 2; ++i_)                         \
      gload16(vg + (size_t)(i_ * 64 + (t >> 3)) * 2048 + (s0_) + vcol,       \
              (char*)Vl + (buf) * 16384 + i_ * 8192 + t * 16);               \
  } while (0)

  f32x4 accO[8];
#pragma unroll
  for (int i = 0; i < 8; ++i) accO[i] = fzero;
  float m_r[4] = {-1e30f, -1e30f, -1e30f, -1e30f};
  float l_r[4] = {0.f, 0.f, 0.f, 0.f};
  const int qrow = qb * 128 + w * 16 + lg * 4;
  const int wrow0 = qb * 128 + w * 16;
  const int jend = 2 * qb + 1;

  STAGE_KV(0, 0);
  for (int j = 0; j <= jend; ++j) {
    if (j < jend) { STAGE_KV((j + 1) & 1, (j + 1) * 64); WAIT_VM4(); }
    else          { WAIT_VM0(); }
    BARRIER();
    const ushort* Kb = Kl + (j & 1) * 8192;
    const ushort* Vb = Vl + (j & 1) * 8192;

    f32x4 sc[4];
#pragma unroll
    for (int ni = 0; ni < 4; ++ni) sc[ni] = fzero;
    __builtin_amdgcn_s_setprio(1);
#pragma unroll
    for (int ni = 0; ni < 4; ++ni)
#pragma unroll
      for (int ks = 0; ks < 4; ++ks) {
        bf16x8 kf = *(const bf16x8*)(Kb + (ni * 16 + lr) * 128 + ksw[ks]);
        sc[ni] = __builtin_amdgcn_mfma_f32_16x16x32_bf16(qf[ks], kf, sc[ni], 0, 0, 0);
      }
    __builtin_amdgcn_s_setprio(0);
    if (j * 64 + 63 > wrow0) {
#pragma unroll
      for (int ni = 0; ni < 4; ++ni)
#pragma unroll
        for (int r = 0; r < 4; ++r)
          if (j * 64 + ni * 16 + lr > qrow + r) sc[ni][r] = -1e30f;
    }
    float mx[4];
#pragma unroll
    for (int r = 0; r < 4; ++r) {
      float v = fmaxf(fmaxf(sc[0][r], sc[1][r]), fmaxf(sc[2][r], sc[3][r]));
#pragma unroll
      for (int m = 8; m; m >>= 1) v = fmaxf(v, __shfl_xor(v, m));
      mx[r] = v;
    }
    bool ok = mx[0] <= m_r[0] + 8.f && mx[1] <= m_r[1] + 8.f &&
              mx[2] <= m_r[2] + 8.f && mx[3] <= m_r[3] + 8.f;
    if (!__all(ok)) {
#pragma unroll
      for (int r = 0; r < 4; ++r) {
        float mnew = fmaxf(m_r[r], mx[r]);
        float fsc = exp2f(m_r[r] - mnew);
        l_r[r] *= fsc;
        m_r[r] = mnew;
#pragma unroll
        for (int i = 0; i < 8; ++i) accO[i][r] *= fsc;
      }
    }
#pragma unroll
    for (int ni = 0; ni < 4; ++ni)
#pragma unroll
      for (int r = 0; r < 4; ++r) {
        int prow = w * 16 + lg * 4 + r;
        int slot = (ni * 2 + (lr >> 3)) ^ (prow & 7);
        Pl[prow * 64 + slot * 8 + rm] = f2bf(exp2f(sc[ni][r] - m_r[r]));
      }
    WAIT_LGKM0();
    f32x4 accL = fzero;
    __builtin_amdgcn_s_setprio(1);
#pragma unroll
    for (int ks = 0; ks < 2; ++ks) {
      bf16x8 pf = *(const bf16x8*)(Pl + (w * 16 + lr) * 64 + vsw[ks]);
#pragma unroll
      for (int nf = 0; nf < 8; ++nf) {
        bf16x8 vf = *(const bf16x8*)(Vb + (nf * 16 + lr) * 64 + vsw[ks]);
        accO[nf] = __builtin_amdgcn_mfma_f32_16x16x32_bf16(pf, vf, accO[nf], 0, 0, 0);
      }
      accL = __builtin_amdgcn_mfma_f32_16x16x32_bf16(pf, ones, accL, 0, 0, 0);
    }
    __builtin_amdgcn_s_setprio(0);
#pragma unroll
    for (int r = 0; r < 4; ++r) l_r[r] += accL[r];
    BARRIER();
  }
#undef STAGE_KV
  float invl[4];
#pragma unroll
  for (int r = 0; r < 4; ++r) invl[r] = 1.f / l_r[r];
#pragma unroll
  for (int nf = 0; nf < 8; ++nf)
#pragma unroll
    for (int r = 0; r < 4; ++r) {
      int q = qb * 128 + w * 16 + lg * 4 + r;
      int d = nf * 16 + lr;
      O[((size_t)(b * 2048 + q)) * 4096 + h * 128 + d] = f2bf(accO[nf][r] * invl[r]);
    }
}

// ------------------------------ launcher -----------------------------------
#define OFF_W    ((size_t)0)
#define OFF_H1   ((size_t)90177536)
#define OFF_XN   ((size_t)157286400)
#define OFF_QKV  ((size_t)190840832)
#define OFF_TAB  ((size_t)241172480)
#define OFF_QR   ((size_t)242221056)
#define OFF_KR   ((size_t)275775488)
#define OFF_VT   ((size_t)284164096)
#define OFF_ATTN ((size_t)292552704)
#define OFF_GATE OFF_QKV
#define OFF_UP   ((size_t)326107136)
#define WS_NEED  ((size_t)416284672)

extern "C" void kernel_launch(void* const* d_in, const int* in_sizes, int n_in,
                              void* d_out, int out_size, void* d_ws,
                              size_t ws_size, hipStream_t stream) {
  (void)in_sizes; (void)n_in; (void)out_size;
  if (ws_size < WS_NEED) return;
  const float* hs     = (const float*)d_in[0];
  const int*   pos    = (const int*)d_in[1];
  const float* w_qkv  = (const float*)d_in[2];
  const float* w_o    = (const float*)d_in[3];
  const float* w_gu   = (const float*)d_in[4];
  const float* w_down = (const float*)d_in[5];
  const float* ln1    = (const float*)d_in[6];
  const float* ln2    = (const float*)d_in[7];
  float* out = (float*)d_out;
  char* ws = (char*)d_ws;

  ushort* W    = (ushort*)(ws + OFF_W);
  float*  h1   = (float*)(ws + OFF_H1);
  ushort* xn   = (ushort*)(ws + OFF_XN);
  ushort* qkv  = (ushort*)(ws + OFF_QKV);
  float2* tab  = (float2*)(ws + OFF_TAB);
  ushort* Qr   = (ushort*)(ws + OFF_QR);
  ushort* Kr   = (ushort*)(ws + OFF_KR);
  ushort* Vt   = (ushort*)(ws + OFF_VT);
  ushort* attn = (ushort*)(ws + OFF_ATTN);
  ushort* gate = (ushort*)(ws + OFF_GATE);
  ushort* act  = (ushort*)(ws + OFF_UP);

  auto kb = gemm256_kernel<ushort, false>;
  auto kf = gemm256_kernel<float, true>;
  hipFuncSetAttribute((const void*)kb, hipFuncAttributeMaxDynamicSharedMemorySize, 131072);
  hipFuncSetAttribute((const void*)kf, hipFuncAttributeMaxDynamicSharedMemorySize, 131072);
  hipFuncSetAttribute((const void*)gemm256_swiglu_kernel, hipFuncAttributeMaxDynamicSharedMemorySize, 131072);
  hipFuncSetAttribute((const void*)attn_kernel, hipFuncAttributeMaxDynamicSharedMemorySize, 81920);

  // --- attention block ---
  rmsnorm_kernel<<<4096, 256, 0, stream>>>(hs, ln1, xn);
  transpose_cast_kernel<<<dim3(64, 96), 256, 0, stream>>>(w_qkv, W, 6144, 0, 4096);
  gemm256_kernel<ushort, false><<<384, 512, 131072, stream>>>(
      xn, W, qkv, nullptr, 4096, 6144, 4096);
  rope_table_kernel<<<512, 256, 0, stream>>>(pos, tab);
  rope_scatter_kernel<<<dim3(64, 48), 256, 0, stream>>>(qkv, tab, Qr, Kr, Vt);
  attn_kernel<<<dim3(16, 32, 2), 512, 81920, stream>>>(Qr, Kr, Vt, attn);
  transpose_cast_kernel<<<dim3(64, 64), 256, 0, stream>>>(w_o, W, 4096, 0, 4096);
  gemm256_kernel<float, true><<<256, 512, 131072, stream>>>(
      attn, W, h1, hs, 4096, 4096, 4096);

  // --- MLP block ---
  rmsnorm_kernel<<<4096, 256, 0, stream>>>(h1, ln2, xn);
  transpose_cast_kernel<<<dim3(64, 172), 256, 0, stream>>>(w_gu, W, 22016, 0, 4096);
  gemm256_kernel<ushort, false><<<688, 512, 131072, stream>>>(
      xn, W, gate, nullptr, 4096, 11008, 4096);
  transpose_cast_kernel<<<dim3(64, 172), 256, 0, stream>>>(w_gu, W, 22016, 11008, 4096);
  gemm256_swiglu_kernel<<<688, 512, 131072, stream>>>(
      xn, W, act, gate, 4096, 11008, 4096);
  transpose_cast_kernel<<<dim3(172, 64), 256, 0, stream>>>(w_down, W, 4096, 0, 11008);
  gemm256_kernel<float, true><<<256, 512, 131072, stream>>>(
      act, W, out, h1, 4096, 4096, 11008);
}

// Round 13
// 1748.206 us; speedup vs baseline: 1.1242x; 1.0225x over previous
//
#include <hip/hip_runtime.h>

// ---------------------------------------------------------------------------
// Llama decoder layer, MI355X (gfx950).
// B=2 S=2048 HIDDEN=4096 HQ=32 HKV=8 D=128 INTER=11008, fp32 in/out.
// R13: hide weight transposes under attention. attn_tc = verbatim R12 attn
// (flattened grid) + trailing 512-thread transpose blocks for w_gu p1 -> W3,
// w_gu p2 -> W4, w_o -> W2 (attn is latency-bound at 3% HBM BW; transposes
// fill its idle slots / causal-imbalance tail). GEMM/swiglu/transpose kernels
// byte-identical to R12 (rule #19 A/B: gate/up/down must stay 350/389/350).
// Workspace repacked with lifetime-checked overlays; h1 lives in d_out
// (down-GEMM reads res[idx] then writes out[idx] -- same-index in-place,
// race-free, fully rewritten each replay -> deterministic).
// ---------------------------------------------------------------------------

typedef __attribute__((ext_vector_type(8))) short bf16x8;
typedef __attribute__((ext_vector_type(4))) float f32x4;

__device__ __forceinline__ ushort f2bf(float f) {           // RNE fp32->bf16
  unsigned u = __float_as_uint(f);
  return (ushort)((u + 0x7fffu + ((u >> 16) & 1u)) >> 16);
}
__device__ __forceinline__ float bf2f(ushort u) {
  union { unsigned u32; float f; } x; x.u32 = ((unsigned)u) << 16; return x.f;
}
__device__ __forceinline__ void gload16(const void* g, void* l) {
  __builtin_amdgcn_global_load_lds((__attribute__((address_space(1))) void*)g,
                                   (__attribute__((address_space(3))) void*)l,
                                   16, 0, 0);
}

#define BARRIER() asm volatile("s_barrier" ::: "memory")
#define WAIT_LGKM0() asm volatile("s_waitcnt lgkmcnt(0)" ::: "memory")
#define WAIT_VM4() asm volatile("s_waitcnt vmcnt(4)" ::: "memory")
#define WAIT_VM0() asm volatile("s_waitcnt vmcnt(0)" ::: "memory")

// --------------------------- RMSNorm (fp32 -> bf16) ------------------------
__global__ __launch_bounds__(256) void rmsnorm_kernel(
    const float* __restrict__ x, const float* __restrict__ g,
    ushort* __restrict__ out) {
  const int row = blockIdx.x, t = threadIdx.x;
  const float4* xp = (const float4*)(x + (size_t)row * 4096);
  float4 v[4]; float ss = 0.f;
#pragma unroll
  for (int i = 0; i < 4; ++i) {
    v[i] = xp[t + i * 256];
    ss += v[i].x * v[i].x + v[i].y * v[i].y + v[i].z * v[i].z + v[i].w * v[i].w;
  }
#pragma unroll
  for (int m = 32; m; m >>= 1) ss += __shfl_xor(ss, m);
  __shared__ float red[4];
  if ((t & 63) == 0) red[t >> 6] = ss;
  __syncthreads();
  float inv = rsqrtf((red[0] + red[1] + red[2] + red[3]) * (1.f / 4096.f) + 1e-6f);
  const float4* gp = (const float4*)g;
  ushort* op = out + (size_t)row * 4096;
#pragma unroll
  for (int i = 0; i < 4; ++i) {
    float4 gv = gp[t + i * 256];
    ushort4 o;
    o.x = f2bf(v[i].x * inv * gv.x); o.y = f2bf(v[i].y * inv * gv.y);
    o.z = f2bf(v[i].z * inv * gv.z); o.w = f2bf(v[i].w * inv * gv.w);
    *(ushort4*)(op + (size_t)(t + i * 256) * 4) = o;
  }
}

// ----------------- transpose + cast fp32 [R][ld_in] -> bf16 [C][R] ---------
__global__ __launch_bounds__(256) void transpose_cast_kernel(
    const float* __restrict__ in, ushort* __restrict__ out,
    int ld_in, int col_off, int R) {
  __shared__ ushort tile[64][65];
  const int t = threadIdx.x;
  const int r0 = blockIdx.x * 64, c0 = blockIdx.y * 64;
  const int rl = t >> 2, cl = (t & 3) * 16;
  const float* ip = in + (size_t)(r0 + rl) * ld_in + col_off + c0 + cl;
#pragma unroll
  for (int i = 0; i < 4; ++i) {
    float4 f = ((const float4*)ip)[i];
    tile[rl][cl + i * 4 + 0] = f2bf(f.x);
    tile[rl][cl + i * 4 + 1] = f2bf(f.y);
    tile[rl][cl + i * 4 + 2] = f2bf(f.z);
    tile[rl][cl + i * 4 + 3] = f2bf(f.w);
  }
  __syncthreads();
  union { ushort us[8]; uint4 v; } pk0, pk1;
#pragma unroll
  for (int j = 0; j < 8; ++j) pk0.us[j] = tile[cl + j][rl];
#pragma unroll
  for (int j = 0; j < 8; ++j) pk1.us[j] = tile[cl + 8 + j][rl];
  uint4* op = (uint4*)(out + (size_t)(c0 + rl) * R + r0 + cl);
  op[0] = pk0.v; op[1] = pk1.v;
}

// ------- 512-thread transpose helper (2 x 64x64 tiles per block) -----------
// half = t>>8 handles col-tile (yy*2 + half); same 65-pad algorithm.
__device__ __forceinline__ void transpose512(
    const float* __restrict__ in, ushort* __restrict__ out,
    int ld_in, int col_off, int R, int ntx, int tbid, ushort* ldsb, int t) {
  const int half = t >> 8, tt = t & 255;
  ushort* tile = ldsb + half * (64 * 65);
  const int x = tbid % ntx, yy = tbid / ntx;
  const int r0 = x * 64, c0 = (yy * 2 + half) * 64;
  const int rl = tt >> 2, cl = (tt & 3) * 16;
  const float* ip = in + (size_t)(r0 + rl) * ld_in + col_off + c0 + cl;
#pragma unroll
  for (int i = 0; i < 4; ++i) {
    float4 f = ((const float4*)ip)[i];
    tile[rl * 65 + cl + i * 4 + 0] = f2bf(f.x);
    tile[rl * 65 + cl + i * 4 + 1] = f2bf(f.y);
    tile[rl * 65 + cl + i * 4 + 2] = f2bf(f.z);
    tile[rl * 65 + cl + i * 4 + 3] = f2bf(f.w);
  }
  __syncthreads();
  union { ushort us[8]; uint4 v; } pk0, pk1;
#pragma unroll
  for (int j = 0; j < 8; ++j) pk0.us[j] = tile[(cl + j) * 65 + rl];
#pragma unroll
  for (int j = 0; j < 8; ++j) pk1.us[j] = tile[(cl + 8 + j) * 65 + rl];
  uint4* op = (uint4*)(out + (size_t)(c0 + rl) * R + r0 + cl);
  op[0] = pk0.v; op[1] = pk1.v;
}

// ------------------------- GEMM 256x256 8-phase ----------------------------
// Byte-identical to R8..R12 (R4 body + col-major XCD chunk mapping).
template <typename OutT, bool RES>
__global__ __launch_bounds__(512, 2) void gemm256_kernel(
    const ushort* __restrict__ A, const ushort* __restrict__ Bt,
    OutT* __restrict__ C, const float* __restrict__ res,
    int M, int N, int K) {
  extern __shared__ ushort lds[];
  ushort* Al = lds;            // [buf:2][half:2][8192 ushorts]
  ushort* Bl = lds + 32768;
  const int t = threadIdx.x, l = t & 63, w = t >> 6;
  const int wr = w >> 2, wc = w & 3;
  const int lr = l & 15, lg = l >> 4;
  const int rhi = lr >> 3, rlo = lr & 7;
  const int srow = l >> 3, sg = (l & 7) ^ srow;

  const int nby = M >> 8;
  const int nwg = (N >> 8) * nby;
  const int cpx = nwg >> 3;
  const int bid = (int)blockIdx.x;
  const int swz = (bid & 7) * cpx + (bid >> 3);   // XCD chunk (nwg%8==0)
  const int m0 = (swz % nby) << 8;                // col-major: B panel shared
  const int n0 = (swz / nby) << 8;                // by 16 consecutive blocks

  const int lof0 = rhi * 512 + rlo * 64 + ((0 + lg) ^ rlo) * 8;  // kk=0
  const int lof1 = rhi * 512 + rlo * 64 + ((4 + lg) ^ rlo) * 8;  // kk=1

  const f32x4 fz = {0.f, 0.f, 0.f, 0.f};
  f32x4 acc[8][4];
#pragma unroll
  for (int i = 0; i < 8; ++i)
#pragma unroll
    for (int j = 0; j < 4; ++j) acc[i][j] = fz;
  bf16x8 a[8][2];
  bf16x8 bq[2][2];

  const ushort* Asrc = A + (size_t)(m0 + w * 8 + srow) * K + sg * 8;
  const ushort* Bsrc = Bt + (size_t)(n0 + w * 8 + srow) * K + sg * 8;
  const size_t rK64 = (size_t)64 * K, rK128 = (size_t)128 * K;
  ushort* Adst = Al + w * 512;
  ushort* Bdst = Bl + w * 512;

#define STAGE_A(buf, half, tile) do {                                   \
    const ushort* s_ = Asrc + (size_t)(half) * rK128 + ((tile) << 6);   \
    ushort* d_ = Adst + (buf) * 16384 + (half) * 8192;                  \
    gload16(s_, d_);                                                    \
    gload16(s_ + rK64, d_ + 4096);                                      \
  } while (0)
#define STAGE_B(buf, half, tile) do {                                   \
    const ushort* s_ = Bsrc + (size_t)(half) * rK128 + ((tile) << 6);   \
    ushort* d_ = Bdst + (buf) * 16384 + (half) * 8192;                  \
    gload16(s_, d_);                                                    \
    gload16(s_ + rK64, d_ + 4096);                                      \
  } while (0)
#define LDA4(AH, QM) do {                                                   \
    _Pragma("unroll") for (int mi_ = 0; mi_ < 4; ++mi_) {                   \
      a[(QM) * 4 + mi_][0] =                                                \
          *(const bf16x8*)((AH) + ((QM) * 4 + mi_) * 1024 + lof0);          \
      a[(QM) * 4 + mi_][1] =                                                \
          *(const bf16x8*)((AH) + ((QM) * 4 + mi_) * 1024 + lof1);          \
    } } while (0)
#define LDB2(BH, NQ) do {                                                   \
    _Pragma("unroll") for (int nj_ = 0; nj_ < 2; ++nj_) {                   \
      bq[nj_][0] = *(const bf16x8*)((BH) + ((NQ) * 2 + nj_) * 1024 + lof0); \
      bq[nj_][1] = *(const bf16x8*)((BH) + ((NQ) * 2 + nj_) * 1024 + lof1); \
    } } while (0)
#define MFMA16(QM, QN)                                                      \
    __builtin_amdgcn_s_setprio(1);                                          \
    _Pragma("unroll") for (int mi_ = 0; mi_ < 4; ++mi_)                     \
    _Pragma("unroll") for (int nj_ = 0; nj_ < 2; ++nj_) {                   \
      acc[(QM) * 4 + mi_][(QN) * 2 + nj_] =                                 \
          __builtin_amdgcn_mfma_f32_16x16x32_bf16(                          \
              a[(QM) * 4 + mi_][0], bq[nj_][0],                             \
              acc[(QM) * 4 + mi_][(QN) * 2 + nj_], 0, 0, 0);                \
      acc[(QM) * 4 + mi_][(QN) * 2 + nj_] =                                 \
          __builtin_amdgcn_mfma_f32_16x16x32_bf16(                          \
              a[(QM) * 4 + mi_][1], bq[nj_][1],                             \
              acc[(QM) * 4 + mi_][(QN) * 2 + nj_], 0, 0, 0);                \
    }                                                                       \
    __builtin_amdgcn_s_setprio(0);

  const ushort* A0h = Al + wr * 8192;
  const ushort* A1h = A0h + 16384;
  const ushort* B0h = Bl + (wc >> 1) * 8192 + (wc & 1) * 4096;
  const ushort* B1h = B0h + 16384;

  const int ntiles = K >> 6, nIter = K >> 7;
  // prologue: tile0 full -> buf0; tile1 A halves -> buf1
  STAGE_A(0, 0, 0); STAGE_A(0, 1, 0); STAGE_B(0, 0, 0); STAGE_B(0, 1, 0);
  STAGE_A(1, 0, 1); STAGE_A(1, 1, 1);
  WAIT_VM4(); BARRIER();

  for (int it = 0; it < nIter; ++it) {
    const int u = it * 2;
    // ---- tile u (buf0) ----
    LDA4(A0h, 0); LDB2(B0h, 0);                 // P1
    STAGE_B(1, 0, u + 1);
    BARRIER(); WAIT_LGKM0(); MFMA16(0, 0); BARRIER();
    LDA4(A0h, 1);                               // P2
    STAGE_B(1, 1, u + 1);
    BARRIER(); WAIT_LGKM0(); MFMA16(1, 0); BARRIER();
    LDB2(B0h, 1);                               // P3
    if (u + 2 < ntiles) STAGE_A(0, 0, u + 2);
    BARRIER(); WAIT_LGKM0(); MFMA16(0, 1); BARRIER();
    if (u + 2 < ntiles) STAGE_A(0, 1, u + 2);   // P4
    BARRIER(); MFMA16(1, 1);
    if (u + 2 < ntiles) { WAIT_VM4(); } else { WAIT_VM0(); }
    BARRIER();
    // ---- tile u+1 (buf1) ----
    LDA4(A1h, 0); LDB2(B1h, 0);                 // P5
    if (u + 2 < ntiles) STAGE_B(0, 0, u + 2);
    BARRIER(); WAIT_LGKM0(); MFMA16(0, 0); BARRIER();
    LDA4(A1h, 1);                               // P6
    if (u + 2 < ntiles) STAGE_B(0, 1, u + 2);
    BARRIER(); WAIT_LGKM0(); MFMA16(1, 0); BARRIER();
    LDB2(B1h, 1);                               // P7
    if (u + 3 < ntiles) STAGE_A(1, 0, u + 3);
    BARRIER(); WAIT_LGKM0(); MFMA16(0, 1); BARRIER();
    if (u + 3 < ntiles) STAGE_A(1, 1, u + 3);   // P8
    BARRIER(); MFMA16(1, 1);
    WAIT_VM4(); BARRIER();
  }

  // epilogue: C row = m0+wr*128+mi*16+lg*4+r, col = n0+wc*64+ni*16+lr
#pragma unroll
  for (int mi = 0; mi < 8; ++mi)
#pragma unroll
    for (int ni = 0; ni < 4; ++ni)
#pragma unroll
      for (int r = 0; r < 4; ++r) {
        int row = m0 + wr * 128 + mi * 16 + lg * 4 + r;
        int col = n0 + wc * 64 + ni * 16 + lr;
        size_t idx = (size_t)row * N + col;
        float v = acc[mi][ni][r];
        if (RES) v += res[idx];
        if constexpr (sizeof(OutT) == 2) C[idx] = f2bf(v);
        else                             C[idx] = v;
      }
#undef STAGE_A
#undef STAGE_B
#undef LDA4
#undef LDB2
#undef MFMA16
}

// ---------------- GEMM 256x256 8-phase, fused-SwiGLU epilogue --------------
// Byte-identical to R12. out = silu(gate) * (A*Bt^T), bf16.
__global__ __launch_bounds__(512, 2) void gemm256_swiglu_kernel(
    const ushort* __restrict__ A, const ushort* __restrict__ Bt,
    ushort* __restrict__ C, const ushort* __restrict__ gate,
    int M, int N, int K) {
  extern __shared__ ushort lds[];
  ushort* Al = lds;
  ushort* Bl = lds + 32768;
  const int t = threadIdx.x, l = t & 63, w = t >> 6;
  const int wr = w >> 2, wc = w & 3;
  const int lr = l & 15, lg = l >> 4;
  const int rhi = lr >> 3, rlo = lr & 7;
  const int srow = l >> 3, sg = (l & 7) ^ srow;

  const int nby = M >> 8;
  const int nwg = (N >> 8) * nby;
  const int cpx = nwg >> 3;
  const int bid = (int)blockIdx.x;
  const int swz = (bid & 7) * cpx + (bid >> 3);
  const int m0 = (swz % nby) << 8;
  const int n0 = (swz / nby) << 8;

  const int lof0 = rhi * 512 + rlo * 64 + ((0 + lg) ^ rlo) * 8;
  const int lof1 = rhi * 512 + rlo * 64 + ((4 + lg) ^ rlo) * 8;

  const f32x4 fz = {0.f, 0.f, 0.f, 0.f};
  f32x4 acc[8][4];
#pragma unroll
  for (int i = 0; i < 8; ++i)
#pragma unroll
    for (int j = 0; j < 4; ++j) acc[i][j] = fz;
  bf16x8 a[8][2];
  bf16x8 bq[2][2];

  const ushort* Asrc = A + (size_t)(m0 + w * 8 + srow) * K + sg * 8;
  const ushort* Bsrc = Bt + (size_t)(n0 + w * 8 + srow) * K + sg * 8;
  const size_t rK64 = (size_t)64 * K, rK128 = (size_t)128 * K;
  ushort* Adst = Al + w * 512;
  ushort* Bdst = Bl + w * 512;

#define STAGE_A(buf, half, tile) do {                                   \
    const ushort* s_ = Asrc + (size_t)(half) * rK128 + ((tile) << 6);   \
    ushort* d_ = Adst + (buf) * 16384 + (half) * 8192;                  \
    gload16(s_, d_);                                                    \
    gload16(s_ + rK64, d_ + 4096);                                      \
  } while (0)
#define STAGE_B(buf, half, tile) do {                                   \
    const ushort* s_ = Bsrc + (size_t)(half) * rK128 + ((tile) << 6);   \
    ushort* d_ = Bdst + (buf) * 16384 + (half) * 8192;                  \
    gload16(s_, d_);                                                    \
    gload16(s_ + rK64, d_ + 4096);                                      \
  } while (0)
#define LDA4(AH, QM) do {                                                   \
    _Pragma("unroll") for (int mi_ = 0; mi_ < 4; ++mi_) {                   \
      a[(QM) * 4 + mi_][0] =                                                \
          *(const bf16x8*)((AH) + ((QM) * 4 + mi_) * 1024 + lof0);          \
      a[(QM) * 4 + mi_][1] =                                                \
          *(const bf16x8*)((AH) + ((QM) * 4 + mi_) * 1024 + lof1);          \
    } } while (0)
#define LDB2(BH, NQ) do {                                                   \
    _Pragma("unroll") for (int nj_ = 0; nj_ < 2; ++nj_) {                   \
      bq[nj_][0] = *(const bf16x8*)((BH) + ((NQ) * 2 + nj_) * 1024 + lof0); \
      bq[nj_][1] = *(const bf16x8*)((BH) + ((NQ) * 2 + nj_) * 1024 + lof1); \
    } } while (0)
#define MFMA16(QM, QN)                                                      \
    __builtin_amdgcn_s_setprio(1);                                          \
    _Pragma("unroll") for (int mi_ = 0; mi_ < 4; ++mi_)                     \
    _Pragma("unroll") for (int nj_ = 0; nj_ < 2; ++nj_) {                   \
      acc[(QM) * 4 + mi_][(QN) * 2 + nj_] =                                 \
          __builtin_amdgcn_mfma_f32_16x16x32_bf16(                          \
              a[(QM) * 4 + mi_][0], bq[nj_][0],                             \
              acc[(QM) * 4 + mi_][(QN) * 2 + nj_], 0, 0, 0);                \
      acc[(QM) * 4 + mi_][(QN) * 2 + nj_] =                                 \
          __builtin_amdgcn_mfma_f32_16x16x32_bf16(                          \
              a[(QM) * 4 + mi_][1], bq[nj_][1],                             \
              acc[(QM) * 4 + mi_][(QN) * 2 + nj_], 0, 0, 0);                \
    }                                                                       \
    __builtin_amdgcn_s_setprio(0);

  const ushort* A0h = Al + wr * 8192;
  const ushort* A1h = A0h + 16384;
  const ushort* B0h = Bl + (wc >> 1) * 8192 + (wc & 1) * 4096;
  const ushort* B1h = B0h + 16384;

  const int ntiles = K >> 6, nIter = K >> 7;
  STAGE_A(0, 0, 0); STAGE_A(0, 1, 0); STAGE_B(0, 0, 0); STAGE_B(0, 1, 0);
  STAGE_A(1, 0, 1); STAGE_A(1, 1, 1);
  WAIT_VM4(); BARRIER();

  for (int it = 0; it < nIter; ++it) {
    const int u = it * 2;
    LDA4(A0h, 0); LDB2(B0h, 0);
    STAGE_B(1, 0, u + 1);
    BARRIER(); WAIT_LGKM0(); MFMA16(0, 0); BARRIER();
    LDA4(A0h, 1);
    STAGE_B(1, 1, u + 1);
    BARRIER(); WAIT_LGKM0(); MFMA16(1, 0); BARRIER();
    LDB2(B0h, 1);
    if (u + 2 < ntiles) STAGE_A(0, 0, u + 2);
    BARRIER(); WAIT_LGKM0(); MFMA16(0, 1); BARRIER();
    if (u + 2 < ntiles) STAGE_A(0, 1, u + 2);
    BARRIER(); MFMA16(1, 1);
    if (u + 2 < ntiles) { WAIT_VM4(); } else { WAIT_VM0(); }
    BARRIER();
    LDA4(A1h, 0); LDB2(B1h, 0);
    if (u + 2 < ntiles) STAGE_B(0, 0, u + 2);
    BARRIER(); WAIT_LGKM0(); MFMA16(0, 0); BARRIER();
    LDA4(A1h, 1);
    if (u + 2 < ntiles) STAGE_B(0, 1, u + 2);
    BARRIER(); WAIT_LGKM0(); MFMA16(1, 0); BARRIER();
    LDB2(B1h, 1);
    if (u + 3 < ntiles) STAGE_A(1, 0, u + 3);
    BARRIER(); WAIT_LGKM0(); MFMA16(0, 1); BARRIER();
    if (u + 3 < ntiles) STAGE_A(1, 1, u + 3);
    BARRIER(); MFMA16(1, 1);
    WAIT_VM4(); BARRIER();
  }

  // fused epilogue: out = silu(gate) * acc
#pragma unroll
  for (int mi = 0; mi < 8; ++mi)
#pragma unroll
    for (int ni = 0; ni < 4; ++ni)
#pragma unroll
      for (int r = 0; r < 4; ++r) {
        int row = m0 + wr * 128 + mi * 16 + lg * 4 + r;
        int col = n0 + wc * 64 + ni * 16 + lr;
        size_t idx = (size_t)row * N + col;
        float g = bf2f(gate[idx]);
        float s = g / (1.f + __expf(-g));
        C[idx] = f2bf(s * acc[mi][ni][r]);
      }
#undef STAGE_A
#undef STAGE_B
#undef LDA4
#undef LDB2
#undef MFMA16
}

// ------------------------------ RoPE table ---------------------------------
__global__ void rope_table_kernel(const int* __restrict__ pos,
                                  float2* __restrict__ tab) {
  int idx = blockIdx.x * 256 + threadIdx.x;  // 2048*64
  int s = idx >> 6, fi = idx & 63;
  float inv = (float)exp(-(double)(2 * fi) / 128.0 * 9.210340371976184);
  float a = (float)pos[s] * inv;
  tab[idx] = make_float2(cosf(a), sinf(a));
}

// --------- RoPE + scatter qkv[T,6144] -> Qr[b,h,s,d] Kr[b,h,s,d] Vt[b,h,d,s]
__global__ __launch_bounds__(256) void rope_scatter_kernel(
    const ushort* __restrict__ qkv, const float2* __restrict__ tab,
    ushort* __restrict__ Qr, ushort* __restrict__ Kr, ushort* __restrict__ Vt) {
  __shared__ ushort vt[64][132];
  const int t = threadIdx.x, tt = blockIdx.x, h = blockIdx.y;  // h: 0..47
  const int row = t >> 2, c = (t & 3) * 16;
  const int tok = tt * 64 + row;
  const int b = tok >> 11, s = tok & 2047;
  const ushort* ip = qkv + (size_t)tok * 6144 + h * 128;
  union U { uint4 v; ushort us[8]; };
  U a0, a1, b0, b1;
  a0.v = *(const uint4*)(ip + c);      a1.v = *(const uint4*)(ip + c + 8);
  b0.v = *(const uint4*)(ip + c + 64); b1.v = *(const uint4*)(ip + c + 72);
  if (h < 40) {  // q or k head: NeoX rope on pairs (i, i+64)
    U o0, o1, o2, o3;
#pragma unroll
    for (int j = 0; j < 8; ++j) {
      float2 cs = tab[s * 64 + c + j];
      float x1 = bf2f(a0.us[j]), x2 = bf2f(b0.us[j]);
      o0.us[j] = f2bf(x1 * cs.x - x2 * cs.y);
      o2.us[j] = f2bf(x2 * cs.x + x1 * cs.y);
    }
#pragma unroll
    for (int j = 0; j < 8; ++j) {
      float2 cs = tab[s * 64 + c + 8 + j];
      float x1 = bf2f(a1.us[j]), x2 = bf2f(b1.us[j]);
      o1.us[j] = f2bf(x1 * cs.x - x2 * cs.y);
      o3.us[j] = f2bf(x2 * cs.x + x1 * cs.y);
    }
    ushort* base;
    if (h < 32) base = Qr + ((size_t)((b * 32 + h) * 2048 + s)) * 128;
    else        base = Kr + ((size_t)((b * 8 + (h - 32)) * 2048 + s)) * 128;
    *(uint4*)(base + c)      = o0.v; *(uint4*)(base + c + 8)  = o1.v;
    *(uint4*)(base + c + 64) = o2.v; *(uint4*)(base + c + 72) = o3.v;
  } else {  // v head: LDS transpose -> Vt[b,hv,d,s]
    const int hv = h - 40;
#pragma unroll
    for (int j = 0; j < 8; ++j) {
      vt[row][c + j]      = a0.us[j]; vt[row][c + 8 + j]  = a1.us[j];
      vt[row][c + 64 + j] = b0.us[j]; vt[row][c + 72 + j] = b1.us[j];
    }
    __syncthreads();
    const int d = t >> 1, s0 = (t & 1) * 32, sb = (tt & 31) * 64;
    U w0, w1, w2, w3;
#pragma unroll
    for (int j = 0; j < 8; ++j) {
      w0.us[j] = vt[s0 + j][d];      w1.us[j] = vt[s0 + 8 + j][d];
      w2.us[j] = vt[s0 + 16 + j][d]; w3.us[j] = vt[s0 + 24 + j][d];
    }
    ushort* vb = Vt + ((size_t)((b * 8 + hv) * 128 + d)) * 2048 + sb + s0;
    *(uint4*)(vb) = w0.v;      *(uint4*)(vb + 8) = w1.v;
    *(uint4*)(vb + 16) = w2.v; *(uint4*)(vb + 24) = w3.v;
  }
}

// ------------- flash attention + hidden weight transposes ------------------
// Blocks [0,1024): verbatim R12 attn body (flattened grid qb/h/b).
// Blocks >= 1024: 512-thr transpose jobs (w_gu p1 -> W3, p2 -> W4, w_o -> W2)
// filling attn's idle slots / causal-imbalance tail (attn is at 3% HBM BW).
__global__ __launch_bounds__(512) void attn_tc_kernel(
    const ushort* __restrict__ Q, const ushort* __restrict__ K,
    const ushort* __restrict__ V, ushort* __restrict__ O,
    const float* t1in, ushort* t1out, int t1ld, int t1off, int t1R, int t1ntx, int t1n,
    const float* t2in, ushort* t2out, int t2ld, int t2off, int t2R, int t2ntx, int t2n,
    const float* t3in, ushort* t3out, int t3ld, int t3off, int t3R, int t3ntx, int t3n) {
  extern __shared__ ushort sm[];
  const int bid = (int)blockIdx.x;
  const int t = threadIdx.x;
  if (bid >= 1024) {                      // transpose blocks
    int tb = bid - 1024;
    if (tb < t1n) {
      transpose512(t1in, t1out, t1ld, t1off, t1R, t1ntx, tb, sm, t);
    } else if (tb < t1n + t2n) {
      transpose512(t2in, t2out, t2ld, t2off, t2R, t2ntx, tb - t1n, sm, t);
    } else {
      transpose512(t3in, t3out, t3ld, t3off, t3R, t3ntx, tb - t1n - t2n, sm, t);
    }
    return;
  }
  const int qb = bid & 15, h = (bid >> 4) & 31, b = bid >> 9;

  ushort* Kl = sm;           // [2][64 s][128 d]
  ushort* Vl = sm + 16384;   // [2][128 d][64 s]
  ushort* Pl = sm + 32768;   // [128][64]
  const int l = t & 63, w = t >> 6;   // w: 0..7
  const int lr = l & 15, lg = l >> 4;
  const int hkv = h >> 2;
  const f32x4 fzero = {0.f, 0.f, 0.f, 0.f};

  const int rm = lr & 7;
  int ksw[4], vsw[2];
#pragma unroll
  for (int ks = 0; ks < 4; ++ks) ksw[ks] = ((ks * 4 + lg) ^ rm) * 8;
  vsw[0] = (lg ^ rm) * 8;
  vsw[1] = ((4 + lg) ^ rm) * 8;
  const int kcol = ((t & 15) ^ ((t >> 4) & 7)) * 8;   // staging src swizzle
  const int vcol = ((t & 7) ^ ((t >> 3) & 7)) * 8;

  const float qscale = 0.08838834764831845f * 1.4426950408889634f;
  const ushort* qp =
      Q + ((size_t)((b * 32 + h) * 2048 + qb * 128 + w * 16 + lr)) * 128 + lg * 8;
  bf16x8 qf[4];
#pragma unroll
  for (int ks = 0; ks < 4; ++ks) {
    bf16x8 raw = *(const bf16x8*)(qp + ks * 32);
#pragma unroll
    for (int j = 0; j < 8; ++j)
      qf[ks][j] = (short)f2bf(bf2f((ushort)raw[j]) * qscale);
  }
  bf16x8 ones;
#pragma unroll
  for (int j = 0; j < 8; ++j) ones[j] = (short)0x3F80;
  WAIT_VM0();

  const ushort* kg = K + ((size_t)(b * 8 + hkv)) * 2048 * 128;
  const ushort* vg = V + ((size_t)(b * 8 + hkv)) * 128 * 2048;

#define STAGE_KV(buf, s0_) do {                                              \
    _Pragma("unroll") for (int i_ = 0; i_ < 2; ++i_)                         \
      gload16(kg + (size_t)((s0_) + i_ * 32 + (t >> 4)) * 128 + kcol,        \
              (char*)Kl + (buf) * 16384 + i_ * 8192 + t * 16);               \
    _Pragma("unroll") for (int i_ = 0; i_ < 2; ++i_)                         \
      gload16(vg + (size_t)(i_ * 64 + (t >> 3)) * 2048 + (s0_) + vcol,       \
              (char*)Vl + (buf) * 16384 + i_ * 8192 + t * 16);               \
  } while (0)

  f32x4 accO[8];
#pragma unroll
  for (int i = 0; i < 8; ++i) accO[i] = fzero;
  float m_r[4] = {-1e30f, -1e30f, -1e30f, -1e30f};
  float l_r[4] = {0.f, 0.f, 0.f, 0.f};
  const int qrow = qb * 128 + w * 16 + lg * 4;
  const int wrow0 = qb * 128 + w * 16;
  const int jend = 2 * qb + 1;

  STAGE_KV(0, 0);
  for (int j = 0; j <= jend; ++j) {
    if (j < jend) { STAGE_KV((j + 1) & 1, (j + 1) * 64); WAIT_VM4(); }
    else          { WAIT_VM0(); }
    BARRIER();
    const ushort* Kb = Kl + (j & 1) * 8192;
    const ushort* Vb = Vl + (j & 1) * 8192;

    f32x4 sc[4];
#pragma unroll
    for (int ni = 0; ni < 4; ++ni) sc[ni] = fzero;
    __builtin_amdgcn_s_setprio(1);
#pragma unroll
    for (int ni = 0; ni < 4; ++ni)
#pragma unroll
      for (int ks = 0; ks < 4; ++ks) {
        bf16x8 kf = *(const bf16x8*)(Kb + (ni * 16 + lr) * 128 + ksw[ks]);
        sc[ni] = __builtin_amdgcn_mfma_f32_16x16x32_bf16(qf[ks], kf, sc[ni], 0, 0, 0);
      }
    __builtin_amdgcn_s_setprio(0);
    if (j * 64 + 63 > wrow0) {
#pragma unroll
      for (int ni = 0; ni < 4; ++ni)
#pragma unroll
        for (int r = 0; r < 4; ++r)
          if (j * 64 + ni * 16 + lr > qrow + r) sc[ni][r] = -1e30f;
    }
    float mx[4];
#pragma unroll
    for (int r = 0; r < 4; ++r) {
      float v = fmaxf(fmaxf(sc[0][r], sc[1][r]), fmaxf(sc[2][r], sc[3][r]));
#pragma unroll
      for (int m = 8; m; m >>= 1) v = fmaxf(v, __shfl_xor(v, m));
      mx[r] = v;
    }
    bool ok = mx[0] <= m_r[0] + 8.f && mx[1] <= m_r[1] + 8.f &&
              mx[2] <= m_r[2] + 8.f && mx[3] <= m_r[3] + 8.f;
    if (!__all(ok)) {
#pragma unroll
      for (int r = 0; r < 4; ++r) {
        float mnew = fmaxf(m_r[r], mx[r]);
        float fsc = exp2f(m_r[r] - mnew);
        l_r[r] *= fsc;
        m_r[r] = mnew;
#pragma unroll
        for (int i = 0; i < 8; ++i) accO[i][r] *= fsc;
      }
    }
#pragma unroll
    for (int ni = 0; ni < 4; ++ni)
#pragma unroll
      for (int r = 0; r < 4; ++r) {
        int prow = w * 16 + lg * 4 + r;
        int slot = (ni * 2 + (lr >> 3)) ^ (prow & 7);
        Pl[prow * 64 + slot * 8 + rm] = f2bf(exp2f(sc[ni][r] - m_r[r]));
      }
    WAIT_LGKM0();
    f32x4 accL = fzero;
    __builtin_amdgcn_s_setprio(1);
#pragma unroll
    for (int ks = 0; ks < 2; ++ks) {
      bf16x8 pf = *(const bf16x8*)(Pl + (w * 16 + lr) * 64 + vsw[ks]);
#pragma unroll
      for (int nf = 0; nf < 8; ++nf) {
        bf16x8 vf = *(const bf16x8*)(Vb + (nf * 16 + lr) * 64 + vsw[ks]);
        accO[nf] = __builtin_amdgcn_mfma_f32_16x16x32_bf16(pf, vf, accO[nf], 0, 0, 0);
      }
      accL = __builtin_amdgcn_mfma_f32_16x16x32_bf16(pf, ones, accL, 0, 0, 0);
    }
    __builtin_amdgcn_s_setprio(0);
#pragma unroll
    for (int r = 0; r < 4; ++r) l_r[r] += accL[r];
    BARRIER();
  }
#undef STAGE_KV
  float invl[4];
#pragma unroll
  for (int r = 0; r < 4; ++r) invl[r] = 1.f / l_r[r];
#pragma unroll
  for (int nf = 0; nf < 8; ++nf)
#pragma unroll
    for (int r = 0; r < 4; ++r) {
      int q = qb * 128 + w * 16 + lg * 4 + r;
      int d = nf * 16 + lr;
      O[((size_t)(b * 2048 + q)) * 4096 + h * 128 + d] = f2bf(accO[nf][r] * invl[r]);
    }
}

// ------------------------------ launcher -----------------------------------
// Lifetime-checked overlay arena (all sizes bytes). h1 lives in d_out.
//  R1 [0,90.18M):        qkvbuf(s3-4) | W3(s5-9) | act(s10-12)
//  R2 [90.18M,180.36M):  W4(s5-10) | W5(s11-12)
//  R3 [180.36M,270.53M): W1(s2-3) | Qr/Kr/Vt/tab(s4-5) | gate(s9-10)
//  R4 [270.53M,320.86M): qkv? no -> qkvbuf in R1? (see below) W2(s5-7)
//  R5 [320.86M,354.42M): xn(s1-3, s8-10) | attnbuf(s5-7)
#define OFF_W3    ((size_t)0)
#define OFF_ACT   ((size_t)0)
#define OFF_W4    ((size_t)90177536)
#define OFF_W5    ((size_t)90177536)
#define OFF_W1    ((size_t)180355072)
#define OFF_QR    ((size_t)180355072)
#define OFF_KR    ((size_t)213909504)
#define OFF_VT    ((size_t)222298112)
#define OFF_TAB   ((size_t)230686720)
#define OFF_GATE  ((size_t)180355072)
#define OFF_QKVB  ((size_t)270532608)
#define OFF_W2    ((size_t)270532608)
#define OFF_XN    ((size_t)320864256)
#define OFF_ATTNB ((size_t)320864256)
#define WS_NEED   ((size_t)416284672)

extern "C" void kernel_launch(void* const* d_in, const int* in_sizes, int n_in,
                              void* d_out, int out_size, void* d_ws,
                              size_t ws_size, hipStream_t stream) {
  (void)in_sizes; (void)n_in; (void)out_size;
  if (ws_size < WS_NEED) return;
  const float* hs     = (const float*)d_in[0];
  const int*   pos    = (const int*)d_in[1];
  const float* w_qkv  = (const float*)d_in[2];
  const float* w_o    = (const float*)d_in[3];
  const float* w_gu   = (const float*)d_in[4];
  const float* w_down = (const float*)d_in[5];
  const float* ln1    = (const float*)d_in[6];
  const float* ln2    = (const float*)d_in[7];
  float* out = (float*)d_out;
  float* h1  = (float*)d_out;          // residual stream lives in d_out
  char* ws = (char*)d_ws;

  ushort* W1    = (ushort*)(ws + OFF_W1);
  ushort* W2    = (ushort*)(ws + OFF_W2);
  ushort* W3    = (ushort*)(ws + OFF_W3);
  ushort* W4    = (ushort*)(ws + OFF_W4);
  ushort* W5    = (ushort*)(ws + OFF_W5);
  ushort* xn    = (ushort*)(ws + OFF_XN);
  ushort* qkvb  = (ushort*)(ws + OFF_QKVB);
  float2* tab   = (float2*)(ws + OFF_TAB);
  ushort* Qr    = (ushort*)(ws + OFF_QR);
  ushort* Kr    = (ushort*)(ws + OFF_KR);
  ushort* Vt    = (ushort*)(ws + OFF_VT);
  ushort* attnb = (ushort*)(ws + OFF_ATTNB);
  ushort* gate  = (ushort*)(ws + OFF_GATE);
  ushort* act   = (ushort*)(ws + OFF_ACT);

  auto kb = gemm256_kernel<ushort, false>;
  auto kf = gemm256_kernel<float, true>;
  hipFuncSetAttribute((const void*)kb, hipFuncAttributeMaxDynamicSharedMemorySize, 131072);
  hipFuncSetAttribute((const void*)kf, hipFuncAttributeMaxDynamicSharedMemorySize, 131072);
  hipFuncSetAttribute((const void*)gemm256_swiglu_kernel, hipFuncAttributeMaxDynamicSharedMemorySize, 131072);
  hipFuncSetAttribute((const void*)attn_tc_kernel, hipFuncAttributeMaxDynamicSharedMemorySize, 81920);

  // s1: rmsnorm1
  rmsnorm_kernel<<<4096, 256, 0, stream>>>(hs, ln1, xn);
  // s2: transpose w_qkv -> W1 (exposed)
  transpose_cast_kernel<<<dim3(64, 96), 256, 0, stream>>>(w_qkv, W1, 6144, 0, 4096);
  // s3: qkv GEMM (writes qkvb in R1; W3 written later at s5)
  gemm256_kernel<ushort, false><<<384, 512, 131072, stream>>>(
      xn, W1, (ushort*)(ws + OFF_QKVB), nullptr, 4096, 6144, 4096);
  // s4: rope
  rope_table_kernel<<<512, 256, 0, stream>>>(pos, tab);
  rope_scatter_kernel<<<dim3(64, 48), 256, 0, stream>>>(qkvb, tab, Qr, Kr, Vt);
  // s5: attn + hidden transposes (w_gu p1 -> W3, w_gu p2 -> W4, w_o -> W2)
  attn_tc_kernel<<<1024 + 5504 + 5504 + 2048, 512, 81920, stream>>>(
      Qr, Kr, Vt, attnb,
      w_gu, W3, 22016, 0,     4096, 64, 5504,
      w_gu, W4, 22016, 11008, 4096, 64, 5504,
      w_o,  W2, 4096,  0,     4096, 64, 2048);
  // s7: o-proj (residual hs) -> h1 (= d_out)
  gemm256_kernel<float, true><<<256, 512, 131072, stream>>>(
      attnb, W2, h1, hs, 4096, 4096, 4096);
  // s8: rmsnorm2 (reads d_out)
  rmsnorm_kernel<<<4096, 256, 0, stream>>>(h1, ln2, xn);
  // s9: gate GEMM
  gemm256_kernel<ushort, false><<<688, 512, 131072, stream>>>(
      xn, W3, gate, nullptr, 4096, 11008, 4096);
  // s10: up GEMM + fused SwiGLU -> act
  gemm256_swiglu_kernel<<<688, 512, 131072, stream>>>(
      xn, W4, act, gate, 4096, 11008, 4096);
  // s11: transpose w_down -> W5 (exposed)
  transpose_cast_kernel<<<dim3(172, 64), 256, 0, stream>>>(w_down, W5, 4096, 0, 11008);
  // s12: down GEMM, residual h1 (= d_out), in-place same-index write
  gemm256_kernel<float, true><<<256, 512, 131072, stream>>>(
      act, W5, out, h1, 4096, 4096, 11008);
}

// Round 14
// 1727.311 us; speedup vs baseline: 1.1378x; 1.0121x over previous
//
#include <hip/hip_runtime.h>

// ---------------------------------------------------------------------------
// Llama decoder layer, MI355X (gfx950).
// B=2 S=2048 HIDDEN=4096 HQ=32 HKV=8 D=128 INTER=11008, fp32 in/out.
// R14: hide w_down transpose under the gate GEMM (gemm256_tc_kernel =
// verbatim gemm256_kernel<ushort,false> body + transpose512 tail blocks,
// same rule-#19-safe recipe as R13's attn_tc). Workspace re-layout:
//  A [0,90.2M):       qkvb(s3-s4) | W3(s5-s9) | act(s10-s12)
//  B [90.2,180.4M):   W4(s5-s10)
//  D [180.4,270.5M):  W1(s2-s3) | tab/Qr/Kr/Vt(s4-s5) | gate(s9-s10)
//  C [270.5,360.7M):  W2(s5-s7) | W5(s9-s12)   [W2 dead before W5 write]
//  E [360.7,394.3M):  xn(s1-s3) | attnb(s5-s7) | xn(s8-s10)  [shared slot]
// Peak 394.3MB < 416.3 budget. h1 lives in d_out (same-index read-then-
// write in down-GEMM epilogue; fully rewritten each replay).
// All other kernels byte-identical to R13.
// ---------------------------------------------------------------------------

typedef __attribute__((ext_vector_type(8))) short bf16x8;
typedef __attribute__((ext_vector_type(4))) float f32x4;

__device__ __forceinline__ ushort f2bf(float f) {           // RNE fp32->bf16
  unsigned u = __float_as_uint(f);
  return (ushort)((u + 0x7fffu + ((u >> 16) & 1u)) >> 16);
}
__device__ __forceinline__ float bf2f(ushort u) {
  union { unsigned u32; float f; } x; x.u32 = ((unsigned)u) << 16; return x.f;
}
__device__ __forceinline__ void gload16(const void* g, void* l) {
  __builtin_amdgcn_global_load_lds((__attribute__((address_space(1))) void*)g,
                                   (__attribute__((address_space(3))) void*)l,
                                   16, 0, 0);
}

#define BARRIER() asm volatile("s_barrier" ::: "memory")
#define WAIT_LGKM0() asm volatile("s_waitcnt lgkmcnt(0)" ::: "memory")
#define WAIT_VM4() asm volatile("s_waitcnt vmcnt(4)" ::: "memory")
#define WAIT_VM0() asm volatile("s_waitcnt vmcnt(0)" ::: "memory")

// --------------------------- RMSNorm (fp32 -> bf16) ------------------------
__global__ __launch_bounds__(256) void rmsnorm_kernel(
    const float* __restrict__ x, const float* __restrict__ g,
    ushort* __restrict__ out) {
  const int row = blockIdx.x, t = threadIdx.x;
  const float4* xp = (const float4*)(x + (size_t)row * 4096);
  float4 v[4]; float ss = 0.f;
#pragma unroll
  for (int i = 0; i < 4; ++i) {
    v[i] = xp[t + i * 256];
    ss += v[i].x * v[i].x + v[i].y * v[i].y + v[i].z * v[i].z + v[i].w * v[i].w;
  }
#pragma unroll
  for (int m = 32; m; m >>= 1) ss += __shfl_xor(ss, m);
  __shared__ float red[4];
  if ((t & 63) == 0) red[t >> 6] = ss;
  __syncthreads();
  float inv = rsqrtf((red[0] + red[1] + red[2] + red[3]) * (1.f / 4096.f) + 1e-6f);
  const float4* gp = (const float4*)g;
  ushort* op = out + (size_t)row * 4096;
#pragma unroll
  for (int i = 0; i < 4; ++i) {
    float4 gv = gp[t + i * 256];
    ushort4 o;
    o.x = f2bf(v[i].x * inv * gv.x); o.y = f2bf(v[i].y * inv * gv.y);
    o.z = f2bf(v[i].z * inv * gv.z); o.w = f2bf(v[i].w * inv * gv.w);
    *(ushort4*)(op + (size_t)(t + i * 256) * 4) = o;
  }
}

// ----------------- transpose + cast fp32 [R][ld_in] -> bf16 [C][R] ---------
__global__ __launch_bounds__(256) void transpose_cast_kernel(
    const float* __restrict__ in, ushort* __restrict__ out,
    int ld_in, int col_off, int R) {
  __shared__ ushort tile[64][65];
  const int t = threadIdx.x;
  const int r0 = blockIdx.x * 64, c0 = blockIdx.y * 64;
  const int rl = t >> 2, cl = (t & 3) * 16;
  const float* ip = in + (size_t)(r0 + rl) * ld_in + col_off + c0 + cl;
#pragma unroll
  for (int i = 0; i < 4; ++i) {
    float4 f = ((const float4*)ip)[i];
    tile[rl][cl + i * 4 + 0] = f2bf(f.x);
    tile[rl][cl + i * 4 + 1] = f2bf(f.y);
    tile[rl][cl + i * 4 + 2] = f2bf(f.z);
    tile[rl][cl + i * 4 + 3] = f2bf(f.w);
  }
  __syncthreads();
  union { ushort us[8]; uint4 v; } pk0, pk1;
#pragma unroll
  for (int j = 0; j < 8; ++j) pk0.us[j] = tile[cl + j][rl];
#pragma unroll
  for (int j = 0; j < 8; ++j) pk1.us[j] = tile[cl + 8 + j][rl];
  uint4* op = (uint4*)(out + (size_t)(c0 + rl) * R + r0 + cl);
  op[0] = pk0.v; op[1] = pk1.v;
}

// ------- 512-thread transpose helper (2 x 64x64 tiles per block) -----------
__device__ __forceinline__ void transpose512(
    const float* __restrict__ in, ushort* __restrict__ out,
    int ld_in, int col_off, int R, int ntx, int tbid, ushort* ldsb, int t) {
  const int half = t >> 8, tt = t & 255;
  ushort* tile = ldsb + half * (64 * 65);
  const int x = tbid % ntx, yy = tbid / ntx;
  const int r0 = x * 64, c0 = (yy * 2 + half) * 64;
  const int rl = tt >> 2, cl = (tt & 3) * 16;
  const float* ip = in + (size_t)(r0 + rl) * ld_in + col_off + c0 + cl;
#pragma unroll
  for (int i = 0; i < 4; ++i) {
    float4 f = ((const float4*)ip)[i];
    tile[rl * 65 + cl + i * 4 + 0] = f2bf(f.x);
    tile[rl * 65 + cl + i * 4 + 1] = f2bf(f.y);
    tile[rl * 65 + cl + i * 4 + 2] = f2bf(f.z);
    tile[rl * 65 + cl + i * 4 + 3] = f2bf(f.w);
  }
  __syncthreads();
  union { ushort us[8]; uint4 v; } pk0, pk1;
#pragma unroll
  for (int j = 0; j < 8; ++j) pk0.us[j] = tile[(cl + j) * 65 + rl];
#pragma unroll
  for (int j = 0; j < 8; ++j) pk1.us[j] = tile[(cl + 8 + j) * 65 + rl];
  uint4* op = (uint4*)(out + (size_t)(c0 + rl) * R + r0 + cl);
  op[0] = pk0.v; op[1] = pk1.v;
}

// ------------------------- GEMM 256x256 8-phase ----------------------------
// Byte-identical to R8..R13 (R4 body + col-major XCD chunk mapping).
template <typename OutT, bool RES>
__global__ __launch_bounds__(512, 2) void gemm256_kernel(
    const ushort* __restrict__ A, const ushort* __restrict__ Bt,
    OutT* __restrict__ C, const float* __restrict__ res,
    int M, int N, int K) {
  extern __shared__ ushort lds[];
  ushort* Al = lds;            // [buf:2][half:2][8192 ushorts]
  ushort* Bl = lds + 32768;
  const int t = threadIdx.x, l = t & 63, w = t >> 6;
  const int wr = w >> 2, wc = w & 3;
  const int lr = l & 15, lg = l >> 4;
  const int rhi = lr >> 3, rlo = lr & 7;
  const int srow = l >> 3, sg = (l & 7) ^ srow;

  const int nby = M >> 8;
  const int nwg = (N >> 8) * nby;
  const int cpx = nwg >> 3;
  const int bid = (int)blockIdx.x;
  const int swz = (bid & 7) * cpx + (bid >> 3);   // XCD chunk (nwg%8==0)
  const int m0 = (swz % nby) << 8;                // col-major: B panel shared
  const int n0 = (swz / nby) << 8;                // by 16 consecutive blocks

  const int lof0 = rhi * 512 + rlo * 64 + ((0 + lg) ^ rlo) * 8;  // kk=0
  const int lof1 = rhi * 512 + rlo * 64 + ((4 + lg) ^ rlo) * 8;  // kk=1

  const f32x4 fz = {0.f, 0.f, 0.f, 0.f};
  f32x4 acc[8][4];
#pragma unroll
  for (int i = 0; i < 8; ++i)
#pragma unroll
    for (int j = 0; j < 4; ++j) acc[i][j] = fz;
  bf16x8 a[8][2];
  bf16x8 bq[2][2];

  const ushort* Asrc = A + (size_t)(m0 + w * 8 + srow) * K + sg * 8;
  const ushort* Bsrc = Bt + (size_t)(n0 + w * 8 + srow) * K + sg * 8;
  const size_t rK64 = (size_t)64 * K, rK128 = (size_t)128 * K;
  ushort* Adst = Al + w * 512;
  ushort* Bdst = Bl + w * 512;

#define STAGE_A(buf, half, tile) do {                                   \
    const ushort* s_ = Asrc + (size_t)(half) * rK128 + ((tile) << 6);   \
    ushort* d_ = Adst + (buf) * 16384 + (half) * 8192;                  \
    gload16(s_, d_);                                                    \
    gload16(s_ + rK64, d_ + 4096);                                      \
  } while (0)
#define STAGE_B(buf, half, tile) do {                                   \
    const ushort* s_ = Bsrc + (size_t)(half) * rK128 + ((tile) << 6);   \
    ushort* d_ = Bdst + (buf) * 16384 + (half) * 8192;                  \
    gload16(s_, d_);                                                    \
    gload16(s_ + rK64, d_ + 4096);                                      \
  } while (0)
#define LDA4(AH, QM) do {                                                   \
    _Pragma("unroll") for (int mi_ = 0; mi_ < 4; ++mi_) {                   \
      a[(QM) * 4 + mi_][0] =                                                \
          *(const bf16x8*)((AH) + ((QM) * 4 + mi_) * 1024 + lof0);          \
      a[(QM) * 4 + mi_][1] =                                                \
          *(const bf16x8*)((AH) + ((QM) * 4 + mi_) * 1024 + lof1);          \
    } } while (0)
#define LDB2(BH, NQ) do {                                                   \
    _Pragma("unroll") for (int nj_ = 0; nj_ < 2; ++nj_) {                   \
      bq[nj_][0] = *(const bf16x8*)((BH) + ((NQ) * 2 + nj_) * 1024 + lof0); \
      bq[nj_][1] = *(const bf16x8*)((BH) + ((NQ) * 2 + nj_) * 1024 + lof1); \
    } } while (0)
#define MFMA16(QM, QN)                                                      \
    __builtin_amdgcn_s_setprio(1);                                          \
    _Pragma("unroll") for (int mi_ = 0; mi_ < 4; ++mi_)                     \
    _Pragma("unroll") for (int nj_ = 0; nj_ < 2; ++nj_) {                   \
      acc[(QM) * 4 + mi_][(QN) * 2 + nj_] =                                 \
          __builtin_amdgcn_mfma_f32_16x16x32_bf16(                          \
              a[(QM) * 4 + mi_][0], bq[nj_][0],                             \
              acc[(QM) * 4 + mi_][(QN) * 2 + nj_], 0, 0, 0);                \
      acc[(QM) * 4 + mi_][(QN) * 2 + nj_] =                                 \
          __builtin_amdgcn_mfma_f32_16x16x32_bf16(                          \
              a[(QM) * 4 + mi_][1], bq[nj_][1],                             \
              acc[(QM) * 4 + mi_][(QN) * 2 + nj_], 0, 0, 0);                \
    }                                                                       \
    __builtin_amdgcn_s_setprio(0);

  const ushort* A0h = Al + wr * 8192;
  const ushort* A1h = A0h + 16384;
  const ushort* B0h = Bl + (wc >> 1) * 8192 + (wc & 1) * 4096;
  const ushort* B1h = B0h + 16384;

  const int ntiles = K >> 6, nIter = K >> 7;
  // prologue: tile0 full -> buf0; tile1 A halves -> buf1
  STAGE_A(0, 0, 0); STAGE_A(0, 1, 0); STAGE_B(0, 0, 0); STAGE_B(0, 1, 0);
  STAGE_A(1, 0, 1); STAGE_A(1, 1, 1);
  WAIT_VM4(); BARRIER();

  for (int it = 0; it < nIter; ++it) {
    const int u = it * 2;
    // ---- tile u (buf0) ----
    LDA4(A0h, 0); LDB2(B0h, 0);                 // P1
    STAGE_B(1, 0, u + 1);
    BARRIER(); WAIT_LGKM0(); MFMA16(0, 0); BARRIER();
    LDA4(A0h, 1);                               // P2
    STAGE_B(1, 1, u + 1);
    BARRIER(); WAIT_LGKM0(); MFMA16(1, 0); BARRIER();
    LDB2(B0h, 1);                               // P3
    if (u + 2 < ntiles) STAGE_A(0, 0, u + 2);
    BARRIER(); WAIT_LGKM0(); MFMA16(0, 1); BARRIER();
    if (u + 2 < ntiles) STAGE_A(0, 1, u + 2);   // P4
    BARRIER(); MFMA16(1, 1);
    if (u + 2 < ntiles) { WAIT_VM4(); } else { WAIT_VM0(); }
    BARRIER();
    // ---- tile u+1 (buf1) ----
    LDA4(A1h, 0); LDB2(B1h, 0);                 // P5
    if (u + 2 < ntiles) STAGE_B(0, 0, u + 2);
    BARRIER(); WAIT_LGKM0(); MFMA16(0, 0); BARRIER();
    LDA4(A1h, 1);                               // P6
    if (u + 2 < ntiles) STAGE_B(0, 1, u + 2);
    BARRIER(); WAIT_LGKM0(); MFMA16(1, 0); BARRIER();
    LDB2(B1h, 1);                               // P7
    if (u + 3 < ntiles) STAGE_A(1, 0, u + 3);
    BARRIER(); WAIT_LGKM0(); MFMA16(0, 1); BARRIER();
    if (u + 3 < ntiles) STAGE_A(1, 1, u + 3);   // P8
    BARRIER(); MFMA16(1, 1);
    WAIT_VM4(); BARRIER();
  }

  // epilogue: C row = m0+wr*128+mi*16+lg*4+r, col = n0+wc*64+ni*16+lr
#pragma unroll
  for (int mi = 0; mi < 8; ++mi)
#pragma unroll
    for (int ni = 0; ni < 4; ++ni)
#pragma unroll
      for (int r = 0; r < 4; ++r) {
        int row = m0 + wr * 128 + mi * 16 + lg * 4 + r;
        int col = n0 + wc * 64 + ni * 16 + lr;
        size_t idx = (size_t)row * N + col;
        float v = acc[mi][ni][r];
        if (RES) v += res[idx];
        if constexpr (sizeof(OutT) == 2) C[idx] = f2bf(v);
        else                             C[idx] = v;
      }
#undef STAGE_A
#undef STAGE_B
#undef LDA4
#undef LDB2
#undef MFMA16
}

// ----------- GEMM (bf16 out, no res) + hidden transpose tail ---------------
// Verbatim gemm256_kernel<ushort,false> body; blocks >= nwg run transpose512
// jobs (w_down -> W5) in the GEMM's scheduling gaps (GEMM at 25% HBM BW).
__global__ __launch_bounds__(512, 2) void gemm256_tc_kernel(
    const ushort* __restrict__ A, const ushort* __restrict__ Bt,
    ushort* __restrict__ C, int M, int N, int K,
    const float* tin, ushort* tout, int tld, int toff, int tR, int tntx) {
  extern __shared__ ushort lds[];
  const int nby = M >> 8;
  const int nwg = (N >> 8) * nby;
  const int bid = (int)blockIdx.x;
  const int t = threadIdx.x;
  if (bid >= nwg) {                        // transpose tail blocks
    transpose512(tin, tout, tld, toff, tR, tntx, bid - nwg, lds, t);
    return;
  }
  ushort* Al = lds;
  ushort* Bl = lds + 32768;
  const int l = t & 63, w = t >> 6;
  const int wr = w >> 2, wc = w & 3;
  const int lr = l & 15, lg = l >> 4;
  const int rhi = lr >> 3, rlo = lr & 7;
  const int srow = l >> 3, sg = (l & 7) ^ srow;

  const int cpx = nwg >> 3;
  const int swz = (bid & 7) * cpx + (bid >> 3);
  const int m0 = (swz % nby) << 8;
  const int n0 = (swz / nby) << 8;

  const int lof0 = rhi * 512 + rlo * 64 + ((0 + lg) ^ rlo) * 8;
  const int lof1 = rhi * 512 + rlo * 64 + ((4 + lg) ^ rlo) * 8;

  const f32x4 fz = {0.f, 0.f, 0.f, 0.f};
  f32x4 acc[8][4];
#pragma unroll
  for (int i = 0; i < 8; ++i)
#pragma unroll
    for (int j = 0; j < 4; ++j) acc[i][j] = fz;
  bf16x8 a[8][2];
  bf16x8 bq[2][2];

  const ushort* Asrc = A + (size_t)(m0 + w * 8 + srow) * K + sg * 8;
  const ushort* Bsrc = Bt + (size_t)(n0 + w * 8 + srow) * K + sg * 8;
  const size_t rK64 = (size_t)64 * K, rK128 = (size_t)128 * K;
  ushort* Adst = Al + w * 512;
  ushort* Bdst = Bl + w * 512;

#define STAGE_A(buf, half, tile) do {                                   \
    const ushort* s_ = Asrc + (size_t)(half) * rK128 + ((tile) << 6);   \
    ushort* d_ = Adst + (buf) * 16384 + (half) * 8192;                  \
    gload16(s_, d_);                                                    \
    gload16(s_ + rK64, d_ + 4096);                                      \
  } while (0)
#define STAGE_B(buf, half, tile) do {                                   \
    const ushort* s_ = Bsrc + (size_t)(half) * rK128 + ((tile) << 6);   \
    ushort* d_ = Bdst + (buf) * 16384 + (half) * 8192;                  \
    gload16(s_, d_);                                                    \
    gload16(s_ + rK64, d_ + 4096);                                      \
  } while (0)
#define LDA4(AH, QM) do {                                                   \
    _Pragma("unroll") for (int mi_ = 0; mi_ < 4; ++mi_) {                   \
      a[(QM) * 4 + mi_][0] =                                                \
          *(const bf16x8*)((AH) + ((QM) * 4 + mi_) * 1024 + lof0);          \
      a[(QM) * 4 + mi_][1] =                                                \
          *(const bf16x8*)((AH) + ((QM) * 4 + mi_) * 1024 + lof1);          \
    } } while (0)
#define LDB2(BH, NQ) do {                                                   \
    _Pragma("unroll") for (int nj_ = 0; nj_ < 2; ++nj_) {                   \
      bq[nj_][0] = *(const bf16x8*)((BH) + ((NQ) * 2 + nj_) * 1024 + lof0); \
      bq[nj_][1] = *(const bf16x8*)((BH) + ((NQ) * 2 + nj_) * 1024 + lof1); \
    } } while (0)
#define MFMA16(QM, QN)                                                      \
    __builtin_amdgcn_s_setprio(1);                                          \
    _Pragma("unroll") for (int mi_ = 0; mi_ < 4; ++mi_)                     \
    _Pragma("unroll") for (int nj_ = 0; nj_ < 2; ++nj_) {                   \
      acc[(QM) * 4 + mi_][(QN) * 2 + nj_] =                                 \
          __builtin_amdgcn_mfma_f32_16x16x32_bf16(                          \
              a[(QM) * 4 + mi_][0], bq[nj_][0],                             \
              acc[(QM) * 4 + mi_][(QN) * 2 + nj_], 0, 0, 0);                \
      acc[(QM) * 4 + mi_][(QN) * 2 + nj_] =                                 \
          __builtin_amdgcn_mfma_f32_16x16x32_bf16(                          \
              a[(QM) * 4 + mi_][1], bq[nj_][1],                             \
              acc[(QM) * 4 + mi_][(QN) * 2 + nj_], 0, 0, 0);                \
    }                                                                       \
    __builtin_amdgcn_s_setprio(0);

  const ushort* A0h = Al + wr * 8192;
  const ushort* A1h = A0h + 16384;
  const ushort* B0h = Bl + (wc >> 1) * 8192 + (wc & 1) * 4096;
  const ushort* B1h = B0h + 16384;

  const int ntiles = K >> 6, nIter = K >> 7;
  STAGE_A(0, 0, 0); STAGE_A(0, 1, 0); STAGE_B(0, 0, 0); STAGE_B(0, 1, 0);
  STAGE_A(1, 0, 1); STAGE_A(1, 1, 1);
  WAIT_VM4(); BARRIER();

  for (int it = 0; it < nIter; ++it) {
    const int u = it * 2;
    LDA4(A0h, 0); LDB2(B0h, 0);
    STAGE_B(1, 0, u + 1);
    BARRIER(); WAIT_LGKM0(); MFMA16(0, 0); BARRIER();
    LDA4(A0h, 1);
    STAGE_B(1, 1, u + 1);
    BARRIER(); WAIT_LGKM0(); MFMA16(1, 0); BARRIER();
    LDB2(B0h, 1);
    if (u + 2 < ntiles) STAGE_A(0, 0, u + 2);
    BARRIER(); WAIT_LGKM0(); MFMA16(0, 1); BARRIER();
    if (u + 2 < ntiles) STAGE_A(0, 1, u + 2);
    BARRIER(); MFMA16(1, 1);
    if (u + 2 < ntiles) { WAIT_VM4(); } else { WAIT_VM0(); }
    BARRIER();
    LDA4(A1h, 0); LDB2(B1h, 0);
    if (u + 2 < ntiles) STAGE_B(0, 0, u + 2);
    BARRIER(); WAIT_LGKM0(); MFMA16(0, 0); BARRIER();
    LDA4(A1h, 1);
    if (u + 2 < ntiles) STAGE_B(0, 1, u + 2);
    BARRIER(); WAIT_LGKM0(); MFMA16(1, 0); BARRIER();
    LDB2(B1h, 1);
    if (u + 3 < ntiles) STAGE_A(1, 0, u + 3);
    BARRIER(); WAIT_LGKM0(); MFMA16(0, 1); BARRIER();
    if (u + 3 < ntiles) STAGE_A(1, 1, u + 3);
    BARRIER(); MFMA16(1, 1);
    WAIT_VM4(); BARRIER();
  }

#pragma unroll
  for (int mi = 0; mi < 8; ++mi)
#pragma unroll
    for (int ni = 0; ni < 4; ++ni)
#pragma unroll
      for (int r = 0; r < 4; ++r) {
        int row = m0 + wr * 128 + mi * 16 + lg * 4 + r;
        int col = n0 + wc * 64 + ni * 16 + lr;
        size_t idx = (size_t)row * N + col;
        C[idx] = f2bf(acc[mi][ni][r]);
      }
#undef STAGE_A
#undef STAGE_B
#undef LDA4
#undef LDB2
#undef MFMA16
}

// ---------------- GEMM 256x256 8-phase, fused-SwiGLU epilogue --------------
// Byte-identical to R12/R13. out = silu(gate) * (A*Bt^T), bf16.
__global__ __launch_bounds__(512, 2) void gemm256_swiglu_kernel(
    const ushort* __restrict__ A, const ushort* __restrict__ Bt,
    ushort* __restrict__ C, const ushort* __restrict__ gate,
    int M, int N, int K) {
  extern __shared__ ushort lds[];
  ushort* Al = lds;
  ushort* Bl = lds + 32768;
  const int t = threadIdx.x, l = t & 63, w = t >> 6;
  const int wr = w >> 2, wc = w & 3;
  const int lr = l & 15, lg = l >> 4;
  const int rhi = lr >> 3, rlo = lr & 7;
  const int srow = l >> 3, sg = (l & 7) ^ srow;

  const int nby = M >> 8;
  const int nwg = (N >> 8) * nby;
  const int cpx = nwg >> 3;
  const int bid = (int)blockIdx.x;
  const int swz = (bid & 7) * cpx + (bid >> 3);
  const int m0 = (swz % nby) << 8;
  const int n0 = (swz / nby) << 8;

  const int lof0 = rhi * 512 + rlo * 64 + ((0 + lg) ^ rlo) * 8;
  const int lof1 = rhi * 512 + rlo * 64 + ((4 + lg) ^ rlo) * 8;

  const f32x4 fz = {0.f, 0.f, 0.f, 0.f};
  f32x4 acc[8][4];
#pragma unroll
  for (int i = 0; i < 8; ++i)
#pragma unroll
    for (int j = 0; j < 4; ++j) acc[i][j] = fz;
  bf16x8 a[8][2];
  bf16x8 bq[2][2];

  const ushort* Asrc = A + (size_t)(m0 + w * 8 + srow) * K + sg * 8;
  const ushort* Bsrc = Bt + (size_t)(n0 + w * 8 + srow) * K + sg * 8;
  const size_t rK64 = (size_t)64 * K, rK128 = (size_t)128 * K;
  ushort* Adst = Al + w * 512;
  ushort* Bdst = Bl + w * 512;

#define STAGE_A(buf, half, tile) do {                                   \
    const ushort* s_ = Asrc + (size_t)(half) * rK128 + ((tile) << 6);   \
    ushort* d_ = Adst + (buf) * 16384 + (half) * 8192;                  \
    gload16(s_, d_);                                                    \
    gload16(s_ + rK64, d_ + 4096);                                      \
  } while (0)
#define STAGE_B(buf, half, tile) do {                                   \
    const ushort* s_ = Bsrc + (size_t)(half) * rK128 + ((tile) << 6);   \
    ushort* d_ = Bdst + (buf) * 16384 + (half) * 8192;                  \
    gload16(s_, d_);                                                    \
    gload16(s_ + rK64, d_ + 4096);                                      \
  } while (0)
#define LDA4(AH, QM) do {                                                   \
    _Pragma("unroll") for (int mi_ = 0; mi_ < 4; ++mi_) {                   \
      a[(QM) * 4 + mi_][0] =                                                \
          *(const bf16x8*)((AH) + ((QM) * 4 + mi_) * 1024 + lof0);          \
      a[(QM) * 4 + mi_][1] =                                                \
          *(const bf16x8*)((AH) + ((QM) * 4 + mi_) * 1024 + lof1);          \
    } } while (0)
#define LDB2(BH, NQ) do {                                                   \
    _Pragma("unroll") for (int nj_ = 0; nj_ < 2; ++nj_) {                   \
      bq[nj_][0] = *(const bf16x8*)((BH) + ((NQ) * 2 + nj_) * 1024 + lof0); \
      bq[nj_][1] = *(const bf16x8*)((BH) + ((NQ) * 2 + nj_) * 1024 + lof1); \
    } } while (0)
#define MFMA16(QM, QN)                                                      \
    __builtin_amdgcn_s_setprio(1);                                          \
    _Pragma("unroll") for (int mi_ = 0; mi_ < 4; ++mi_)                     \
    _Pragma("unroll") for (int nj_ = 0; nj_ < 2; ++nj_) {                   \
      acc[(QM) * 4 + mi_][(QN) * 2 + nj_] =                                 \
          __builtin_amdgcn_mfma_f32_16x16x32_bf16(                          \
              a[(QM) * 4 + mi_][0], bq[nj_][0],                             \
              acc[(QM) * 4 + mi_][(QN) * 2 + nj_], 0, 0, 0);                \
      acc[(QM) * 4 + mi_][(QN) * 2 + nj_] =                                 \
          __builtin_amdgcn_mfma_f32_16x16x32_bf16(                          \
              a[(QM) * 4 + mi_][1], bq[nj_][1],                             \
              acc[(QM) * 4 + mi_][(QN) * 2 + nj_], 0, 0, 0);                \
    }                                                                       \
    __builtin_amdgcn_s_setprio(0);

  const ushort* A0h = Al + wr * 8192;
  const ushort* A1h = A0h + 16384;
  const ushort* B0h = Bl + (wc >> 1) * 8192 + (wc & 1) * 4096;
  const ushort* B1h = B0h + 16384;

  const int ntiles = K >> 6, nIter = K >> 7;
  STAGE_A(0, 0, 0); STAGE_A(0, 1, 0); STAGE_B(0, 0, 0); STAGE_B(0, 1, 0);
  STAGE_A(1, 0, 1); STAGE_A(1, 1, 1);
  WAIT_VM4(); BARRIER();

  for (int it = 0; it < nIter; ++it) {
    const int u = it * 2;
    LDA4(A0h, 0); LDB2(B0h, 0);
    STAGE_B(1, 0, u + 1);
    BARRIER(); WAIT_LGKM0(); MFMA16(0, 0); BARRIER();
    LDA4(A0h, 1);
    STAGE_B(1, 1, u + 1);
    BARRIER(); WAIT_LGKM0(); MFMA16(1, 0); BARRIER();
    LDB2(B0h, 1);
    if (u + 2 < ntiles) STAGE_A(0, 0, u + 2);
    BARRIER(); WAIT_LGKM0(); MFMA16(0, 1); BARRIER();
    if (u + 2 < ntiles) STAGE_A(0, 1, u + 2);
    BARRIER(); MFMA16(1, 1);
    if (u + 2 < ntiles) { WAIT_VM4(); } else { WAIT_VM0(); }
    BARRIER();
    LDA4(A1h, 0); LDB2(B1h, 0);
    if (u + 2 < ntiles) STAGE_B(0, 0, u + 2);
    BARRIER(); WAIT_LGKM0(); MFMA16(0, 0); BARRIER();
    LDA4(A1h, 1);
    if (u + 2 < ntiles) STAGE_B(0, 1, u + 2);
    BARRIER(); WAIT_LGKM0(); MFMA16(1, 0); BARRIER();
    LDB2(B1h, 1);
    if (u + 3 < ntiles) STAGE_A(1, 0, u + 3);
    BARRIER(); WAIT_LGKM0(); MFMA16(0, 1); BARRIER();
    if (u + 3 < ntiles) STAGE_A(1, 1, u + 3);
    BARRIER(); MFMA16(1, 1);
    WAIT_VM4(); BARRIER();
  }

  // fused epilogue: out = silu(gate) * acc
#pragma unroll
  for (int mi = 0; mi < 8; ++mi)
#pragma unroll
    for (int ni = 0; ni < 4; ++ni)
#pragma unroll
      for (int r = 0; r < 4; ++r) {
        int row = m0 + wr * 128 + mi * 16 + lg * 4 + r;
        int col = n0 + wc * 64 + ni * 16 + lr;
        size_t idx = (size_t)row * N + col;
        float g = bf2f(gate[idx]);
        float s = g / (1.f + __expf(-g));
        C[idx] = f2bf(s * acc[mi][ni][r]);
      }
#undef STAGE_A
#undef STAGE_B
#undef LDA4
#undef LDB2
#undef MFMA16
}

// ------------------------------ RoPE table ---------------------------------
__global__ void rope_table_kernel(const int* __restrict__ pos,
                                  float2* __restrict__ tab) {
  int idx = blockIdx.x * 256 + threadIdx.x;  // 2048*64
  int s = idx >> 6, fi = idx & 63;
  float inv = (float)exp(-(double)(2 * fi) / 128.0 * 9.210340371976184);
  float a = (float)pos[s] * inv;
  tab[idx] = make_float2(cosf(a), sinf(a));
}

// --------- RoPE + scatter qkv[T,6144] -> Qr[b,h,s,d] Kr[b,h,s,d] Vt[b,h,d,s]
__global__ __launch_bounds__(256) void rope_scatter_kernel(
    const ushort* __restrict__ qkv, const float2* __restrict__ tab,
    ushort* __restrict__ Qr, ushort* __restrict__ Kr, ushort* __restrict__ Vt) {
  __shared__ ushort vt[64][132];
  const int t = threadIdx.x, tt = blockIdx.x, h = blockIdx.y;  // h: 0..47
  const int row = t >> 2, c = (t & 3) * 16;
  const int tok = tt * 64 + row;
  const int b = tok >> 11, s = tok & 2047;
  const ushort* ip = qkv + (size_t)tok * 6144 + h * 128;
  union U { uint4 v; ushort us[8]; };
  U a0, a1, b0, b1;
  a0.v = *(const uint4*)(ip + c);      a1.v = *(const uint4*)(ip + c + 8);
  b0.v = *(const uint4*)(ip + c + 64); b1.v = *(const uint4*)(ip + c + 72);
  if (h < 40) {  // q or k head: NeoX rope on pairs (i, i+64)
    U o0, o1, o2, o3;
#pragma unroll
    for (int j = 0; j < 8; ++j) {
      float2 cs = tab[s * 64 + c + j];
      float x1 = bf2f(a0.us[j]), x2 = bf2f(b0.us[j]);
      o0.us[j] = f2bf(x1 * cs.x - x2 * cs.y);
      o2.us[j] = f2bf(x2 * cs.x + x1 * cs.y);
    }
#pragma unroll
    for (int j = 0; j < 8; ++j) {
      float2 cs = tab[s * 64 + c + 8 + j];
      float x1 = bf2f(a1.us[j]), x2 = bf2f(b1.us[j]);
      o1.us[j] = f2bf(x1 * cs.x - x2 * cs.y);
      o3.us[j] = f2bf(x2 * cs.x + x1 * cs.y);
    }
    ushort* base;
    if (h < 32) base = Qr + ((size_t)((b * 32 + h) * 2048 + s)) * 128;
    else        base = Kr + ((size_t)((b * 8 + (h - 32)) * 2048 + s)) * 128;
    *(uint4*)(base + c)      = o0.v; *(uint4*)(base + c + 8)  = o1.v;
    *(uint4*)(base + c + 64) = o2.v; *(uint4*)(base + c + 72) = o3.v;
  } else {  // v head: LDS transpose -> Vt[b,hv,d,s]
    const int hv = h - 40;
#pragma unroll
    for (int j = 0; j < 8; ++j) {
      vt[row][c + j]      = a0.us[j]; vt[row][c + 8 + j]  = a1.us[j];
      vt[row][c + 64 + j] = b0.us[j]; vt[row][c + 72 + j] = b1.us[j];
    }
    __syncthreads();
    const int d = t >> 1, s0 = (t & 1) * 32, sb = (tt & 31) * 64;
    U w0, w1, w2, w3;
#pragma unroll
    for (int j = 0; j < 8; ++j) {
      w0.us[j] = vt[s0 + j][d];      w1.us[j] = vt[s0 + 8 + j][d];
      w2.us[j] = vt[s0 + 16 + j][d]; w3.us[j] = vt[s0 + 24 + j][d];
    }
    ushort* vb = Vt + ((size_t)((b * 8 + hv) * 128 + d)) * 2048 + sb + s0;
    *(uint4*)(vb) = w0.v;      *(uint4*)(vb + 8) = w1.v;
    *(uint4*)(vb + 16) = w2.v; *(uint4*)(vb + 24) = w3.v;
  }
}

// ------------- flash attention + hidden weight transposes ------------------
// Byte-identical to R13 attn_tc.
__global__ __launch_bounds__(512) void attn_tc_kernel(
    const ushort* __restrict__ Q, const ushort* __restrict__ K,
    const ushort* __restrict__ V, ushort* __restrict__ O,
    const float* t1in, ushort* t1out, int t1ld, int t1off, int t1R, int t1ntx, int t1n,
    const float* t2in, ushort* t2out, int t2ld, int t2off, int t2R, int t2ntx, int t2n,
    const float* t3in, ushort* t3out, int t3ld, int t3off, int t3R, int t3ntx, int t3n) {
  extern __shared__ ushort sm[];
  const int bid = (int)blockIdx.x;
  const int t = threadIdx.x;
  if (bid >= 1024) {                      // transpose blocks
    int tb = bid - 1024;
    if (tb < t1n) {
      transpose512(t1in, t1out, t1ld, t1off, t1R, t1ntx, tb, sm, t);
    } else if (tb < t1n + t2n) {
      transpose512(t2in, t2out, t2ld, t2off, t2R, t2ntx, tb - t1n, sm, t);
    } else {
      transpose512(t3in, t3out, t3ld, t3off, t3R, t3ntx, tb - t1n - t2n, sm, t);
    }
    return;
  }
  const int qb = bid & 15, h = (bid >> 4) & 31, b = bid >> 9;

  ushort* Kl = sm;           // [2][64 s][128 d]
  ushort* Vl = sm + 16384;   // [2][128 d][64 s]
  ushort* Pl = sm + 32768;   // [128][64]
  const int l = t & 63, w = t >> 6;   // w: 0..7
  const int lr = l & 15, lg = l >> 4;
  const int hkv = h >> 2;
  const f32x4 fzero = {0.f, 0.f, 0.f, 0.f};

  const int rm = lr & 7;
  int ksw[4], vsw[2];
#pragma unroll
  for (int ks = 0; ks < 4; ++ks) ksw[ks] = ((ks * 4 + lg) ^ rm) * 8;
  vsw[0] = (lg ^ rm) * 8;
  vsw[1] = ((4 + lg) ^ rm) * 8;
  const int kcol = ((t & 15) ^ ((t >> 4) & 7)) * 8;   // staging src swizzle
  const int vcol = ((t & 7) ^ ((t >> 3) & 7)) * 8;

  const float qscale = 0.08838834764831845f * 1.4426950408889634f;
  const ushort* qp =
      Q + ((size_t)((b * 32 + h) * 2048 + qb * 128 + w * 16 + lr)) * 128 + lg * 8;
  bf16x8 qf[4];
#pragma unroll
  for (int ks = 0; ks < 4; ++ks) {
    bf16x8 raw = *(const bf16x8*)(qp + ks * 32);
#pragma unroll
    for (int j = 0; j < 8; ++j)
      qf[ks][j] = (short)f2bf(bf2f((ushort)raw[j]) * qscale);
  }
  bf16x8 ones;
#pragma unroll
  for (int j = 0; j < 8; ++j) ones[j] = (short)0x3F80;
  WAIT_VM0();

  const ushort* kg = K + ((size_t)(b * 8 + hkv)) * 2048 * 128;
  const ushort* vg = V + ((size_t)(b * 8 + hkv)) * 128 * 2048;

#define STAGE_KV(buf, s0_) do {                                              \
    _Pragma("unroll") for (int i_ = 0; i_ < 2; ++i_)                         \
      gload16(kg + (size_t)((s0_) + i_ * 32 + (t >> 4)) * 128 + kcol,        \
              (char*)Kl + (buf) * 16384 + i_ * 8192 + t * 16);               \
    _Pragma("unroll") for (int i_ = 0; i_ < 2; ++i_)                         \
      gload16(vg + (size_t)(i_ * 64 + (t >> 3)) * 2048 + (s0_) + vcol,       \
              (char*)Vl + (buf) * 16384 + i_ * 8192 + t * 16);               \
  } while (0)

  f32x4 accO[8];
#pragma unroll
  for (int i = 0; i < 8; ++i) accO[i] = fzero;
  float m_r[4] = {-1e30f, -1e30f, -1e30f, -1e30f};
  float l_r[4] = {0.f, 0.f, 0.f, 0.f};
  const int qrow = qb * 128 + w * 16 + lg * 4;
  const int wrow0 = qb * 128 + w * 16;
  const int jend = 2 * qb + 1;

  STAGE_KV(0, 0);
  for (int j = 0; j <= jend; ++j) {
    if (j < jend) { STAGE_KV((j + 1) & 1, (j + 1) * 64); WAIT_VM4(); }
    else          { WAIT_VM0(); }
    BARRIER();
    const ushort* Kb = Kl + (j & 1) * 8192;
    const ushort* Vb = Vl + (j & 1) * 8192;

    f32x4 sc[4];
#pragma unroll
    for (int ni = 0; ni < 4; ++ni) sc[ni] = fzero;
    __builtin_amdgcn_s_setprio(1);
#pragma unroll
    for (int ni = 0; ni < 4; ++ni)
#pragma unroll
      for (int ks = 0; ks < 4; ++ks) {
        bf16x8 kf = *(const bf16x8*)(Kb + (ni * 16 + lr) * 128 + ksw[ks]);
        sc[ni] = __builtin_amdgcn_mfma_f32_16x16x32_bf16(qf[ks], kf, sc[ni], 0, 0, 0);
      }
    __builtin_amdgcn_s_setprio(0);
    if (j * 64 + 63 > wrow0) {
#pragma unroll
      for (int ni = 0; ni < 4; ++ni)
#pragma unroll
        for (int r = 0; r < 4; ++r)
          if (j * 64 + ni * 16 + lr > qrow + r) sc[ni][r] = -1e30f;
    }
    float mx[4];
#pragma unroll
    for (int r = 0; r < 4; ++r) {
      float v = fmaxf(fmaxf(sc[0][r], sc[1][r]), fmaxf(sc[2][r], sc[3][r]));
#pragma unroll
      for (int m = 8; m; m >>= 1) v = fmaxf(v, __shfl_xor(v, m));
      mx[r] = v;
    }
    bool ok = mx[0] <= m_r[0] + 8.f && mx[1] <= m_r[1] + 8.f &&
              mx[2] <= m_r[2] + 8.f && mx[3] <= m_r[3] + 8.f;
    if (!__all(ok)) {
#pragma unroll
      for (int r = 0; r < 4; ++r) {
        float mnew = fmaxf(m_r[r], mx[r]);
        float fsc = exp2f(m_r[r] - mnew);
        l_r[r] *= fsc;
        m_r[r] = mnew;
#pragma unroll
        for (int i = 0; i < 8; ++i) accO[i][r] *= fsc;
      }
    }
#pragma unroll
    for (int ni = 0; ni < 4; ++ni)
#pragma unroll
      for (int r = 0; r < 4; ++r) {
        int prow = w * 16 + lg * 4 + r;
        int slot = (ni * 2 + (lr >> 3)) ^ (prow & 7);
        Pl[prow * 64 + slot * 8 + rm] = f2bf(exp2f(sc[ni][r] - m_r[r]));
      }
    WAIT_LGKM0();
    f32x4 accL = fzero;
    __builtin_amdgcn_s_setprio(1);
#pragma unroll
    for (int ks = 0; ks < 2; ++ks) {
      bf16x8 pf = *(const bf16x8*)(Pl + (w * 16 + lr) * 64 + vsw[ks]);
#pragma unroll
      for (int nf = 0; nf < 8; ++nf) {
        bf16x8 vf = *(const bf16x8*)(Vb + (nf * 16 + lr) * 64 + vsw[ks]);
        accO[nf] = __builtin_amdgcn_mfma_f32_16x16x32_bf16(pf, vf, accO[nf], 0, 0, 0);
      }
      accL = __builtin_amdgcn_mfma_f32_16x16x32_bf16(pf, ones, accL, 0, 0, 0);
    }
    __builtin_amdgcn_s_setprio(0);
#pragma unroll
    for (int r = 0; r < 4; ++r) l_r[r] += accL[r];
    BARRIER();
  }
#undef STAGE_KV
  float invl[4];
#pragma unroll
  for (int r = 0; r < 4; ++r) invl[r] = 1.f / l_r[r];
#pragma unroll
  for (int nf = 0; nf < 8; ++nf)
#pragma unroll
    for (int r = 0; r < 4; ++r) {
      int q = qb * 128 + w * 16 + lg * 4 + r;
      int d = nf * 16 + lr;
      O[((size_t)(b * 2048 + q)) * 4096 + h * 128 + d] = f2bf(accO[nf][r] * invl[r]);
    }
}

// ------------------------------ launcher -----------------------------------
#define OFF_A     ((size_t)0)           // qkvb | W3 | act
#define OFF_B     ((size_t)90177536)    // W4
#define OFF_D     ((size_t)180355072)   // W1 | tab/Qr/Kr/Vt | gate
#define OFF_C     ((size_t)270532608)   // W2 | W5
#define OFF_E     ((size_t)360710144)   // xn | attnb | xn
#define OFF_TAB   (OFF_D)
#define OFF_QR    (OFF_D + 1048576)
#define OFF_KR    (OFF_D + 34603008)
#define OFF_VT    (OFF_D + 42991616)
#define WS_NEED   ((size_t)416284672)

extern "C" void kernel_launch(void* const* d_in, const int* in_sizes, int n_in,
                              void* d_out, int out_size, void* d_ws,
                              size_t ws_size, hipStream_t stream) {
  (void)in_sizes; (void)n_in; (void)out_size;
  if (ws_size < WS_NEED) return;
  const float* hs     = (const float*)d_in[0];
  const int*   pos    = (const int*)d_in[1];
  const float* w_qkv  = (const float*)d_in[2];
  const float* w_o    = (const float*)d_in[3];
  const float* w_gu   = (const float*)d_in[4];
  const float* w_down = (const float*)d_in[5];
  const float* ln1    = (const float*)d_in[6];
  const float* ln2    = (const float*)d_in[7];
  float* out = (float*)d_out;
  float* h1  = (float*)d_out;          // residual stream lives in d_out
  char* ws = (char*)d_ws;

  ushort* qkvb  = (ushort*)(ws + OFF_A);
  ushort* W3    = (ushort*)(ws + OFF_A);
  ushort* act   = (ushort*)(ws + OFF_A);
  ushort* W4    = (ushort*)(ws + OFF_B);
  ushort* W1    = (ushort*)(ws + OFF_D);
  ushort* gate  = (ushort*)(ws + OFF_D);
  float2* tab   = (float2*)(ws + OFF_TAB);
  ushort* Qr    = (ushort*)(ws + OFF_QR);
  ushort* Kr    = (ushort*)(ws + OFF_KR);
  ushort* Vt    = (ushort*)(ws + OFF_VT);
  ushort* W2    = (ushort*)(ws + OFF_C);
  ushort* W5    = (ushort*)(ws + OFF_C);
  ushort* xn    = (ushort*)(ws + OFF_E);
  ushort* attnb = (ushort*)(ws + OFF_E);

  auto kb = gemm256_kernel<ushort, false>;
  auto kf = gemm256_kernel<float, true>;
  hipFuncSetAttribute((const void*)kb, hipFuncAttributeMaxDynamicSharedMemorySize, 131072);
  hipFuncSetAttribute((const void*)kf, hipFuncAttributeMaxDynamicSharedMemorySize, 131072);
  hipFuncSetAttribute((const void*)gemm256_tc_kernel, hipFuncAttributeMaxDynamicSharedMemorySize, 131072);
  hipFuncSetAttribute((const void*)gemm256_swiglu_kernel, hipFuncAttributeMaxDynamicSharedMemorySize, 131072);
  hipFuncSetAttribute((const void*)attn_tc_kernel, hipFuncAttributeMaxDynamicSharedMemorySize, 81920);

  // s1: rmsnorm1 -> xn(E)
  rmsnorm_kernel<<<4096, 256, 0, stream>>>(hs, ln1, xn);
  // s2: transpose w_qkv -> W1(D) (exposed, small)
  transpose_cast_kernel<<<dim3(64, 96), 256, 0, stream>>>(w_qkv, W1, 6144, 0, 4096);
  // s3: qkv GEMM -> qkvb(A)
  gemm256_kernel<ushort, false><<<384, 512, 131072, stream>>>(
      xn, W1, qkvb, nullptr, 4096, 6144, 4096);
  // s4: rope -> tab/Qr/Kr/Vt (D, over W1)
  rope_table_kernel<<<512, 256, 0, stream>>>(pos, tab);
  rope_scatter_kernel<<<dim3(64, 48), 256, 0, stream>>>(qkvb, tab, Qr, Kr, Vt);
  // s5: attn -> attnb(E) + hidden transposes (w_gu p1->W3(A), p2->W4(B), w_o->W2(C))
  attn_tc_kernel<<<1024 + 5504 + 5504 + 2048, 512, 81920, stream>>>(
      Qr, Kr, Vt, attnb,
      w_gu, W3, 22016, 0,     4096, 64, 5504,
      w_gu, W4, 22016, 11008, 4096, 64, 5504,
      w_o,  W2, 4096,  0,     4096, 64, 2048);
  // s7: o-proj (residual hs) -> h1 (= d_out)
  gemm256_kernel<float, true><<<256, 512, 131072, stream>>>(
      attnb, W2, h1, hs, 4096, 4096, 4096);
  // s8: rmsnorm2 -> xn(E, over attnb)
  rmsnorm_kernel<<<4096, 256, 0, stream>>>(h1, ln2, xn);
  // s9: gate GEMM -> gate(D) + hidden transpose (w_down -> W5(C, over W2))
  gemm256_tc_kernel<<<688 + 5504, 512, 131072, stream>>>(
      xn, W3, gate, 4096, 11008, 4096,
      w_down, W5, 4096, 0, 11008, 172);
  // s10: up GEMM + fused SwiGLU -> act(A, over W3)
  gemm256_swiglu_kernel<<<688, 512, 131072, stream>>>(
      xn, W4, act, gate, 4096, 11008, 4096);
  // s12: down GEMM, residual h1 (= d_out), same-index in-place write
  gemm256_kernel<float, true><<<256, 512, 131072, stream>>>(
      act, W5, out, h1, 4096, 4096, 11008);
}

// Round 15
// 1726.170 us; speedup vs baseline: 1.1386x; 1.0007x over previous
//
#include <hip/hip_runtime.h>

// ---------------------------------------------------------------------------
// Llama decoder layer, MI355X (gfx950).
// B=2 S=2048 HIDDEN=4096 HQ=32 HKV=8 D=128 INTER=11008, fp32 in/out.
// R15: fuse the three independent front-of-graph launches into pre_kernel:
// blocks [0,4096) rmsnorm1 (512-thr variant), [4096,7168) w_qkv->W1
// transpose512 jobs, [7168,7424) rope_table. tab relocated to region B
// (was overlapping W1; B is free until s5). All GEMM/attn/tc kernels
// byte-identical to R14 (rule #19).
// Overlay lifetimes (audited):
//  A: qkvb(s3-s4) | W3(s5-s9) | act(s10-s12)
//  B: tab(s1-s4) | W4(s5-s10)
//  D: W1(s1-s3) | Qr/Kr/Vt(s4-s5) | gate(s9-s10)
//  C: W2(s5-s7) | W5(s9-s12)
//  E: xn(s1-s3) | attnb(s5-s7) | xn(s8-s10)
// h1 lives in d_out (same-index read-then-write in down-GEMM epilogue).
// ---------------------------------------------------------------------------

typedef __attribute__((ext_vector_type(8))) short bf16x8;
typedef __attribute__((ext_vector_type(4))) float f32x4;

__device__ __forceinline__ ushort f2bf(float f) {           // RNE fp32->bf16
  unsigned u = __float_as_uint(f);
  return (ushort)((u + 0x7fffu + ((u >> 16) & 1u)) >> 16);
}
__device__ __forceinline__ float bf2f(ushort u) {
  union { unsigned u32; float f; } x; x.u32 = ((unsigned)u) << 16; return x.f;
}
__device__ __forceinline__ void gload16(const void* g, void* l) {
  __builtin_amdgcn_global_load_lds((__attribute__((address_space(1))) void*)g,
                                   (__attribute__((address_space(3))) void*)l,
                                   16, 0, 0);
}

#define BARRIER() asm volatile("s_barrier" ::: "memory")
#define WAIT_LGKM0() asm volatile("s_waitcnt lgkmcnt(0)" ::: "memory")
#define WAIT_VM4() asm volatile("s_waitcnt vmcnt(4)" ::: "memory")
#define WAIT_VM0() asm volatile("s_waitcnt vmcnt(0)" ::: "memory")

// --------------------------- RMSNorm (fp32 -> bf16) ------------------------
__global__ __launch_bounds__(256) void rmsnorm_kernel(
    const float* __restrict__ x, const float* __restrict__ g,
    ushort* __restrict__ out) {
  const int row = blockIdx.x, t = threadIdx.x;
  const float4* xp = (const float4*)(x + (size_t)row * 4096);
  float4 v[4]; float ss = 0.f;
#pragma unroll
  for (int i = 0; i < 4; ++i) {
    v[i] = xp[t + i * 256];
    ss += v[i].x * v[i].x + v[i].y * v[i].y + v[i].z * v[i].z + v[i].w * v[i].w;
  }
#pragma unroll
  for (int m = 32; m; m >>= 1) ss += __shfl_xor(ss, m);
  __shared__ float red[4];
  if ((t & 63) == 0) red[t >> 6] = ss;
  __syncthreads();
  float inv = rsqrtf((red[0] + red[1] + red[2] + red[3]) * (1.f / 4096.f) + 1e-6f);
  const float4* gp = (const float4*)g;
  ushort* op = out + (size_t)row * 4096;
#pragma unroll
  for (int i = 0; i < 4; ++i) {
    float4 gv = gp[t + i * 256];
    ushort4 o;
    o.x = f2bf(v[i].x * inv * gv.x); o.y = f2bf(v[i].y * inv * gv.y);
    o.z = f2bf(v[i].z * inv * gv.z); o.w = f2bf(v[i].w * inv * gv.w);
    *(ushort4*)(op + (size_t)(t + i * 256) * 4) = o;
  }
}

// ------- 512-thread transpose helper (2 x 64x64 tiles per block) -----------
__device__ __forceinline__ void transpose512(
    const float* __restrict__ in, ushort* __restrict__ out,
    int ld_in, int col_off, int R, int ntx, int tbid, ushort* ldsb, int t) {
  const int half = t >> 8, tt = t & 255;
  ushort* tile = ldsb + half * (64 * 65);
  const int x = tbid % ntx, yy = tbid / ntx;
  const int r0 = x * 64, c0 = (yy * 2 + half) * 64;
  const int rl = tt >> 2, cl = (tt & 3) * 16;
  const float* ip = in + (size_t)(r0 + rl) * ld_in + col_off + c0 + cl;
#pragma unroll
  for (int i = 0; i < 4; ++i) {
    float4 f = ((const float4*)ip)[i];
    tile[rl * 65 + cl + i * 4 + 0] = f2bf(f.x);
    tile[rl * 65 + cl + i * 4 + 1] = f2bf(f.y);
    tile[rl * 65 + cl + i * 4 + 2] = f2bf(f.z);
    tile[rl * 65 + cl + i * 4 + 3] = f2bf(f.w);
  }
  __syncthreads();
  union { ushort us[8]; uint4 v; } pk0, pk1;
#pragma unroll
  for (int j = 0; j < 8; ++j) pk0.us[j] = tile[(cl + j) * 65 + rl];
#pragma unroll
  for (int j = 0; j < 8; ++j) pk1.us[j] = tile[(cl + 8 + j) * 65 + rl];
  uint4* op = (uint4*)(out + (size_t)(c0 + rl) * R + r0 + cl);
  op[0] = pk0.v; op[1] = pk1.v;
}

// ---- fused front: rmsnorm1 + w_qkv transpose + rope table (independent) ---
__global__ __launch_bounds__(512) void pre_kernel(
    const float* __restrict__ hs, const float* __restrict__ ln1,
    ushort* __restrict__ xn, const float* __restrict__ wq,
    ushort* __restrict__ W1, const int* __restrict__ pos,
    float2* __restrict__ tab) {
  __shared__ ushort sm[2 * 64 * 65];
  const int bid = (int)blockIdx.x, t = threadIdx.x;
  if (bid < 4096) {              // rmsnorm row = bid, 8 floats/thread
    const float4* xp = (const float4*)(hs + (size_t)bid * 4096);
    float4 v0 = xp[t], v1 = xp[t + 512];
    float ss = v0.x * v0.x + v0.y * v0.y + v0.z * v0.z + v0.w * v0.w +
               v1.x * v1.x + v1.y * v1.y + v1.z * v1.z + v1.w * v1.w;
#pragma unroll
    for (int m = 32; m; m >>= 1) ss += __shfl_xor(ss, m);
    float* redf = (float*)sm;
    if ((t & 63) == 0) redf[t >> 6] = ss;
    __syncthreads();
    float tot = redf[0] + redf[1] + redf[2] + redf[3] +
                redf[4] + redf[5] + redf[6] + redf[7];
    float inv = rsqrtf(tot * (1.f / 4096.f) + 1e-6f);
    const float4* gp = (const float4*)ln1;
    float4 g0 = gp[t], g1 = gp[t + 512];
    ushort* op = xn + (size_t)bid * 4096;
    ushort4 o0, o1;
    o0.x = f2bf(v0.x * inv * g0.x); o0.y = f2bf(v0.y * inv * g0.y);
    o0.z = f2bf(v0.z * inv * g0.z); o0.w = f2bf(v0.w * inv * g0.w);
    o1.x = f2bf(v1.x * inv * g1.x); o1.y = f2bf(v1.y * inv * g1.y);
    o1.z = f2bf(v1.z * inv * g1.z); o1.w = f2bf(v1.w * inv * g1.w);
    *(ushort4*)(op + (size_t)t * 4) = o0;
    *(ushort4*)(op + (size_t)(t + 512) * 4) = o1;
  } else if (bid < 4096 + 3072) {  // w_qkv[4096,6144] -> W1[6144,4096]
    transpose512(wq, W1, 6144, 0, 4096, 64, bid - 4096, sm, t);
  } else {                          // rope table, idx over 2048*64
    int idx = (bid - 7168) * 512 + t;
    int s = idx >> 6, fi = idx & 63;
    float inv = (float)exp(-(double)(2 * fi) / 128.0 * 9.210340371976184);
    float a = (float)pos[s] * inv;
    tab[idx] = make_float2(cosf(a), sinf(a));
  }
}

// ------------------------- GEMM 256x256 8-phase ----------------------------
// Byte-identical to R8..R14 (R4 body + col-major XCD chunk mapping).
template <typename OutT, bool RES>
__global__ __launch_bounds__(512, 2) void gemm256_kernel(
    const ushort* __restrict__ A, const ushort* __restrict__ Bt,
    OutT* __restrict__ C, const float* __restrict__ res,
    int M, int N, int K) {
  extern __shared__ ushort lds[];
  ushort* Al = lds;            // [buf:2][half:2][8192 ushorts]
  ushort* Bl = lds + 32768;
  const int t = threadIdx.x, l = t & 63, w = t >> 6;
  const int wr = w >> 2, wc = w & 3;
  const int lr = l & 15, lg = l >> 4;
  const int rhi = lr >> 3, rlo = lr & 7;
  const int srow = l >> 3, sg = (l & 7) ^ srow;

  const int nby = M >> 8;
  const int nwg = (N >> 8) * nby;
  const int cpx = nwg >> 3;
  const int bid = (int)blockIdx.x;
  const int swz = (bid & 7) * cpx + (bid >> 3);   // XCD chunk (nwg%8==0)
  const int m0 = (swz % nby) << 8;                // col-major: B panel shared
  const int n0 = (swz / nby) << 8;                // by 16 consecutive blocks

  const int lof0 = rhi * 512 + rlo * 64 + ((0 + lg) ^ rlo) * 8;  // kk=0
  const int lof1 = rhi * 512 + rlo * 64 + ((4 + lg) ^ rlo) * 8;  // kk=1

  const f32x4 fz = {0.f, 0.f, 0.f, 0.f};
  f32x4 acc[8][4];
#pragma unroll
  for (int i = 0; i < 8; ++i)
#pragma unroll
    for (int j = 0; j < 4; ++j) acc[i][j] = fz;
  bf16x8 a[8][2];
  bf16x8 bq[2][2];

  const ushort* Asrc = A + (size_t)(m0 + w * 8 + srow) * K + sg * 8;
  const ushort* Bsrc = Bt + (size_t)(n0 + w * 8 + srow) * K + sg * 8;
  const size_t rK64 = (size_t)64 * K, rK128 = (size_t)128 * K;
  ushort* Adst = Al + w * 512;
  ushort* Bdst = Bl + w * 512;

#define STAGE_A(buf, half, tile) do {                                   \
    const ushort* s_ = Asrc + (size_t)(half) * rK128 + ((tile) << 6);   \
    ushort* d_ = Adst + (buf) * 16384 + (half) * 8192;                  \
    gload16(s_, d_);                                                    \
    gload16(s_ + rK64, d_ + 4096);                                      \
  } while (0)
#define STAGE_B(buf, half, tile) do {                                   \
    const ushort* s_ = Bsrc + (size_t)(half) * rK128 + ((tile) << 6);   \
    ushort* d_ = Bdst + (buf) * 16384 + (half) * 8192;                  \
    gload16(s_, d_);                                                    \
    gload16(s_ + rK64, d_ + 4096);                                      \
  } while (0)
#define LDA4(AH, QM) do {                                                   \
    _Pragma("unroll") for (int mi_ = 0; mi_ < 4; ++mi_) {                   \
      a[(QM) * 4 + mi_][0] =                                                \
          *(const bf16x8*)((AH) + ((QM) * 4 + mi_) * 1024 + lof0);          \
      a[(QM) * 4 + mi_][1] =                                                \
          *(const bf16x8*)((AH) + ((QM) * 4 + mi_) * 1024 + lof1);          \
    } } while (0)
#define LDB2(BH, NQ) do {                                                   \
    _Pragma("unroll") for (int nj_ = 0; nj_ < 2; ++nj_) {                   \
      bq[nj_][0] = *(const bf16x8*)((BH) + ((NQ) * 2 + nj_) * 1024 + lof0); \
      bq[nj_][1] = *(const bf16x8*)((BH) + ((NQ) * 2 + nj_) * 1024 + lof1); \
    } } while (0)
#define MFMA16(QM, QN)                                                      \
    __builtin_amdgcn_s_setprio(1);                                          \
    _Pragma("unroll") for (int mi_ = 0; mi_ < 4; ++mi_)                     \
    _Pragma("unroll") for (int nj_ = 0; nj_ < 2; ++nj_) {                   \
      acc[(QM) * 4 + mi_][(QN) * 2 + nj_] =                                 \
          __builtin_amdgcn_mfma_f32_16x16x32_bf16(                          \
              a[(QM) * 4 + mi_][0], bq[nj_][0],                             \
              acc[(QM) * 4 + mi_][(QN) * 2 + nj_], 0, 0, 0);                \
      acc[(QM) * 4 + mi_][(QN) * 2 + nj_] =                                 \
          __builtin_amdgcn_mfma_f32_16x16x32_bf16(                          \
              a[(QM) * 4 + mi_][1], bq[nj_][1],                             \
              acc[(QM) * 4 + mi_][(QN) * 2 + nj_], 0, 0, 0);                \
    }                                                                       \
    __builtin_amdgcn_s_setprio(0);

  const ushort* A0h = Al + wr * 8192;
  const ushort* A1h = A0h + 16384;
  const ushort* B0h = Bl + (wc >> 1) * 8192 + (wc & 1) * 4096;
  const ushort* B1h = B0h + 16384;

  const int ntiles = K >> 6, nIter = K >> 7;
  // prologue: tile0 full -> buf0; tile1 A halves -> buf1
  STAGE_A(0, 0, 0); STAGE_A(0, 1, 0); STAGE_B(0, 0, 0); STAGE_B(0, 1, 0);
  STAGE_A(1, 0, 1); STAGE_A(1, 1, 1);
  WAIT_VM4(); BARRIER();

  for (int it = 0; it < nIter; ++it) {
    const int u = it * 2;
    // ---- tile u (buf0) ----
    LDA4(A0h, 0); LDB2(B0h, 0);                 // P1
    STAGE_B(1, 0, u + 1);
    BARRIER(); WAIT_LGKM0(); MFMA16(0, 0); BARRIER();
    LDA4(A0h, 1);                               // P2
    STAGE_B(1, 1, u + 1);
    BARRIER(); WAIT_LGKM0(); MFMA16(1, 0); BARRIER();
    LDB2(B0h, 1);                               // P3
    if (u + 2 < ntiles) STAGE_A(0, 0, u + 2);
    BARRIER(); WAIT_LGKM0(); MFMA16(0, 1); BARRIER();
    if (u + 2 < ntiles) STAGE_A(0, 1, u + 2);   // P4
    BARRIER(); MFMA16(1, 1);
    if (u + 2 < ntiles) { WAIT_VM4(); } else { WAIT_VM0(); }
    BARRIER();
    // ---- tile u+1 (buf1) ----
    LDA4(A1h, 0); LDB2(B1h, 0);                 // P5
    if (u + 2 < ntiles) STAGE_B(0, 0, u + 2);
    BARRIER(); WAIT_LGKM0(); MFMA16(0, 0); BARRIER();
    LDA4(A1h, 1);                               // P6
    if (u + 2 < ntiles) STAGE_B(0, 1, u + 2);
    BARRIER(); WAIT_LGKM0(); MFMA16(1, 0); BARRIER();
    LDB2(B1h, 1);                               // P7
    if (u + 3 < ntiles) STAGE_A(1, 0, u + 3);
    BARRIER(); WAIT_LGKM0(); MFMA16(0, 1); BARRIER();
    if (u + 3 < ntiles) STAGE_A(1, 1, u + 3);   // P8
    BARRIER(); MFMA16(1, 1);
    WAIT_VM4(); BARRIER();
  }

  // epilogue: C row = m0+wr*128+mi*16+lg*4+r, col = n0+wc*64+ni*16+lr
#pragma unroll
  for (int mi = 0; mi < 8; ++mi)
#pragma unroll
    for (int ni = 0; ni < 4; ++ni)
#pragma unroll
      for (int r = 0; r < 4; ++r) {
        int row = m0 + wr * 128 + mi * 16 + lg * 4 + r;
        int col = n0 + wc * 64 + ni * 16 + lr;
        size_t idx = (size_t)row * N + col;
        float v = acc[mi][ni][r];
        if (RES) v += res[idx];
        if constexpr (sizeof(OutT) == 2) C[idx] = f2bf(v);
        else                             C[idx] = v;
      }
#undef STAGE_A
#undef STAGE_B
#undef LDA4
#undef LDB2
#undef MFMA16
}

// ----------- GEMM (bf16 out, no res) + hidden transpose tail ---------------
// Byte-identical to R14.
__global__ __launch_bounds__(512, 2) void gemm256_tc_kernel(
    const ushort* __restrict__ A, const ushort* __restrict__ Bt,
    ushort* __restrict__ C, int M, int N, int K,
    const float* tin, ushort* tout, int tld, int toff, int tR, int tntx) {
  extern __shared__ ushort lds[];
  const int nby = M >> 8;
  const int nwg = (N >> 8) * nby;
  const int bid = (int)blockIdx.x;
  const int t = threadIdx.x;
  if (bid >= nwg) {                        // transpose tail blocks
    transpose512(tin, tout, tld, toff, tR, tntx, bid - nwg, lds, t);
    return;
  }
  ushort* Al = lds;
  ushort* Bl = lds + 32768;
  const int l = t & 63, w = t >> 6;
  const int wr = w >> 2, wc = w & 3;
  const int lr = l & 15, lg = l >> 4;
  const int rhi = lr >> 3, rlo = lr & 7;
  const int srow = l >> 3, sg = (l & 7) ^ srow;

  const int cpx = nwg >> 3;
  const int swz = (bid & 7) * cpx + (bid >> 3);
  const int m0 = (swz % nby) << 8;
  const int n0 = (swz / nby) << 8;

  const int lof0 = rhi * 512 + rlo * 64 + ((0 + lg) ^ rlo) * 8;
  const int lof1 = rhi * 512 + rlo * 64 + ((4 + lg) ^ rlo) * 8;

  const f32x4 fz = {0.f, 0.f, 0.f, 0.f};
  f32x4 acc[8][4];
#pragma unroll
  for (int i = 0; i < 8; ++i)
#pragma unroll
    for (int j = 0; j < 4; ++j) acc[i][j] = fz;
  bf16x8 a[8][2];
  bf16x8 bq[2][2];

  const ushort* Asrc = A + (size_t)(m0 + w * 8 + srow) * K + sg * 8;
  const ushort* Bsrc = Bt + (size_t)(n0 + w * 8 + srow) * K + sg * 8;
  const size_t rK64 = (size_t)64 * K, rK128 = (size_t)128 * K;
  ushort* Adst = Al + w * 512;
  ushort* Bdst = Bl + w * 512;

#define STAGE_A(buf, half, tile) do {                                   \
    const ushort* s_ = Asrc + (size_t)(half) * rK128 + ((tile) << 6);   \
    ushort* d_ = Adst + (buf) * 16384 + (half) * 8192;                  \
    gload16(s_, d_);                                                    \
    gload16(s_ + rK64, d_ + 4096);                                      \
  } while (0)
#define STAGE_B(buf, half, tile) do {                                   \
    const ushort* s_ = Bsrc + (size_t)(half) * rK128 + ((tile) << 6);   \
    ushort* d_ = Bdst + (buf) * 16384 + (half) * 8192;                  \
    gload16(s_, d_);                                                    \
    gload16(s_ + rK64, d_ + 4096);                                      \
  } while (0)
#define LDA4(AH, QM) do {                                                   \
    _Pragma("unroll") for (int mi_ = 0; mi_ < 4; ++mi_) {                   \
      a[(QM) * 4 + mi_][0] =                                                \
          *(const bf16x8*)((AH) + ((QM) * 4 + mi_) * 1024 + lof0);          \
      a[(QM) * 4 + mi_][1] =                                                \
          *(const bf16x8*)((AH) + ((QM) * 4 + mi_) * 1024 + lof1);          \
    } } while (0)
#define LDB2(BH, NQ) do {                                                   \
    _Pragma("unroll") for (int nj_ = 0; nj_ < 2; ++nj_) {                   \
      bq[nj_][0] = *(const bf16x8*)((BH) + ((NQ) * 2 + nj_) * 1024 + lof0); \
      bq[nj_][1] = *(const bf16x8*)((BH) + ((NQ) * 2 + nj_) * 1024 + lof1); \
    } } while (0)
#define MFMA16(QM, QN)                                                      \
    __builtin_amdgcn_s_setprio(1);                                          \
    _Pragma("unroll") for (int mi_ = 0; mi_ < 4; ++mi_)                     \
    _Pragma("unroll") for (int nj_ = 0; nj_ < 2; ++nj_) {                   \
      acc[(QM) * 4 + mi_][(QN) * 2 + nj_] =                                 \
          __builtin_amdgcn_mfma_f32_16x16x32_bf16(                          \
              a[(QM) * 4 + mi_][0], bq[nj_][0],                             \
              acc[(QM) * 4 + mi_][(QN) * 2 + nj_], 0, 0, 0);                \
      acc[(QM) * 4 + mi_][(QN) * 2 + nj_] =                                 \
          __builtin_amdgcn_mfma_f32_16x16x32_bf16(                          \
              a[(QM) * 4 + mi_][1], bq[nj_][1],                             \
              acc[(QM) * 4 + mi_][(QN) * 2 + nj_], 0, 0, 0);                \
    }                                                                       \
    __builtin_amdgcn_s_setprio(0);

  const ushort* A0h = Al + wr * 8192;
  const ushort* A1h = A0h + 16384;
  const ushort* B0h = Bl + (wc >> 1) * 8192 + (wc & 1) * 4096;
  const ushort* B1h = B0h + 16384;

  const int ntiles = K >> 6, nIter = K >> 7;
  STAGE_A(0, 0, 0); STAGE_A(0, 1, 0); STAGE_B(0, 0, 0); STAGE_B(0, 1, 0);
  STAGE_A(1, 0, 1); STAGE_A(1, 1, 1);
  WAIT_VM4(); BARRIER();

  for (int it = 0; it < nIter; ++it) {
    const int u = it * 2;
    LDA4(A0h, 0); LDB2(B0h, 0);
    STAGE_B(1, 0, u + 1);
    BARRIER(); WAIT_LGKM0(); MFMA16(0, 0); BARRIER();
    LDA4(A0h, 1);
    STAGE_B(1, 1, u + 1);
    BARRIER(); WAIT_LGKM0(); MFMA16(1, 0); BARRIER();
    LDB2(B0h, 1);
    if (u + 2 < ntiles) STAGE_A(0, 0, u + 2);
    BARRIER(); WAIT_LGKM0(); MFMA16(0, 1); BARRIER();
    if (u + 2 < ntiles) STAGE_A(0, 1, u + 2);
    BARRIER(); MFMA16(1, 1);
    if (u + 2 < ntiles) { WAIT_VM4(); } else { WAIT_VM0(); }
    BARRIER();
    LDA4(A1h, 0); LDB2(B1h, 0);
    if (u + 2 < ntiles) STAGE_B(0, 0, u + 2);
    BARRIER(); WAIT_LGKM0(); MFMA16(0, 0); BARRIER();
    LDA4(A1h, 1);
    if (u + 2 < ntiles) STAGE_B(0, 1, u + 2);
    BARRIER(); WAIT_LGKM0(); MFMA16(1, 0); BARRIER();
    LDB2(B1h, 1);
    if (u + 3 < ntiles) STAGE_A(1, 0, u + 3);
    BARRIER(); WAIT_LGKM0(); MFMA16(0, 1); BARRIER();
    if (u + 3 < ntiles) STAGE_A(1, 1, u + 3);
    BARRIER(); MFMA16(1, 1);
    WAIT_VM4(); BARRIER();
  }

#pragma unroll
  for (int mi = 0; mi < 8; ++mi)
#pragma unroll
    for (int ni = 0; ni < 4; ++ni)
#pragma unroll
      for (int r = 0; r < 4; ++r) {
        int row = m0 + wr * 128 + mi * 16 + lg * 4 + r;
        int col = n0 + wc * 64 + ni * 16 + lr;
        size_t idx = (size_t)row * N + col;
        C[idx] = f2bf(acc[mi][ni][r]);
      }
#undef STAGE_A
#undef STAGE_B
#undef LDA4
#undef LDB2
#undef MFMA16
}

// ---------------- GEMM 256x256 8-phase, fused-SwiGLU epilogue --------------
// Byte-identical to R12..R14. out = silu(gate) * (A*Bt^T), bf16.
__global__ __launch_bounds__(512, 2) void gemm256_swiglu_kernel(
    const ushort* __restrict__ A, const ushort* __restrict__ Bt,
    ushort* __restrict__ C, const ushort* __restrict__ gate,
    int M, int N, int K) {
  extern __shared__ ushort lds[];
  ushort* Al = lds;
  ushort* Bl = lds + 32768;
  const int t = threadIdx.x, l = t & 63, w = t >> 6;
  const int wr = w >> 2, wc = w & 3;
  const int lr = l & 15, lg = l >> 4;
  const int rhi = lr >> 3, rlo = lr & 7;
  const int srow = l >> 3, sg = (l & 7) ^ srow;

  const int nby = M >> 8;
  const int nwg = (N >> 8) * nby;
  const int cpx = nwg >> 3;
  const int bid = (int)blockIdx.x;
  const int swz = (bid & 7) * cpx + (bid >> 3);
  const int m0 = (swz % nby) << 8;
  const int n0 = (swz / nby) << 8;

  const int lof0 = rhi * 512 + rlo * 64 + ((0 + lg) ^ rlo) * 8;
  const int lof1 = rhi * 512 + rlo * 64 + ((4 + lg) ^ rlo) * 8;

  const f32x4 fz = {0.f, 0.f, 0.f, 0.f};
  f32x4 acc[8][4];
#pragma unroll
  for (int i = 0; i < 8; ++i)
#pragma unroll
    for (int j = 0; j < 4; ++j) acc[i][j] = fz;
  bf16x8 a[8][2];
  bf16x8 bq[2][2];

  const ushort* Asrc = A + (size_t)(m0 + w * 8 + srow) * K + sg * 8;
  const ushort* Bsrc = Bt + (size_t)(n0 + w * 8 + srow) * K + sg * 8;
  const size_t rK64 = (size_t)64 * K, rK128 = (size_t)128 * K;
  ushort* Adst = Al + w * 512;
  ushort* Bdst = Bl + w * 512;

#define STAGE_A(buf, half, tile) do {                                   \
    const ushort* s_ = Asrc + (size_t)(half) * rK128 + ((tile) << 6);   \
    ushort* d_ = Adst + (buf) * 16384 + (half) * 8192;                  \
    gload16(s_, d_);                                                    \
    gload16(s_ + rK64, d_ + 4096);                                      \
  } while (0)
#define STAGE_B(buf, half, tile) do {                                   \
    const ushort* s_ = Bsrc + (size_t)(half) * rK128 + ((tile) << 6);   \
    ushort* d_ = Bdst + (buf) * 16384 + (half) * 8192;                  \
    gload16(s_, d_);                                                    \
    gload16(s_ + rK64, d_ + 4096);                                      \
  } while (0)
#define LDA4(AH, QM) do {                                                   \
    _Pragma("unroll") for (int mi_ = 0; mi_ < 4; ++mi_) {                   \
      a[(QM) * 4 + mi_][0] =                                                \
          *(const bf16x8*)((AH) + ((QM) * 4 + mi_) * 1024 + lof0);          \
      a[(QM) * 4 + mi_][1] =                                                \
          *(const bf16x8*)((AH) + ((QM) * 4 + mi_) * 1024 + lof1);          \
    } } while (0)
#define LDB2(BH, NQ) do {                                                   \
    _Pragma("unroll") for (int nj_ = 0; nj_ < 2; ++nj_) {                   \
      bq[nj_][0] = *(const bf16x8*)((BH) + ((NQ) * 2 + nj_) * 1024 + lof0); \
      bq[nj_][1] = *(const bf16x8*)((BH) + ((NQ) * 2 + nj_) * 1024 + lof1); \
    } } while (0)
#define MFMA16(QM, QN)                                                      \
    __builtin_amdgcn_s_setprio(1);                                          \
    _Pragma("unroll") for (int mi_ = 0; mi_ < 4; ++mi_)                     \
    _Pragma("unroll") for (int nj_ = 0; nj_ < 2; ++nj_) {                   \
      acc[(QM) * 4 + mi_][(QN) * 2 + nj_] =                                 \
          __builtin_amdgcn_mfma_f32_16x16x32_bf16(                          \
              a[(QM) * 4 + mi_][0], bq[nj_][0],                             \
              acc[(QM) * 4 + mi_][(QN) * 2 + nj_], 0, 0, 0);                \
      acc[(QM) * 4 + mi_][(QN) * 2 + nj_] =                                 \
          __builtin_amdgcn_mfma_f32_16x16x32_bf16(                          \
              a[(QM) * 4 + mi_][1], bq[nj_][1],                             \
              acc[(QM) * 4 + mi_][(QN) * 2 + nj_], 0, 0, 0);                \
    }                                                                       \
    __builtin_amdgcn_s_setprio(0);

  const ushort* A0h = Al + wr * 8192;
  const ushort* A1h = A0h + 16384;
  const ushort* B0h = Bl + (wc >> 1) * 8192 + (wc & 1) * 4096;
  const ushort* B1h = B0h + 16384;

  const int ntiles = K >> 6, nIter = K >> 7;
  STAGE_A(0, 0, 0); STAGE_A(0, 1, 0); STAGE_B(0, 0, 0); STAGE_B(0, 1, 0);
  STAGE_A(1, 0, 1); STAGE_A(1, 1, 1);
  WAIT_VM4(); BARRIER();

  for (int it = 0; it < nIter; ++it) {
    const int u = it * 2;
    LDA4(A0h, 0); LDB2(B0h, 0);
    STAGE_B(1, 0, u + 1);
    BARRIER(); WAIT_LGKM0(); MFMA16(0, 0); BARRIER();
    LDA4(A0h, 1);
    STAGE_B(1, 1, u + 1);
    BARRIER(); WAIT_LGKM0(); MFMA16(1, 0); BARRIER();
    LDB2(B0h, 1);
    if (u + 2 < ntiles) STAGE_A(0, 0, u + 2);
    BARRIER(); WAIT_LGKM0(); MFMA16(0, 1); BARRIER();
    if (u + 2 < ntiles) STAGE_A(0, 1, u + 2);
    BARRIER(); MFMA16(1, 1);
    if (u + 2 < ntiles) { WAIT_VM4(); } else { WAIT_VM0(); }
    BARRIER();
    LDA4(A1h, 0); LDB2(B1h, 0);
    if (u + 2 < ntiles) STAGE_B(0, 0, u + 2);
    BARRIER(); WAIT_LGKM0(); MFMA16(0, 0); BARRIER();
    LDA4(A1h, 1);
    if (u + 2 < ntiles) STAGE_B(0, 1, u + 2);
    BARRIER(); WAIT_LGKM0(); MFMA16(1, 0); BARRIER();
    LDB2(B1h, 1);
    if (u + 3 < ntiles) STAGE_A(1, 0, u + 3);
    BARRIER(); WAIT_LGKM0(); MFMA16(0, 1); BARRIER();
    if (u + 3 < ntiles) STAGE_A(1, 1, u + 3);
    BARRIER(); MFMA16(1, 1);
    WAIT_VM4(); BARRIER();
  }

  // fused epilogue: out = silu(gate) * acc
#pragma unroll
  for (int mi = 0; mi < 8; ++mi)
#pragma unroll
    for (int ni = 0; ni < 4; ++ni)
#pragma unroll
      for (int r = 0; r < 4; ++r) {
        int row = m0 + wr * 128 + mi * 16 + lg * 4 + r;
        int col = n0 + wc * 64 + ni * 16 + lr;
        size_t idx = (size_t)row * N + col;
        float g = bf2f(gate[idx]);
        float s = g / (1.f + __expf(-g));
        C[idx] = f2bf(s * acc[mi][ni][r]);
      }
#undef STAGE_A
#undef STAGE_B
#undef LDA4
#undef LDB2
#undef MFMA16
}

// --------- RoPE + scatter qkv[T,6144] -> Qr[b,h,s,d] Kr[b,h,s,d] Vt[b,h,d,s]
__global__ __launch_bounds__(256) void rope_scatter_kernel(
    const ushort* __restrict__ qkv, const float2* __restrict__ tab,
    ushort* __restrict__ Qr, ushort* __restrict__ Kr, ushort* __restrict__ Vt) {
  __shared__ ushort vt[64][132];
  const int t = threadIdx.x, tt = blockIdx.x, h = blockIdx.y;  // h: 0..47
  const int row = t >> 2, c = (t & 3) * 16;
  const int tok = tt * 64 + row;
  const int b = tok >> 11, s = tok & 2047;
  const ushort* ip = qkv + (size_t)tok * 6144 + h * 128;
  union U { uint4 v; ushort us[8]; };
  U a0, a1, b0, b1;
  a0.v = *(const uint4*)(ip + c);      a1.v = *(const uint4*)(ip + c + 8);
  b0.v = *(const uint4*)(ip + c + 64); b1.v = *(const uint4*)(ip + c + 72);
  if (h < 40) {  // q or k head: NeoX rope on pairs (i, i+64)
    U o0, o1, o2, o3;
#pragma unroll
    for (int j = 0; j < 8; ++j) {
      float2 cs = tab[s * 64 + c + j];
      float x1 = bf2f(a0.us[j]), x2 = bf2f(b0.us[j]);
      o0.us[j] = f2bf(x1 * cs.x - x2 * cs.y);
      o2.us[j] = f2bf(x2 * cs.x + x1 * cs.y);
    }
#pragma unroll
    for (int j = 0; j < 8; ++j) {
      float2 cs = tab[s * 64 + c + 8 + j];
      float x1 = bf2f(a1.us[j]), x2 = bf2f(b1.us[j]);
      o1.us[j] = f2bf(x1 * cs.x - x2 * cs.y);
      o3.us[j] = f2bf(x2 * cs.x + x1 * cs.y);
    }
    ushort* base;
    if (h < 32) base = Qr + ((size_t)((b * 32 + h) * 2048 + s)) * 128;
    else        base = Kr + ((size_t)((b * 8 + (h - 32)) * 2048 + s)) * 128;
    *(uint4*)(base + c)      = o0.v; *(uint4*)(base + c + 8)  = o1.v;
    *(uint4*)(base + c + 64) = o2.v; *(uint4*)(base + c + 72) = o3.v;
  } else {  // v head: LDS transpose -> Vt[b,hv,d,s]
    const int hv = h - 40;
#pragma unroll
    for (int j = 0; j < 8; ++j) {
      vt[row][c + j]      = a0.us[j]; vt[row][c + 8 + j]  = a1.us[j];
      vt[row][c + 64 + j] = b0.us[j]; vt[row][c + 72 + j] = b1.us[j];
    }
    __syncthreads();
    const int d = t >> 1, s0 = (t & 1) * 32, sb = (tt & 31) * 64;
    U w0, w1, w2, w3;
#pragma unroll
    for (int j = 0; j < 8; ++j) {
      w0.us[j] = vt[s0 + j][d];      w1.us[j] = vt[s0 + 8 + j][d];
      w2.us[j] = vt[s0 + 16 + j][d]; w3.us[j] = vt[s0 + 24 + j][d];
    }
    ushort* vb = Vt + ((size_t)((b * 8 + hv) * 128 + d)) * 2048 + sb + s0;
    *(uint4*)(vb) = w0.v;      *(uint4*)(vb + 8) = w1.v;
    *(uint4*)(vb + 16) = w2.v; *(uint4*)(vb + 24) = w3.v;
  }
}

// ------------- flash attention + hidden weight transposes ------------------
// Byte-identical to R13/R14 attn_tc.
__global__ __launch_bounds__(512) void attn_tc_kernel(
    const ushort* __restrict__ Q, const ushort* __restrict__ K,
    const ushort* __restrict__ V, ushort* __restrict__ O,
    const float* t1in, ushort* t1out, int t1ld, int t1off, int t1R, int t1ntx, int t1n,
    const float* t2in, ushort* t2out, int t2ld, int t2off, int t2R, int t2ntx, int t2n,
    const float* t3in, ushort* t3out, int t3ld, int t3off, int t3R, int t3ntx, int t3n) {
  extern __shared__ ushort sm[];
  const int bid = (int)blockIdx.x;
  const int t = threadIdx.x;
  if (bid >= 1024) {                      // transpose blocks
    int tb = bid - 1024;
    if (tb < t1n) {
      transpose512(t1in, t1out, t1ld, t1off, t1R, t1ntx, tb, sm, t);
    } else if (tb < t1n + t2n) {
      transpose512(t2in, t2out, t2ld, t2off, t2R, t2ntx, tb - t1n, sm, t);
    } else {
      transpose512(t3in, t3out, t3ld, t3off, t3R, t3ntx, tb - t1n - t2n, sm, t);
    }
    return;
  }
  const int qb = bid & 15, h = (bid >> 4) & 31, b = bid >> 9;

  ushort* Kl = sm;           // [2][64 s][128 d]
  ushort* Vl = sm + 16384;   // [2][128 d][64 s]
  ushort* Pl = sm + 32768;   // [128][64]
  const int l = t & 63, w = t >> 6;   // w: 0..7
  const int lr = l & 15, lg = l >> 4;
  const int hkv = h >> 2;
  const f32x4 fzero = {0.f, 0.f, 0.f, 0.f};

  const int rm = lr & 7;
  int ksw[4], vsw[2];
#pragma unroll
  for (int ks = 0; ks < 4; ++ks) ksw[ks] = ((ks * 4 + lg) ^ rm) * 8;
  vsw[0] = (lg ^ rm) * 8;
  vsw[1] = ((4 + lg) ^ rm) * 8;
  const int kcol = ((t & 15) ^ ((t >> 4) & 7)) * 8;   // staging src swizzle
  const int vcol = ((t & 7) ^ ((t >> 3) & 7)) * 8;

  const float qscale = 0.08838834764831845f * 1.4426950408889634f;
  const ushort* qp =
      Q + ((size_t)((b * 32 + h) * 2048 + qb * 128 + w * 16 + lr)) * 128 + lg * 8;
  bf16x8 qf[4];
#pragma unroll
  for (int ks = 0; ks < 4; ++ks) {
    bf16x8 raw = *(const bf16x8*)(qp + ks * 32);
#pragma unroll
    for (int j = 0; j < 8; ++j)
      qf[ks][j] = (short)f2bf(bf2f((ushort)raw[j]) * qscale);
  }
  bf16x8 ones;
#pragma unroll
  for (int j = 0; j < 8; ++j) ones[j] = (short)0x3F80;
  WAIT_VM0();

  const ushort* kg = K + ((size_t)(b * 8 + hkv)) * 2048 * 128;
  const ushort* vg = V + ((size_t)(b * 8 + hkv)) * 128 * 2048;

#define STAGE_KV(buf, s0_) do {                                              \
    _Pragma("unroll") for (int i_ = 0; i_ < 2; ++i_)                         \
      gload16(kg + (size_t)((s0_) + i_ * 32 + (t >> 4)) * 128 + kcol,        \
              (char*)Kl + (buf) * 16384 + i_ * 8192 + t * 16);               \
    _Pragma("unroll") for (int i_ = 0; i_ < 2; ++i_)                         \
      gload16(vg + (size_t)(i_ * 64 + (t >> 3)) * 2048 + (s0_) + vcol,       \
              (char*)Vl + (buf) * 16384 + i_ * 8192 + t * 16);               \
  } while (0)

  f32x4 accO[8];
#pragma unroll
  for (int i = 0; i < 8; ++i) accO[i] = fzero;
  float m_r[4] = {-1e30f, -1e30f, -1e30f, -1e30f};
  float l_r[4] = {0.f, 0.f, 0.f, 0.f};
  const int qrow = qb * 128 + w * 16 + lg * 4;
  const int wrow0 = qb * 128 + w * 16;
  const int jend = 2 * qb + 1;

  STAGE_KV(0, 0);
  for (int j = 0; j <= jend; ++j) {
    if (j < jend) { STAGE_KV((j + 1) & 1, (j + 1) * 64); WAIT_VM4(); }
    else          { WAIT_VM0(); }
    BARRIER();
    const ushort* Kb = Kl + (j & 1) * 8192;
    const ushort* Vb = Vl + (j & 1) * 8192;

    f32x4 sc[4];
#pragma unroll
    for (int ni = 0; ni < 4; ++ni) sc[ni] = fzero;
    __builtin_amdgcn_s_setprio(1);
#pragma unroll
    for (int ni = 0; ni < 4; ++ni)
#pragma unroll
      for (int ks = 0; ks < 4; ++ks) {
        bf16x8 kf = *(const bf16x8*)(Kb + (ni * 16 + lr) * 128 + ksw[ks]);
        sc[ni] = __builtin_amdgcn_mfma_f32_16x16x32_bf16(qf[ks], kf, sc[ni], 0, 0, 0);
      }
    __builtin_amdgcn_s_setprio(0);
    if (j * 64 + 63 > wrow0) {
#pragma unroll
      for (int ni = 0; ni < 4; ++ni)
#pragma unroll
        for (int r = 0; r < 4; ++r)
          if (j * 64 + ni * 16 + lr > qrow + r) sc[ni][r] = -1e30f;
    }
    float mx[4];
#pragma unroll
    for (int r = 0; r < 4; ++r) {
      float v = fmaxf(fmaxf(sc[0][r], sc[1][r]), fmaxf(sc[2][r], sc[3][r]));
#pragma unroll
      for (int m = 8; m; m >>= 1) v = fmaxf(v, __shfl_xor(v, m));
      mx[r] = v;
    }
    bool ok = mx[0] <= m_r[0] + 8.f && mx[1] <= m_r[1] + 8.f &&
              mx[2] <= m_r[2] + 8.f && mx[3] <= m_r[3] + 8.f;
    if (!__all(ok)) {
#pragma unroll
      for (int r = 0; r < 4; ++r) {
        float mnew = fmaxf(m_r[r], mx[r]);
        float fsc = exp2f(m_r[r] - mnew);
        l_r[r] *= fsc;
        m_r[r] = mnew;
#pragma unroll
        for (int i = 0; i < 8; ++i) accO[i][r] *= fsc;
      }
    }
#pragma unroll
    for (int ni = 0; ni < 4; ++ni)
#pragma unroll
      for (int r = 0; r < 4; ++r) {
        int prow = w * 16 + lg * 4 + r;
        int slot = (ni * 2 + (lr >> 3)) ^ (prow & 7);
        Pl[prow * 64 + slot * 8 + rm] = f2bf(exp2f(sc[ni][r] - m_r[r]));
      }
    WAIT_LGKM0();
    f32x4 accL = fzero;
    __builtin_amdgcn_s_setprio(1);
#pragma unroll
    for (int ks = 0; ks < 2; ++ks) {
      bf16x8 pf = *(const bf16x8*)(Pl + (w * 16 + lr) * 64 + vsw[ks]);
#pragma unroll
      for (int nf = 0; nf < 8; ++nf) {
        bf16x8 vf = *(const bf16x8*)(Vb + (nf * 16 + lr) * 64 + vsw[ks]);
        accO[nf] = __builtin_amdgcn_mfma_f32_16x16x32_bf16(pf, vf, accO[nf], 0, 0, 0);
      }
      accL = __builtin_amdgcn_mfma_f32_16x16x32_bf16(pf, ones, accL, 0, 0, 0);
    }
    __builtin_amdgcn_s_setprio(0);
#pragma unroll
    for (int r = 0; r < 4; ++r) l_r[r] += accL[r];
    BARRIER();
  }
#undef STAGE_KV
  float invl[4];
#pragma unroll
  for (int r = 0; r < 4; ++r) invl[r] = 1.f / l_r[r];
#pragma unroll
  for (int nf = 0; nf < 8; ++nf)
#pragma unroll
    for (int r = 0; r < 4; ++r) {
      int q = qb * 128 + w * 16 + lg * 4 + r;
      int d = nf * 16 + lr;
      O[((size_t)(b * 2048 + q)) * 4096 + h * 128 + d] = f2bf(accO[nf][r] * invl[r]);
    }
}

// ------------------------------ launcher -----------------------------------
#define OFF_A     ((size_t)0)           // qkvb | W3 | act
#define OFF_B     ((size_t)90177536)    // tab | W4
#define OFF_D     ((size_t)180355072)   // W1 | Qr/Kr/Vt | gate
#define OFF_C     ((size_t)270532608)   // W2 | W5
#define OFF_E     ((size_t)360710144)   // xn | attnb | xn
#define OFF_TAB   (OFF_B)
#define OFF_QR    (OFF_D + 1048576)
#define OFF_KR    (OFF_D + 34603008)
#define OFF_VT    (OFF_D + 42991616)
#define WS_NEED   ((size_t)416284672)

extern "C" void kernel_launch(void* const* d_in, const int* in_sizes, int n_in,
                              void* d_out, int out_size, void* d_ws,
                              size_t ws_size, hipStream_t stream) {
  (void)in_sizes; (void)n_in; (void)out_size;
  if (ws_size < WS_NEED) return;
  const float* hs     = (const float*)d_in[0];
  const int*   pos    = (const int*)d_in[1];
  const float* w_qkv  = (const float*)d_in[2];
  const float* w_o    = (const float*)d_in[3];
  const float* w_gu   = (const float*)d_in[4];
  const float* w_down = (const float*)d_in[5];
  const float* ln1    = (const float*)d_in[6];
  const float* ln2    = (const float*)d_in[7];
  float* out = (float*)d_out;
  float* h1  = (float*)d_out;          // residual stream lives in d_out
  char* ws = (char*)d_ws;

  ushort* qkvb  = (ushort*)(ws + OFF_A);
  ushort* W3    = (ushort*)(ws + OFF_A);
  ushort* act   = (ushort*)(ws + OFF_A);
  float2* tab   = (float2*)(ws + OFF_TAB);
  ushort* W4    = (ushort*)(ws + OFF_B);
  ushort* W1    = (ushort*)(ws + OFF_D);
  ushort* gate  = (ushort*)(ws + OFF_D);
  ushort* Qr    = (ushort*)(ws + OFF_QR);
  ushort* Kr    = (ushort*)(ws + OFF_KR);
  ushort* Vt    = (ushort*)(ws + OFF_VT);
  ushort* W2    = (ushort*)(ws + OFF_C);
  ushort* W5    = (ushort*)(ws + OFF_C);
  ushort* xn    = (ushort*)(ws + OFF_E);
  ushort* attnb = (ushort*)(ws + OFF_E);

  auto kb = gemm256_kernel<ushort, false>;
  auto kf = gemm256_kernel<float, true>;
  hipFuncSetAttribute((const void*)kb, hipFuncAttributeMaxDynamicSharedMemorySize, 131072);
  hipFuncSetAttribute((const void*)kf, hipFuncAttributeMaxDynamicSharedMemorySize, 131072);
  hipFuncSetAttribute((const void*)gemm256_tc_kernel, hipFuncAttributeMaxDynamicSharedMemorySize, 131072);
  hipFuncSetAttribute((const void*)gemm256_swiglu_kernel, hipFuncAttributeMaxDynamicSharedMemorySize, 131072);
  hipFuncSetAttribute((const void*)attn_tc_kernel, hipFuncAttributeMaxDynamicSharedMemorySize, 81920);

  // s1: fused rmsnorm1 -> xn(E), w_qkv -> W1(D), rope table -> tab(B)
  pre_kernel<<<4096 + 3072 + 256, 512, 0, stream>>>(
      hs, ln1, xn, w_qkv, W1, pos, tab);
  // s3: qkv GEMM -> qkvb(A)
  gemm256_kernel<ushort, false><<<384, 512, 131072, stream>>>(
      xn, W1, qkvb, nullptr, 4096, 6144, 4096);
  // s4: rope scatter -> Qr/Kr/Vt (D, over W1)
  rope_scatter_kernel<<<dim3(64, 48), 256, 0, stream>>>(qkvb, tab, Qr, Kr, Vt);
  // s5: attn -> attnb(E) + hidden transposes (w_gu p1->W3(A), p2->W4(B), w_o->W2(C))
  attn_tc_kernel<<<1024 + 5504 + 5504 + 2048, 512, 81920, stream>>>(
      Qr, Kr, Vt, attnb,
      w_gu, W3, 22016, 0,     4096, 64, 5504,
      w_gu, W4, 22016, 11008, 4096, 64, 5504,
      w_o,  W2, 4096,  0,     4096, 64, 2048);
  // s7: o-proj (residual hs) -> h1 (= d_out)
  gemm256_kernel<float, true><<<256, 512, 131072, stream>>>(
      attnb, W2, h1, hs, 4096, 4096, 4096);
  // s8: rmsnorm2 -> xn(E, over attnb)
  rmsnorm_kernel<<<4096, 256, 0, stream>>>(h1, ln2, xn);
  // s9: gate GEMM -> gate(D) + hidden transpose (w_down -> W5(C, over W2))
  gemm256_tc_kernel<<<688 + 5504, 512, 131072, stream>>>(
      xn, W3, gate, 4096, 11008, 4096,
      w_down, W5, 4096, 0, 11008, 172);
  // s10: up GEMM + fused SwiGLU -> act(A, over W3)
  gemm256_swiglu_kernel<<<688, 512, 131072, stream>>>(
      xn, W4, act, gate, 4096, 11008, 4096);
  // s12: down GEMM, residual h1 (= d_out), same-index in-place write
  gemm256_kernel<float, true><<<256, 512, 131072, stream>>>(
      act, W5, out, h1, 4096, 4096, 11008);
}

// Round 16
// 1708.315 us; speedup vs baseline: 1.1505x; 1.0105x over previous
//
#include <hip/hip_runtime.h>

// ---------------------------------------------------------------------------
// Llama decoder layer, MI355X (gfx950).
// B=2 S=2048 HIDDEN=4096 HQ=32 HKV=8 D=128 INTER=11008, fp32 in/out.
// R16: pack the qkv launch's idle tail (384 blocks = 1.5 occupancy rounds;
// round 2 idles 128 CUs) with the w_o transpose by REUSING gemm256_tc_kernel
// (same body as R14/R15, different args -- no new kernel code). attn_tc
// drops the w_o job (t3n=0). All kernel bodies byte-identical to R15.
// Overlay lifetimes (audited):
//  A: qkvb(s3-s4) | W3(s5-s9) | act(s10-s12)
//  B: tab(s1-s4) | W4(s5-s10)
//  D: W1(s1-s3) | Qr/Kr/Vt(s4-s5) | gate(s9-s10)
//  C: W2(s3-s7) | W5(s9-s12)     [W2 now written during s3 launch]
//  E: xn(s1-s3) | attnb(s5-s7) | xn(s8-s10)
// h1 lives in d_out (same-index read-then-write in down-GEMM epilogue).
// ---------------------------------------------------------------------------

typedef __attribute__((ext_vector_type(8))) short bf16x8;
typedef __attribute__((ext_vector_type(4))) float f32x4;

__device__ __forceinline__ ushort f2bf(float f) {           // RNE fp32->bf16
  unsigned u = __float_as_uint(f);
  return (ushort)((u + 0x7fffu + ((u >> 16) & 1u)) >> 16);
}
__device__ __forceinline__ float bf2f(ushort u) {
  union { unsigned u32; float f; } x; x.u32 = ((unsigned)u) << 16; return x.f;
}
__device__ __forceinline__ void gload16(const void* g, void* l) {
  __builtin_amdgcn_global_load_lds((__attribute__((address_space(1))) void*)g,
                                   (__attribute__((address_space(3))) void*)l,
                                   16, 0, 0);
}

#define BARRIER() asm volatile("s_barrier" ::: "memory")
#define WAIT_LGKM0() asm volatile("s_waitcnt lgkmcnt(0)" ::: "memory")
#define WAIT_VM4() asm volatile("s_waitcnt vmcnt(4)" ::: "memory")
#define WAIT_VM0() asm volatile("s_waitcnt vmcnt(0)" ::: "memory")

// --------------------------- RMSNorm (fp32 -> bf16) ------------------------
__global__ __launch_bounds__(256) void rmsnorm_kernel(
    const float* __restrict__ x, const float* __restrict__ g,
    ushort* __restrict__ out) {
  const int row = blockIdx.x, t = threadIdx.x;
  const float4* xp = (const float4*)(x + (size_t)row * 4096);
  float4 v[4]; float ss = 0.f;
#pragma unroll
  for (int i = 0; i < 4; ++i) {
    v[i] = xp[t + i * 256];
    ss += v[i].x * v[i].x + v[i].y * v[i].y + v[i].z * v[i].z + v[i].w * v[i].w;
  }
#pragma unroll
  for (int m = 32; m; m >>= 1) ss += __shfl_xor(ss, m);
  __shared__ float red[4];
  if ((t & 63) == 0) red[t >> 6] = ss;
  __syncthreads();
  float inv = rsqrtf((red[0] + red[1] + red[2] + red[3]) * (1.f / 4096.f) + 1e-6f);
  const float4* gp = (const float4*)g;
  ushort* op = out + (size_t)row * 4096;
#pragma unroll
  for (int i = 0; i < 4; ++i) {
    float4 gv = gp[t + i * 256];
    ushort4 o;
    o.x = f2bf(v[i].x * inv * gv.x); o.y = f2bf(v[i].y * inv * gv.y);
    o.z = f2bf(v[i].z * inv * gv.z); o.w = f2bf(v[i].w * inv * gv.w);
    *(ushort4*)(op + (size_t)(t + i * 256) * 4) = o;
  }
}

// ------- 512-thread transpose helper (2 x 64x64 tiles per block) -----------
__device__ __forceinline__ void transpose512(
    const float* __restrict__ in, ushort* __restrict__ out,
    int ld_in, int col_off, int R, int ntx, int tbid, ushort* ldsb, int t) {
  const int half = t >> 8, tt = t & 255;
  ushort* tile = ldsb + half * (64 * 65);
  const int x = tbid % ntx, yy = tbid / ntx;
  const int r0 = x * 64, c0 = (yy * 2 + half) * 64;
  const int rl = tt >> 2, cl = (tt & 3) * 16;
  const float* ip = in + (size_t)(r0 + rl) * ld_in + col_off + c0 + cl;
#pragma unroll
  for (int i = 0; i < 4; ++i) {
    float4 f = ((const float4*)ip)[i];
    tile[rl * 65 + cl + i * 4 + 0] = f2bf(f.x);
    tile[rl * 65 + cl + i * 4 + 1] = f2bf(f.y);
    tile[rl * 65 + cl + i * 4 + 2] = f2bf(f.z);
    tile[rl * 65 + cl + i * 4 + 3] = f2bf(f.w);
  }
  __syncthreads();
  union { ushort us[8]; uint4 v; } pk0, pk1;
#pragma unroll
  for (int j = 0; j < 8; ++j) pk0.us[j] = tile[(cl + j) * 65 + rl];
#pragma unroll
  for (int j = 0; j < 8; ++j) pk1.us[j] = tile[(cl + 8 + j) * 65 + rl];
  uint4* op = (uint4*)(out + (size_t)(c0 + rl) * R + r0 + cl);
  op[0] = pk0.v; op[1] = pk1.v;
}

// ---- fused front: rmsnorm1 + w_qkv transpose + rope table (independent) ---
__global__ __launch_bounds__(512) void pre_kernel(
    const float* __restrict__ hs, const float* __restrict__ ln1,
    ushort* __restrict__ xn, const float* __restrict__ wq,
    ushort* __restrict__ W1, const int* __restrict__ pos,
    float2* __restrict__ tab) {
  __shared__ ushort sm[2 * 64 * 65];
  const int bid = (int)blockIdx.x, t = threadIdx.x;
  if (bid < 4096) {              // rmsnorm row = bid, 8 floats/thread
    const float4* xp = (const float4*)(hs + (size_t)bid * 4096);
    float4 v0 = xp[t], v1 = xp[t + 512];
    float ss = v0.x * v0.x + v0.y * v0.y + v0.z * v0.z + v0.w * v0.w +
               v1.x * v1.x + v1.y * v1.y + v1.z * v1.z + v1.w * v1.w;
#pragma unroll
    for (int m = 32; m; m >>= 1) ss += __shfl_xor(ss, m);
    float* redf = (float*)sm;
    if ((t & 63) == 0) redf[t >> 6] = ss;
    __syncthreads();
    float tot = redf[0] + redf[1] + redf[2] + redf[3] +
                redf[4] + redf[5] + redf[6] + redf[7];
    float inv = rsqrtf(tot * (1.f / 4096.f) + 1e-6f);
    const float4* gp = (const float4*)ln1;
    float4 g0 = gp[t], g1 = gp[t + 512];
    ushort* op = xn + (size_t)bid * 4096;
    ushort4 o0, o1;
    o0.x = f2bf(v0.x * inv * g0.x); o0.y = f2bf(v0.y * inv * g0.y);
    o0.z = f2bf(v0.z * inv * g0.z); o0.w = f2bf(v0.w * inv * g0.w);
    o1.x = f2bf(v1.x * inv * g1.x); o1.y = f2bf(v1.y * inv * g1.y);
    o1.z = f2bf(v1.z * inv * g1.z); o1.w = f2bf(v1.w * inv * g1.w);
    *(ushort4*)(op + (size_t)t * 4) = o0;
    *(ushort4*)(op + (size_t)(t + 512) * 4) = o1;
  } else if (bid < 4096 + 3072) {  // w_qkv[4096,6144] -> W1[6144,4096]
    transpose512(wq, W1, 6144, 0, 4096, 64, bid - 4096, sm, t);
  } else {                          // rope table, idx over 2048*64
    int idx = (bid - 7168) * 512 + t;
    int s = idx >> 6, fi = idx & 63;
    float inv = (float)exp(-(double)(2 * fi) / 128.0 * 9.210340371976184);
    float a = (float)pos[s] * inv;
    tab[idx] = make_float2(cosf(a), sinf(a));
  }
}

// ------------------------- GEMM 256x256 8-phase ----------------------------
// Byte-identical to R8..R15 (R4 body + col-major XCD chunk mapping).
template <typename OutT, bool RES>
__global__ __launch_bounds__(512, 2) void gemm256_kernel(
    const ushort* __restrict__ A, const ushort* __restrict__ Bt,
    OutT* __restrict__ C, const float* __restrict__ res,
    int M, int N, int K) {
  extern __shared__ ushort lds[];
  ushort* Al = lds;            // [buf:2][half:2][8192 ushorts]
  ushort* Bl = lds + 32768;
  const int t = threadIdx.x, l = t & 63, w = t >> 6;
  const int wr = w >> 2, wc = w & 3;
  const int lr = l & 15, lg = l >> 4;
  const int rhi = lr >> 3, rlo = lr & 7;
  const int srow = l >> 3, sg = (l & 7) ^ srow;

  const int nby = M >> 8;
  const int nwg = (N >> 8) * nby;
  const int cpx = nwg >> 3;
  const int bid = (int)blockIdx.x;
  const int swz = (bid & 7) * cpx + (bid >> 3);   // XCD chunk (nwg%8==0)
  const int m0 = (swz % nby) << 8;                // col-major: B panel shared
  const int n0 = (swz / nby) << 8;                // by 16 consecutive blocks

  const int lof0 = rhi * 512 + rlo * 64 + ((0 + lg) ^ rlo) * 8;  // kk=0
  const int lof1 = rhi * 512 + rlo * 64 + ((4 + lg) ^ rlo) * 8;  // kk=1

  const f32x4 fz = {0.f, 0.f, 0.f, 0.f};
  f32x4 acc[8][4];
#pragma unroll
  for (int i = 0; i < 8; ++i)
#pragma unroll
    for (int j = 0; j < 4; ++j) acc[i][j] = fz;
  bf16x8 a[8][2];
  bf16x8 bq[2][2];

  const ushort* Asrc = A + (size_t)(m0 + w * 8 + srow) * K + sg * 8;
  const ushort* Bsrc = Bt + (size_t)(n0 + w * 8 + srow) * K + sg * 8;
  const size_t rK64 = (size_t)64 * K, rK128 = (size_t)128 * K;
  ushort* Adst = Al + w * 512;
  ushort* Bdst = Bl + w * 512;

#define STAGE_A(buf, half, tile) do {                                   \
    const ushort* s_ = Asrc + (size_t)(half) * rK128 + ((tile) << 6);   \
    ushort* d_ = Adst + (buf) * 16384 + (half) * 8192;                  \
    gload16(s_, d_);                                                    \
    gload16(s_ + rK64, d_ + 4096);                                      \
  } while (0)
#define STAGE_B(buf, half, tile) do {                                   \
    const ushort* s_ = Bsrc + (size_t)(half) * rK128 + ((tile) << 6);   \
    ushort* d_ = Bdst + (buf) * 16384 + (half) * 8192;                  \
    gload16(s_, d_);                                                    \
    gload16(s_ + rK64, d_ + 4096);                                      \
  } while (0)
#define LDA4(AH, QM) do {                                                   \
    _Pragma("unroll") for (int mi_ = 0; mi_ < 4; ++mi_) {                   \
      a[(QM) * 4 + mi_][0] =                                                \
          *(const bf16x8*)((AH) + ((QM) * 4 + mi_) * 1024 + lof0);          \
      a[(QM) * 4 + mi_][1] =                                                \
          *(const bf16x8*)((AH) + ((QM) * 4 + mi_) * 1024 + lof1);          \
    } } while (0)
#define LDB2(BH, NQ) do {                                                   \
    _Pragma("unroll") for (int nj_ = 0; nj_ < 2; ++nj_) {                   \
      bq[nj_][0] = *(const bf16x8*)((BH) + ((NQ) * 2 + nj_) * 1024 + lof0); \
      bq[nj_][1] = *(const bf16x8*)((BH) + ((NQ) * 2 + nj_) * 1024 + lof1); \
    } } while (0)
#define MFMA16(QM, QN)                                                      \
    __builtin_amdgcn_s_setprio(1);                                          \
    _Pragma("unroll") for (int mi_ = 0; mi_ < 4; ++mi_)                     \
    _Pragma("unroll") for (int nj_ = 0; nj_ < 2; ++nj_) {                   \
      acc[(QM) * 4 + mi_][(QN) * 2 + nj_] =                                 \
          __builtin_amdgcn_mfma_f32_16x16x32_bf16(                          \
              a[(QM) * 4 + mi_][0], bq[nj_][0],                             \
              acc[(QM) * 4 + mi_][(QN) * 2 + nj_], 0, 0, 0);                \
      acc[(QM) * 4 + mi_][(QN) * 2 + nj_] =                                 \
          __builtin_amdgcn_mfma_f32_16x16x32_bf16(                          \
              a[(QM) * 4 + mi_][1], bq[nj_][1],                             \
              acc[(QM) * 4 + mi_][(QN) * 2 + nj_], 0, 0, 0);                \
    }                                                                       \
    __builtin_amdgcn_s_setprio(0);

  const ushort* A0h = Al + wr * 8192;
  const ushort* A1h = A0h + 16384;
  const ushort* B0h = Bl + (wc >> 1) * 8192 + (wc & 1) * 4096;
  const ushort* B1h = B0h + 16384;

  const int ntiles = K >> 6, nIter = K >> 7;
  // prologue: tile0 full -> buf0; tile1 A halves -> buf1
  STAGE_A(0, 0, 0); STAGE_A(0, 1, 0); STAGE_B(0, 0, 0); STAGE_B(0, 1, 0);
  STAGE_A(1, 0, 1); STAGE_A(1, 1, 1);
  WAIT_VM4(); BARRIER();

  for (int it = 0; it < nIter; ++it) {
    const int u = it * 2;
    // ---- tile u (buf0) ----
    LDA4(A0h, 0); LDB2(B0h, 0);                 // P1
    STAGE_B(1, 0, u + 1);
    BARRIER(); WAIT_LGKM0(); MFMA16(0, 0); BARRIER();
    LDA4(A0h, 1);                               // P2
    STAGE_B(1, 1, u + 1);
    BARRIER(); WAIT_LGKM0(); MFMA16(1, 0); BARRIER();
    LDB2(B0h, 1);                               // P3
    if (u + 2 < ntiles) STAGE_A(0, 0, u + 2);
    BARRIER(); WAIT_LGKM0(); MFMA16(0, 1); BARRIER();
    if (u + 2 < ntiles) STAGE_A(0, 1, u + 2);   // P4
    BARRIER(); MFMA16(1, 1);
    if (u + 2 < ntiles) { WAIT_VM4(); } else { WAIT_VM0(); }
    BARRIER();
    // ---- tile u+1 (buf1) ----
    LDA4(A1h, 0); LDB2(B1h, 0);                 // P5
    if (u + 2 < ntiles) STAGE_B(0, 0, u + 2);
    BARRIER(); WAIT_LGKM0(); MFMA16(0, 0); BARRIER();
    LDA4(A1h, 1);                               // P6
    if (u + 2 < ntiles) STAGE_B(0, 1, u + 2);
    BARRIER(); WAIT_LGKM0(); MFMA16(1, 0); BARRIER();
    LDB2(B1h, 1);                               // P7
    if (u + 3 < ntiles) STAGE_A(1, 0, u + 3);
    BARRIER(); WAIT_LGKM0(); MFMA16(0, 1); BARRIER();
    if (u + 3 < ntiles) STAGE_A(1, 1, u + 3);   // P8
    BARRIER(); MFMA16(1, 1);
    WAIT_VM4(); BARRIER();
  }

  // epilogue: C row = m0+wr*128+mi*16+lg*4+r, col = n0+wc*64+ni*16+lr
#pragma unroll
  for (int mi = 0; mi < 8; ++mi)
#pragma unroll
    for (int ni = 0; ni < 4; ++ni)
#pragma unroll
      for (int r = 0; r < 4; ++r) {
        int row = m0 + wr * 128 + mi * 16 + lg * 4 + r;
        int col = n0 + wc * 64 + ni * 16 + lr;
        size_t idx = (size_t)row * N + col;
        float v = acc[mi][ni][r];
        if (RES) v += res[idx];
        if constexpr (sizeof(OutT) == 2) C[idx] = f2bf(v);
        else                             C[idx] = v;
      }
#undef STAGE_A
#undef STAGE_B
#undef LDA4
#undef LDB2
#undef MFMA16
}

// ----------- GEMM (bf16 out, no res) + hidden transpose tail ---------------
// Byte-identical to R14/R15. Used for gate(+w_down) AND qkv(+w_o).
__global__ __launch_bounds__(512, 2) void gemm256_tc_kernel(
    const ushort* __restrict__ A, const ushort* __restrict__ Bt,
    ushort* __restrict__ C, int M, int N, int K,
    const float* tin, ushort* tout, int tld, int toff, int tR, int tntx) {
  extern __shared__ ushort lds[];
  const int nby = M >> 8;
  const int nwg = (N >> 8) * nby;
  const int bid = (int)blockIdx.x;
  const int t = threadIdx.x;
  if (bid >= nwg) {                        // transpose tail blocks
    transpose512(tin, tout, tld, toff, tR, tntx, bid - nwg, lds, t);
    return;
  }
  ushort* Al = lds;
  ushort* Bl = lds + 32768;
  const int l = t & 63, w = t >> 6;
  const int wr = w >> 2, wc = w & 3;
  const int lr = l & 15, lg = l >> 4;
  const int rhi = lr >> 3, rlo = lr & 7;
  const int srow = l >> 3, sg = (l & 7) ^ srow;

  const int cpx = nwg >> 3;
  const int swz = (bid & 7) * cpx + (bid >> 3);
  const int m0 = (swz % nby) << 8;
  const int n0 = (swz / nby) << 8;

  const int lof0 = rhi * 512 + rlo * 64 + ((0 + lg) ^ rlo) * 8;
  const int lof1 = rhi * 512 + rlo * 64 + ((4 + lg) ^ rlo) * 8;

  const f32x4 fz = {0.f, 0.f, 0.f, 0.f};
  f32x4 acc[8][4];
#pragma unroll
  for (int i = 0; i < 8; ++i)
#pragma unroll
    for (int j = 0; j < 4; ++j) acc[i][j] = fz;
  bf16x8 a[8][2];
  bf16x8 bq[2][2];

  const ushort* Asrc = A + (size_t)(m0 + w * 8 + srow) * K + sg * 8;
  const ushort* Bsrc = Bt + (size_t)(n0 + w * 8 + srow) * K + sg * 8;
  const size_t rK64 = (size_t)64 * K, rK128 = (size_t)128 * K;
  ushort* Adst = Al + w * 512;
  ushort* Bdst = Bl + w * 512;

#define STAGE_A(buf, half, tile) do {                                   \
    const ushort* s_ = Asrc + (size_t)(half) * rK128 + ((tile) << 6);   \
    ushort* d_ = Adst + (buf) * 16384 + (half) * 8192;                  \
    gload16(s_, d_);                                                    \
    gload16(s_ + rK64, d_ + 4096);                                      \
  } while (0)
#define STAGE_B(buf, half, tile) do {                                   \
    const ushort* s_ = Bsrc + (size_t)(half) * rK128 + ((tile) << 6);   \
    ushort* d_ = Bdst + (buf) * 16384 + (half) * 8192;                  \
    gload16(s_, d_);                                                    \
    gload16(s_ + rK64, d_ + 4096);                                      \
  } while (0)
#define LDA4(AH, QM) do {                                                   \
    _Pragma("unroll") for (int mi_ = 0; mi_ < 4; ++mi_) {                   \
      a[(QM) * 4 + mi_][0] =                                                \
          *(const bf16x8*)((AH) + ((QM) * 4 + mi_) * 1024 + lof0);          \
      a[(QM) * 4 + mi_][1] =                                                \
          *(const bf16x8*)((AH) + ((QM) * 4 + mi_) * 1024 + lof1);          \
    } } while (0)
#define LDB2(BH, NQ) do {                                                   \
    _Pragma("unroll") for (int nj_ = 0; nj_ < 2; ++nj_) {                   \
      bq[nj_][0] = *(const bf16x8*)((BH) + ((NQ) * 2 + nj_) * 1024 + lof0); \
      bq[nj_][1] = *(const bf16x8*)((BH) + ((NQ) * 2 + nj_) * 1024 + lof1); \
    } } while (0)
#define MFMA16(QM, QN)                                                      \
    __builtin_amdgcn_s_setprio(1);                                          \
    _Pragma("unroll") for (int mi_ = 0; mi_ < 4; ++mi_)                     \
    _Pragma("unroll") for (int nj_ = 0; nj_ < 2; ++nj_) {                   \
      acc[(QM) * 4 + mi_][(QN) * 2 + nj_] =                                 \
          __builtin_amdgcn_mfma_f32_16x16x32_bf16(                          \
              a[(QM) * 4 + mi_][0], bq[nj_][0],                             \
              acc[(QM) * 4 + mi_][(QN) * 2 + nj_], 0, 0, 0);                \
      acc[(QM) * 4 + mi_][(QN) * 2 + nj_] =                                 \
          __builtin_amdgcn_mfma_f32_16x16x32_bf16(                          \
              a[(QM) * 4 + mi_][1], bq[nj_][1],                             \
              acc[(QM) * 4 + mi_][(QN) * 2 + nj_], 0, 0, 0);                \
    }                                                                       \
    __builtin_amdgcn_s_setprio(0);

  const ushort* A0h = Al + wr * 8192;
  const ushort* A1h = A0h + 16384;
  const ushort* B0h = Bl + (wc >> 1) * 8192 + (wc & 1) * 4096;
  const ushort* B1h = B0h + 16384;

  const int ntiles = K >> 6, nIter = K >> 7;
  STAGE_A(0, 0, 0); STAGE_A(0, 1, 0); STAGE_B(0, 0, 0); STAGE_B(0, 1, 0);
  STAGE_A(1, 0, 1); STAGE_A(1, 1, 1);
  WAIT_VM4(); BARRIER();

  for (int it = 0; it < nIter; ++it) {
    const int u = it * 2;
    LDA4(A0h, 0); LDB2(B0h, 0);
    STAGE_B(1, 0, u + 1);
    BARRIER(); WAIT_LGKM0(); MFMA16(0, 0); BARRIER();
    LDA4(A0h, 1);
    STAGE_B(1, 1, u + 1);
    BARRIER(); WAIT_LGKM0(); MFMA16(1, 0); BARRIER();
    LDB2(B0h, 1);
    if (u + 2 < ntiles) STAGE_A(0, 0, u + 2);
    BARRIER(); WAIT_LGKM0(); MFMA16(0, 1); BARRIER();
    if (u + 2 < ntiles) STAGE_A(0, 1, u + 2);
    BARRIER(); MFMA16(1, 1);
    if (u + 2 < ntiles) { WAIT_VM4(); } else { WAIT_VM0(); }
    BARRIER();
    LDA4(A1h, 0); LDB2(B1h, 0);
    if (u + 2 < ntiles) STAGE_B(0, 0, u + 2);
    BARRIER(); WAIT_LGKM0(); MFMA16(0, 0); BARRIER();
    LDA4(A1h, 1);
    if (u + 2 < ntiles) STAGE_B(0, 1, u + 2);
    BARRIER(); WAIT_LGKM0(); MFMA16(1, 0); BARRIER();
    LDB2(B1h, 1);
    if (u + 3 < ntiles) STAGE_A(1, 0, u + 3);
    BARRIER(); WAIT_LGKM0(); MFMA16(0, 1); BARRIER();
    if (u + 3 < ntiles) STAGE_A(1, 1, u + 3);
    BARRIER(); MFMA16(1, 1);
    WAIT_VM4(); BARRIER();
  }

#pragma unroll
  for (int mi = 0; mi < 8; ++mi)
#pragma unroll
    for (int ni = 0; ni < 4; ++ni)
#pragma unroll
      for (int r = 0; r < 4; ++r) {
        int row = m0 + wr * 128 + mi * 16 + lg * 4 + r;
        int col = n0 + wc * 64 + ni * 16 + lr;
        size_t idx = (size_t)row * N + col;
        C[idx] = f2bf(acc[mi][ni][r]);
      }
#undef STAGE_A
#undef STAGE_B
#undef LDA4
#undef LDB2
#undef MFMA16
}

// ---------------- GEMM 256x256 8-phase, fused-SwiGLU epilogue --------------
// Byte-identical to R12..R15. out = silu(gate) * (A*Bt^T), bf16.
__global__ __launch_bounds__(512, 2) void gemm256_swiglu_kernel(
    const ushort* __restrict__ A, const ushort* __restrict__ Bt,
    ushort* __restrict__ C, const ushort* __restrict__ gate,
    int M, int N, int K) {
  extern __shared__ ushort lds[];
  ushort* Al = lds;
  ushort* Bl = lds + 32768;
  const int t = threadIdx.x, l = t & 63, w = t >> 6;
  const int wr = w >> 2, wc = w & 3;
  const int lr = l & 15, lg = l >> 4;
  const int rhi = lr >> 3, rlo = lr & 7;
  const int srow = l >> 3, sg = (l & 7) ^ srow;

  const int nby = M >> 8;
  const int nwg = (N >> 8) * nby;
  const int cpx = nwg >> 3;
  const int bid = (int)blockIdx.x;
  const int swz = (bid & 7) * cpx + (bid >> 3);
  const int m0 = (swz % nby) << 8;
  const int n0 = (swz / nby) << 8;

  const int lof0 = rhi * 512 + rlo * 64 + ((0 + lg) ^ rlo) * 8;
  const int lof1 = rhi * 512 + rlo * 64 + ((4 + lg) ^ rlo) * 8;

  const f32x4 fz = {0.f, 0.f, 0.f, 0.f};
  f32x4 acc[8][4];
#pragma unroll
  for (int i = 0; i < 8; ++i)
#pragma unroll
    for (int j = 0; j < 4; ++j) acc[i][j] = fz;
  bf16x8 a[8][2];
  bf16x8 bq[2][2];

  const ushort* Asrc = A + (size_t)(m0 + w * 8 + srow) * K + sg * 8;
  const ushort* Bsrc = Bt + (size_t)(n0 + w * 8 + srow) * K + sg * 8;
  const size_t rK64 = (size_t)64 * K, rK128 = (size_t)128 * K;
  ushort* Adst = Al + w * 512;
  ushort* Bdst = Bl + w * 512;

#define STAGE_A(buf, half, tile) do {                                   \
    const ushort* s_ = Asrc + (size_t)(half) * rK128 + ((tile) << 6);   \
    ushort* d_ = Adst + (buf) * 16384 + (half) * 8192;                  \
    gload16(s_, d_);                                                    \
    gload16(s_ + rK64, d_ + 4096);                                      \
  } while (0)
#define STAGE_B(buf, half, tile) do {                                   \
    const ushort* s_ = Bsrc + (size_t)(half) * rK128 + ((tile) << 6);   \
    ushort* d_ = Bdst + (buf) * 16384 + (half) * 8192;                  \
    gload16(s_, d_);                                                    \
    gload16(s_ + rK64, d_ + 4096);                                      \
  } while (0)
#define LDA4(AH, QM) do {                                                   \
    _Pragma("unroll") for (int mi_ = 0; mi_ < 4; ++mi_) {                   \
      a[(QM) * 4 + mi_][0] =                                                \
          *(const bf16x8*)((AH) + ((QM) * 4 + mi_) * 1024 + lof0);          \
      a[(QM) * 4 + mi_][1] =                                                \
          *(const bf16x8*)((AH) + ((QM) * 4 + mi_) * 1024 + lof1);          \
    } } while (0)
#define LDB2(BH, NQ) do {                                                   \
    _Pragma("unroll") for (int nj_ = 0; nj_ < 2; ++nj_) {                   \
      bq[nj_][0] = *(const bf16x8*)((BH) + ((NQ) * 2 + nj_) * 1024 + lof0); \
      bq[nj_][1] = *(const bf16x8*)((BH) + ((NQ) * 2 + nj_) * 1024 + lof1); \
    } } while (0)
#define MFMA16(QM, QN)                                                      \
    __builtin_amdgcn_s_setprio(1);                                          \
    _Pragma("unroll") for (int mi_ = 0; mi_ < 4; ++mi_)                     \
    _Pragma("unroll") for (int nj_ = 0; nj_ < 2; ++nj_) {                   \
      acc[(QM) * 4 + mi_][(QN) * 2 + nj_] =                                 \
          __builtin_amdgcn_mfma_f32_16x16x32_bf16(                          \
              a[(QM) * 4 + mi_][0], bq[nj_][0],                             \
              acc[(QM) * 4 + mi_][(QN) * 2 + nj_], 0, 0, 0);                \
      acc[(QM) * 4 + mi_][(QN) * 2 + nj_] =                                 \
          __builtin_amdgcn_mfma_f32_16x16x32_bf16(                          \
              a[(QM) * 4 + mi_][1], bq[nj_][1],                             \
              acc[(QM) * 4 + mi_][(QN) * 2 + nj_], 0, 0, 0);                \
    }                                                                       \
    __builtin_amdgcn_s_setprio(0);

  const ushort* A0h = Al + wr * 8192;
  const ushort* A1h = A0h + 16384;
  const ushort* B0h = Bl + (wc >> 1) * 8192 + (wc & 1) * 4096;
  const ushort* B1h = B0h + 16384;

  const int ntiles = K >> 6, nIter = K >> 7;
  STAGE_A(0, 0, 0); STAGE_A(0, 1, 0); STAGE_B(0, 0, 0); STAGE_B(0, 1, 0);
  STAGE_A(1, 0, 1); STAGE_A(1, 1, 1);
  WAIT_VM4(); BARRIER();

  for (int it = 0; it < nIter; ++it) {
    const int u = it * 2;
    LDA4(A0h, 0); LDB2(B0h, 0);
    STAGE_B(1, 0, u + 1);
    BARRIER(); WAIT_LGKM0(); MFMA16(0, 0); BARRIER();
    LDA4(A0h, 1);
    STAGE_B(1, 1, u + 1);
    BARRIER(); WAIT_LGKM0(); MFMA16(1, 0); BARRIER();
    LDB2(B0h, 1);
    if (u + 2 < ntiles) STAGE_A(0, 0, u + 2);
    BARRIER(); WAIT_LGKM0(); MFMA16(0, 1); BARRIER();
    if (u + 2 < ntiles) STAGE_A(0, 1, u + 2);
    BARRIER(); MFMA16(1, 1);
    if (u + 2 < ntiles) { WAIT_VM4(); } else { WAIT_VM0(); }
    BARRIER();
    LDA4(A1h, 0); LDB2(B1h, 0);
    if (u + 2 < ntiles) STAGE_B(0, 0, u + 2);
    BARRIER(); WAIT_LGKM0(); MFMA16(0, 0); BARRIER();
    LDA4(A1h, 1);
    if (u + 2 < ntiles) STAGE_B(0, 1, u + 2);
    BARRIER(); WAIT_LGKM0(); MFMA16(1, 0); BARRIER();
    LDB2(B1h, 1);
    if (u + 3 < ntiles) STAGE_A(1, 0, u + 3);
    BARRIER(); WAIT_LGKM0(); MFMA16(0, 1); BARRIER();
    if (u + 3 < ntiles) STAGE_A(1, 1, u + 3);
    BARRIER(); MFMA16(1, 1);
    WAIT_VM4(); BARRIER();
  }

  // fused epilogue: out = silu(gate) * acc
#pragma unroll
  for (int mi = 0; mi < 8; ++mi)
#pragma unroll
    for (int ni = 0; ni < 4; ++ni)
#pragma unroll
      for (int r = 0; r < 4; ++r) {
        int row = m0 + wr * 128 + mi * 16 + lg * 4 + r;
        int col = n0 + wc * 64 + ni * 16 + lr;
        size_t idx = (size_t)row * N + col;
        float g = bf2f(gate[idx]);
        float s = g / (1.f + __expf(-g));
        C[idx] = f2bf(s * acc[mi][ni][r]);
      }
#undef STAGE_A
#undef STAGE_B
#undef LDA4
#undef LDB2
#undef MFMA16
}

// --------- RoPE + scatter qkv[T,6144] -> Qr[b,h,s,d] Kr[b,h,s,d] Vt[b,h,d,s]
__global__ __launch_bounds__(256) void rope_scatter_kernel(
    const ushort* __restrict__ qkv, const float2* __restrict__ tab,
    ushort* __restrict__ Qr, ushort* __restrict__ Kr, ushort* __restrict__ Vt) {
  __shared__ ushort vt[64][132];
  const int t = threadIdx.x, tt = blockIdx.x, h = blockIdx.y;  // h: 0..47
  const int row = t >> 2, c = (t & 3) * 16;
  const int tok = tt * 64 + row;
  const int b = tok >> 11, s = tok & 2047;
  const ushort* ip = qkv + (size_t)tok * 6144 + h * 128;
  union U { uint4 v; ushort us[8]; };
  U a0, a1, b0, b1;
  a0.v = *(const uint4*)(ip + c);      a1.v = *(const uint4*)(ip + c + 8);
  b0.v = *(const uint4*)(ip + c + 64); b1.v = *(const uint4*)(ip + c + 72);
  if (h < 40) {  // q or k head: NeoX rope on pairs (i, i+64)
    U o0, o1, o2, o3;
#pragma unroll
    for (int j = 0; j < 8; ++j) {
      float2 cs = tab[s * 64 + c + j];
      float x1 = bf2f(a0.us[j]), x2 = bf2f(b0.us[j]);
      o0.us[j] = f2bf(x1 * cs.x - x2 * cs.y);
      o2.us[j] = f2bf(x2 * cs.x + x1 * cs.y);
    }
#pragma unroll
    for (int j = 0; j < 8; ++j) {
      float2 cs = tab[s * 64 + c + 8 + j];
      float x1 = bf2f(a1.us[j]), x2 = bf2f(b1.us[j]);
      o1.us[j] = f2bf(x1 * cs.x - x2 * cs.y);
      o3.us[j] = f2bf(x2 * cs.x + x1 * cs.y);
    }
    ushort* base;
    if (h < 32) base = Qr + ((size_t)((b * 32 + h) * 2048 + s)) * 128;
    else        base = Kr + ((size_t)((b * 8 + (h - 32)) * 2048 + s)) * 128;
    *(uint4*)(base + c)      = o0.v; *(uint4*)(base + c + 8)  = o1.v;
    *(uint4*)(base + c + 64) = o2.v; *(uint4*)(base + c + 72) = o3.v;
  } else {  // v head: LDS transpose -> Vt[b,hv,d,s]
    const int hv = h - 40;
#pragma unroll
    for (int j = 0; j < 8; ++j) {
      vt[row][c + j]      = a0.us[j]; vt[row][c + 8 + j]  = a1.us[j];
      vt[row][c + 64 + j] = b0.us[j]; vt[row][c + 72 + j] = b1.us[j];
    }
    __syncthreads();
    const int d = t >> 1, s0 = (t & 1) * 32, sb = (tt & 31) * 64;
    U w0, w1, w2, w3;
#pragma unroll
    for (int j = 0; j < 8; ++j) {
      w0.us[j] = vt[s0 + j][d];      w1.us[j] = vt[s0 + 8 + j][d];
      w2.us[j] = vt[s0 + 16 + j][d]; w3.us[j] = vt[s0 + 24 + j][d];
    }
    ushort* vb = Vt + ((size_t)((b * 8 + hv) * 128 + d)) * 2048 + sb + s0;
    *(uint4*)(vb) = w0.v;      *(uint4*)(vb + 8) = w1.v;
    *(uint4*)(vb + 16) = w2.v; *(uint4*)(vb + 24) = w3.v;
  }
}

// ------------- flash attention + hidden weight transposes ------------------
// Byte-identical to R13..R15 attn_tc.
__global__ __launch_bounds__(512) void attn_tc_kernel(
    const ushort* __restrict__ Q, const ushort* __restrict__ K,
    const ushort* __restrict__ V, ushort* __restrict__ O,
    const float* t1in, ushort* t1out, int t1ld, int t1off, int t1R, int t1ntx, int t1n,
    const float* t2in, ushort* t2out, int t2ld, int t2off, int t2R, int t2ntx, int t2n,
    const float* t3in, ushort* t3out, int t3ld, int t3off, int t3R, int t3ntx, int t3n) {
  extern __shared__ ushort sm[];
  const int bid = (int)blockIdx.x;
  const int t = threadIdx.x;
  if (bid >= 1024) {                      // transpose blocks
    int tb = bid - 1024;
    if (tb < t1n) {
      transpose512(t1in, t1out, t1ld, t1off, t1R, t1ntx, tb, sm, t);
    } else if (tb < t1n + t2n) {
      transpose512(t2in, t2out, t2ld, t2off, t2R, t2ntx, tb - t1n, sm, t);
    } else {
      transpose512(t3in, t3out, t3ld, t3off, t3R, t3ntx, tb - t1n - t2n, sm, t);
    }
    return;
  }
  const int qb = bid & 15, h = (bid >> 4) & 31, b = bid >> 9;

  ushort* Kl = sm;           // [2][64 s][128 d]
  ushort* Vl = sm + 16384;   // [2][128 d][64 s]
  ushort* Pl = sm + 32768;   // [128][64]
  const int l = t & 63, w = t >> 6;   // w: 0..7
  const int lr = l & 15, lg = l >> 4;
  const int hkv = h >> 2;
  const f32x4 fzero = {0.f, 0.f, 0.f, 0.f};

  const int rm = lr & 7;
  int ksw[4], vsw[2];
#pragma unroll
  for (int ks = 0; ks < 4; ++ks) ksw[ks] = ((ks * 4 + lg) ^ rm) * 8;
  vsw[0] = (lg ^ rm) * 8;
  vsw[1] = ((4 + lg) ^ rm) * 8;
  const int kcol = ((t & 15) ^ ((t >> 4) & 7)) * 8;   // staging src swizzle
  const int vcol = ((t & 7) ^ ((t >> 3) & 7)) * 8;

  const float qscale = 0.08838834764831845f * 1.4426950408889634f;
  const ushort* qp =
      Q + ((size_t)((b * 32 + h) * 2048 + qb * 128 + w * 16 + lr)) * 128 + lg * 8;
  bf16x8 qf[4];
#pragma unroll
  for (int ks = 0; ks < 4; ++ks) {
    bf16x8 raw = *(const bf16x8*)(qp + ks * 32);
#pragma unroll
    for (int j = 0; j < 8; ++j)
      qf[ks][j] = (short)f2bf(bf2f((ushort)raw[j]) * qscale);
  }
  bf16x8 ones;
#pragma unroll
  for (int j = 0; j < 8; ++j) ones[j] = (short)0x3F80;
  WAIT_VM0();

  const ushort* kg = K + ((size_t)(b * 8 + hkv)) * 2048 * 128;
  const ushort* vg = V + ((size_t)(b * 8 + hkv)) * 128 * 2048;

#define STAGE_KV(buf, s0_) do {                                              \
    _Pragma("unroll") for (int i_ = 0; i_ < 2; ++i_)                         \
      gload16(kg + (size_t)((s0_) + i_ * 32 + (t >> 4)) * 128 + kcol,        \
              (char*)Kl + (buf) * 16384 + i_ * 8192 + t * 16);               \
    _Pragma("unroll") for (int i_ = 0; i_ < 2; ++i_)                         \
      gload16(vg + (size_t)(i_ * 64 + (t >> 3)) * 2048 + (s0_) + vcol,       \
              (char*)Vl + (buf) * 16384 + i_ * 8192 + t * 16);               \
  } while (0)

  f32x4 accO[8];
#pragma unroll
  for (int i = 0; i < 8; ++i) accO[i] = fzero;
  float m_r[4] = {-1e30f, -1e30f, -1e30f, -1e30f};
  float l_r[4] = {0.f, 0.f, 0.f, 0.f};
  const int qrow = qb * 128 + w * 16 + lg * 4;
  const int wrow0 = qb * 128 + w * 16;
  const int jend = 2 * qb + 1;

  STAGE_KV(0, 0);
  for (int j = 0; j <= jend; ++j) {
    if (j < jend) { STAGE_KV((j + 1) & 1, (j + 1) * 64); WAIT_VM4(); }
    else          { WAIT_VM0(); }
    BARRIER();
    const ushort* Kb = Kl + (j & 1) * 8192;
    const ushort* Vb = Vl + (j & 1) * 8192;

    f32x4 sc[4];
#pragma unroll
    for (int ni = 0; ni < 4; ++ni) sc[ni] = fzero;
    __builtin_amdgcn_s_setprio(1);
#pragma unroll
    for (int ni = 0; ni < 4; ++ni)
#pragma unroll
      for (int ks = 0; ks < 4; ++ks) {
        bf16x8 kf = *(const bf16x8*)(Kb + (ni * 16 + lr) * 128 + ksw[ks]);
        sc[ni] = __builtin_amdgcn_mfma_f32_16x16x32_bf16(qf[ks], kf, sc[ni], 0, 0, 0);
      }
    __builtin_amdgcn_s_setprio(0);
    if (j * 64 + 63 > wrow0) {
#pragma unroll
      for (int ni = 0; ni < 4; ++ni)
#pragma unroll
        for (int r = 0; r < 4; ++r)
          if (j * 64 + ni * 16 + lr > qrow + r) sc[ni][r] = -1e30f;
    }
    float mx[4];
#pragma unroll
    for (int r = 0; r < 4; ++r) {
      float v = fmaxf(fmaxf(sc[0][r], sc[1][r]), fmaxf(sc[2][r], sc[3][r]));
#pragma unroll
      for (int m = 8; m; m >>= 1) v = fmaxf(v, __shfl_xor(v, m));
      mx[r] = v;
    }
    bool ok = mx[0] <= m_r[0] + 8.f && mx[1] <= m_r[1] + 8.f &&
              mx[2] <= m_r[2] + 8.f && mx[3] <= m_r[3] + 8.f;
    if (!__all(ok)) {
#pragma unroll
      for (int r = 0; r < 4; ++r) {
        float mnew = fmaxf(m_r[r], mx[r]);
        float fsc = exp2f(m_r[r] - mnew);
        l_r[r] *= fsc;
        m_r[r] = mnew;
#pragma unroll
        for (int i = 0; i < 8; ++i) accO[i][r] *= fsc;
      }
    }
#pragma unroll
    for (int ni = 0; ni < 4; ++ni)
#pragma unroll
      for (int r = 0; r < 4; ++r) {
        int prow = w * 16 + lg * 4 + r;
        int slot = (ni * 2 + (lr >> 3)) ^ (prow & 7);
        Pl[prow * 64 + slot * 8 + rm] = f2bf(exp2f(sc[ni][r] - m_r[r]));
      }
    WAIT_LGKM0();
    f32x4 accL = fzero;
    __builtin_amdgcn_s_setprio(1);
#pragma unroll
    for (int ks = 0; ks < 2; ++ks) {
      bf16x8 pf = *(const bf16x8*)(Pl + (w * 16 + lr) * 64 + vsw[ks]);
#pragma unroll
      for (int nf = 0; nf < 8; ++nf) {
        bf16x8 vf = *(const bf16x8*)(Vb + (nf * 16 + lr) * 64 + vsw[ks]);
        accO[nf] = __builtin_amdgcn_mfma_f32_16x16x32_bf16(pf, vf, accO[nf], 0, 0, 0);
      }
      accL = __builtin_amdgcn_mfma_f32_16x16x32_bf16(pf, ones, accL, 0, 0, 0);
    }
    __builtin_amdgcn_s_setprio(0);
#pragma unroll
    for (int r = 0; r < 4; ++r) l_r[r] += accL[r];
    BARRIER();
  }
#undef STAGE_KV
  float invl[4];
#pragma unroll
  for (int r = 0; r < 4; ++r) invl[r] = 1.f / l_r[r];
#pragma unroll
  for (int nf = 0; nf < 8; ++nf)
#pragma unroll
    for (int r = 0; r < 4; ++r) {
      int q = qb * 128 + w * 16 + lg * 4 + r;
      int d = nf * 16 + lr;
      O[((size_t)(b * 2048 + q)) * 4096 + h * 128 + d] = f2bf(accO[nf][r] * invl[r]);
    }
}

// ------------------------------ launcher -----------------------------------
#define OFF_A     ((size_t)0)           // qkvb | W3 | act
#define OFF_B     ((size_t)90177536)    // tab | W4
#define OFF_D     ((size_t)180355072)   // W1 | Qr/Kr/Vt | gate
#define OFF_C     ((size_t)270532608)   // W2 | W5
#define OFF_E     ((size_t)360710144)   // xn | attnb | xn
#define OFF_TAB   (OFF_B)
#define OFF_QR    (OFF_D + 1048576)
#define OFF_KR    (OFF_D + 34603008)
#define OFF_VT    (OFF_D + 42991616)
#define WS_NEED   ((size_t)416284672)

extern "C" void kernel_launch(void* const* d_in, const int* in_sizes, int n_in,
                              void* d_out, int out_size, void* d_ws,
                              size_t ws_size, hipStream_t stream) {
  (void)in_sizes; (void)n_in; (void)out_size;
  if (ws_size < WS_NEED) return;
  const float* hs     = (const float*)d_in[0];
  const int*   pos    = (const int*)d_in[1];
  const float* w_qkv  = (const float*)d_in[2];
  const float* w_o    = (const float*)d_in[3];
  const float* w_gu   = (const float*)d_in[4];
  const float* w_down = (const float*)d_in[5];
  const float* ln1    = (const float*)d_in[6];
  const float* ln2    = (const float*)d_in[7];
  float* out = (float*)d_out;
  float* h1  = (float*)d_out;          // residual stream lives in d_out
  char* ws = (char*)d_ws;

  ushort* qkvb  = (ushort*)(ws + OFF_A);
  ushort* W3    = (ushort*)(ws + OFF_A);
  ushort* act   = (ushort*)(ws + OFF_A);
  float2* tab   = (float2*)(ws + OFF_TAB);
  ushort* W4    = (ushort*)(ws + OFF_B);
  ushort* W1    = (ushort*)(ws + OFF_D);
  ushort* gate  = (ushort*)(ws + OFF_D);
  ushort* Qr    = (ushort*)(ws + OFF_QR);
  ushort* Kr    = (ushort*)(ws + OFF_KR);
  ushort* Vt    = (ushort*)(ws + OFF_VT);
  ushort* W2    = (ushort*)(ws + OFF_C);
  ushort* W5    = (ushort*)(ws + OFF_C);
  ushort* xn    = (ushort*)(ws + OFF_E);
  ushort* attnb = (ushort*)(ws + OFF_E);

  auto kb = gemm256_kernel<ushort, false>;
  auto kf = gemm256_kernel<float, true>;
  hipFuncSetAttribute((const void*)kb, hipFuncAttributeMaxDynamicSharedMemorySize, 131072);
  hipFuncSetAttribute((const void*)kf, hipFuncAttributeMaxDynamicSharedMemorySize, 131072);
  hipFuncSetAttribute((const void*)gemm256_tc_kernel, hipFuncAttributeMaxDynamicSharedMemorySize, 131072);
  hipFuncSetAttribute((const void*)gemm256_swiglu_kernel, hipFuncAttributeMaxDynamicSharedMemorySize, 131072);
  hipFuncSetAttribute((const void*)attn_tc_kernel, hipFuncAttributeMaxDynamicSharedMemorySize, 81920);

  // s1: fused rmsnorm1 -> xn(E), w_qkv -> W1(D), rope table -> tab(B)
  pre_kernel<<<4096 + 3072 + 256, 512, 0, stream>>>(
      hs, ln1, xn, w_qkv, W1, pos, tab);
  // s3: qkv GEMM -> qkvb(A) + hidden transpose (w_o -> W2(C)) in idle tail
  gemm256_tc_kernel<<<384 + 2048, 512, 131072, stream>>>(
      xn, W1, qkvb, 4096, 6144, 4096,
      w_o, W2, 4096, 0, 4096, 64);
  // s4: rope scatter -> Qr/Kr/Vt (D, over W1)
  rope_scatter_kernel<<<dim3(64, 48), 256, 0, stream>>>(qkvb, tab, Qr, Kr, Vt);
  // s5: attn -> attnb(E) + hidden transposes (w_gu p1->W3(A), p2->W4(B))
  attn_tc_kernel<<<1024 + 5504 + 5504, 512, 81920, stream>>>(
      Qr, Kr, Vt, attnb,
      w_gu, W3, 22016, 0,     4096, 64, 5504,
      w_gu, W4, 22016, 11008, 4096, 64, 5504,
      w_o,  W2, 4096,  0,     4096, 64, 0);
  // s7: o-proj (residual hs) -> h1 (= d_out)
  gemm256_kernel<float, true><<<256, 512, 131072, stream>>>(
      attnb, W2, h1, hs, 4096, 4096, 4096);
  // s8: rmsnorm2 -> xn(E, over attnb)
  rmsnorm_kernel<<<4096, 256, 0, stream>>>(h1, ln2, xn);
  // s9: gate GEMM -> gate(D) + hidden transpose (w_down -> W5(C, over W2))
  gemm256_tc_kernel<<<688 + 5504, 512, 131072, stream>>>(
      xn, W3, gate, 4096, 11008, 4096,
      w_down, W5, 4096, 0, 11008, 172);
  // s10: up GEMM + fused SwiGLU -> act(A, over W3)
  gemm256_swiglu_kernel<<<688, 512, 131072, stream>>>(
      xn, W4, act, gate, 4096, 11008, 4096);
  // s12: down GEMM, residual h1 (= d_out), same-index in-place write
  gemm256_kernel<float, true><<<256, 512, 131072, stream>>>(
      act, W5, out, h1, 4096, 4096, 11008);
}